// Round 8
// baseline (223.231 us; speedup 1.0000x reference)
//
#include <hip/hip_runtime.h>

typedef unsigned short u16;
typedef __attribute__((ext_vector_type(4))) float f32x4;
typedef __attribute__((ext_vector_type(8))) __bf16 bf16x8;
typedef __attribute__((ext_vector_type(8))) unsigned short u16x8;
typedef __attribute__((ext_vector_type(4))) unsigned short u16x4;

// ---------- scalar bf16 helpers ----------
__device__ __forceinline__ u16 f2b(float f) {
    unsigned int u = __builtin_bit_cast(unsigned int, f);
    u = (u + 0x7FFFu + ((u >> 16) & 1u)) >> 16;
    return (u16)u;
}
__device__ __forceinline__ float b2f(u16 h) {
    unsigned int u = ((unsigned int)h) << 16;
    return __builtin_bit_cast(float, u);
}

// async global->LDS, 16B per lane; LDS dest is wave-uniform base (+lane*16 by HW)
__device__ __forceinline__ void gload_lds16(const u16* g, u16* l) {
    __builtin_amdgcn_global_load_lds(
        (const __attribute__((address_space(1))) void*)g,
        (__attribute__((address_space(3))) void*)l,
        16, 0, 0);
}

__device__ __forceinline__ bf16x8 lds_frag(const u16* p) {
    u16x8 t = *(const u16x8*)p;
    return __builtin_bit_cast(bf16x8, t);
}

#define FENCE asm volatile("" ::: "memory")
#define BARRIER do { FENCE; __builtin_amdgcn_s_barrier(); FENCE; } while (0)
#define WAIT_VM4 asm volatile("s_waitcnt vmcnt(4)" ::: "memory")
#define WAIT_VM0 asm volatile("s_waitcnt vmcnt(0)" ::: "memory")

// ---------------- prep kernels ----------------
__global__ __launch_bounds__(256) void cast_x_kernel(const float* __restrict__ in,
                                                     u16* __restrict__ out) {
    int i = (blockIdx.x * 256 + threadIdx.x) * 4;
    float4 v = *(const float4*)&in[i];
    u16x4 o = { f2b(v.x), f2b(v.y), f2b(v.z), f2b(v.w) };
    *(u16x4*)&out[i] = o;
}

// WT[(sel*1024 + h*64 + e)][d] = w_sel[h][d][e]  — LDS-tiled transpose
__global__ __launch_bounds__(256) void tr_wqkv(const float* __restrict__ wq,
                                               const float* __restrict__ wk,
                                               const float* __restrict__ wv,
                                               u16* __restrict__ WT) {
    __shared__ float tile[32][33];
    int z = blockIdx.z;                    // 0..47 = sel*16 + h
    int sel = z >> 4, h = z & 15;
    const float* w = (sel == 0) ? wq : (sel == 1) ? wk : wv;
    w += (long)h * 65536;                  // [1024][64]
    int tx = threadIdx.x & 31, ty = threadIdx.x >> 5;
    int d0 = blockIdx.x * 32, e0 = blockIdx.y * 32;
#pragma unroll
    for (int i = 0; i < 32; i += 8)
        tile[ty + i][tx] = w[(long)(d0 + ty + i) * 64 + e0 + tx];
    __syncthreads();
#pragma unroll
    for (int i = 0; i < 32; i += 8)
        WT[((long)(sel * 1024 + h * 64 + e0 + ty + i)) * 1024 + d0 + tx] = f2b(tile[tx][ty + i]);
}

__global__ __launch_bounds__(256) void prep_bias(const float* __restrict__ bq,
                                                 const float* __restrict__ bk,
                                                 const float* __restrict__ bv,
                                                 float* __restrict__ BI) {
    int i = blockIdx.x * 256 + threadIdx.x;   // < 3072
    const float* b = (i < 1024) ? bq : (i < 2048) ? bk : bv;
    BI[i] = b[((i & 1023) >> 6) * 64 + (i & 63)];
}

// out[c][r] = (bf16) in[r][c]   (in: [R][C] f32)
__global__ __launch_bounds__(256) void transpose_cast(const float* __restrict__ in,
                                                      u16* __restrict__ out, int R, int C) {
    __shared__ float tile[32][33];
    int tx = threadIdx.x & 31, ty = threadIdx.x >> 5;   // 32 x 8
    int r0 = blockIdx.y * 32, c0 = blockIdx.x * 32;
#pragma unroll
    for (int i = 0; i < 32; i += 8)
        tile[ty + i][tx] = in[(long)(r0 + ty + i) * C + c0 + tx];
    __syncthreads();
#pragma unroll
    for (int i = 0; i < 32; i += 8)
        out[(long)(c0 + ty + i) * R + r0 + tx] = f2b(tile[tx][ty + i]);
}

// Kc/Vc f32 expand from QKVB cols 1024..3071 (values bf16-exact)
__global__ __launch_bounds__(256) void kv_expand(const u16* __restrict__ QKVB,
                                                 float* __restrict__ kv) {
    int idx = blockIdx.x * 256 + threadIdx.x;  // 4096*2048/8 = 1,048,576
    int row = idx >> 8;
    int co = (idx & 255) * 8;                  // col in [0,2048), 8-aligned
    u16x8 v = *(const u16x8*)&QKVB[(long)row * 3072 + 1024 + co];
    float4 f0 = { b2f(v[0]), b2f(v[1]), b2f(v[2]), b2f(v[3]) };
    float4 f1 = { b2f(v[4]), b2f(v[5]), b2f(v[6]), b2f(v[7]) };
    long base = (long)(co >> 10) * 4194304 + (long)row * 1024 + (co & 1023);
    *(float4*)&kv[base] = f0;
    *(float4*)&kv[base + 4] = f1;
}

// ---------------- 3-slot BK=32 GEMM, compiler-scheduled body, counted vmcnt ------
// C[M,N] = A[M,K] @ BT[N,K]^T. Tile BM=WM*MF*16, BN=WN*NF*16, BK=32, T=WM*WN*64.
// MODE 1: +bias (G1). MODE 2: +bias, relu (G4). MODE 4: 2-way split-K bf16
// partials to Q0/Q1 (G3,G5).
// Loop per K-tile: stage tile t+2 into free slot (4 gloads, 2-tile lead) ->
// frag reads + MFMA in ONE block (no lgkm/sched barriers: compiler emits
// progressive counted lgkmcnt, reads overlap MFMA across waves) -> vmcnt(4)
// (retires tile t+1 only; never drains mid-loop) -> single s_barrier.
// LDS row-XOR swizzle col^=(row&3)<<3 (elems), inverse applied on global src.
// Epilogue: acc -> swizzled LDS repack (EPH halves) -> coalesced u16x8 stores.
template <int MODE, int WM, int WN, int MF, int NF, bool COLOUT>
__global__ __launch_bounds__(WM * WN * 64, 2) void gemmV(
    const u16* __restrict__ A, const u16* __restrict__ BT, const float* __restrict__ bias,
    u16* __restrict__ Cb, u16* __restrict__ Q0, u16* __restrict__ Q1,
    int M, int N, int K, int lda, int ldb, int ldc, int kchunk) {
    constexpr int T   = WM * WN * 64;
    constexpr int BM  = WM * MF * 16;
    constexpr int BN  = WN * NF * 16;
    constexpr int RPI = T / 4;            // rows per gload instr (4 lanes/row @16B)
    constexpr int LA  = BM / RPI;
    constexpr int LB  = BN / RPI;
    constexpr int EPI = T * 8;            // LDS elems per gload instr
    constexpr int SLOT = (BM + BN) * 32;  // elems per slot (A then B)
    constexpr int EPH = (BM * BN > 3 * SLOT) ? 2 : 1;
    constexpr int HR  = BM / EPH;
    __shared__ __align__(16) u16 SMEM[3 * SLOT];
    const int tid = threadIdx.x;
    const int lane = tid & 63;
    const int wid = tid >> 6;
    const int wr = wid / WN, wc = wid % WN;
    const int ntile = N / BN;
    const int mtile = M / BM;
    int bid = blockIdx.x;
    int kb = 0, ksz = K;
    u16* Pout = Q0;
    if (MODE == 4) {
        int tiles = mtile * ntile;
        int sk = bid / tiles; bid -= sk * tiles;
        kb = sk * kchunk;
        int rem = K - kb; ksz = rem < kchunk ? rem : kchunk;
        Pout = sk ? Q1 : Q0;
    }
    // XCD-chunked bijective swizzle (tile count multiple of 8)
    {
        int q = (mtile * ntile) >> 3;
        bid = (bid & 7) * q + (bid >> 3);
    }
    int bi, bj;
    if (COLOUT) { bj = bid / mtile; bi = bid % mtile; }
    else        { bi = bid / ntile; bj = bid % ntile; }
    const int brow = bi * BM, bcol = bj * BN;
    const int nt = ksz >> 5;              // BK=32 tiles

    // ---- staging addressing (inverse-swizzled global source, linear LDS dest)
    const int srow = tid >> 2;
    const int scol = ((tid & 3) ^ (srow & 3)) << 3;
    const u16* ag = A + (long)(brow + srow) * lda + kb + scol;
    const u16* bg = BT + (long)(bcol + srow) * ldb + kb + scol;
    const long aI = (long)RPI * lda, bI = (long)RPI * ldb;
    const int sdst = tid << 3;

    auto STG = [&](u16* s, int t) {
#pragma unroll
        for (int j = 0; j < LA; ++j)
            gload_lds16(ag + ((long)t << 5) + j * aI, &s[j * EPI + sdst]);
#pragma unroll
        for (int j = 0; j < LB; ++j)
            gload_lds16(bg + ((long)t << 5) + j * bI, &s[LA * EPI + j * EPI + sdst]);
    };

    f32x4 acc[MF][NF] = {};

    // ---- fragment read addressing (swizzled)
    const int ln15 = lane & 15;
    const int eoff = (((lane >> 4) << 3) ^ ((lane & 3) << 3));
    const int arow0 = wr * (MF * 16) + ln15;
    const int brow0 = wc * (NF * 16) + ln15;

    u16 *p0 = SMEM, *p1 = SMEM + SLOT, *p2 = SMEM + 2 * SLOT;
    // ---- prologue: stage t0, t1; retire t0; keep t1 in flight
    STG(p0, 0);
    STG(p1, 1);
    WAIT_VM4;
    BARRIER;

    for (int t = 0; t < nt; ++t) {
        if (t + 2 < nt) STG(p2, t + 2);
        bf16x8 bf[NF], af[MF];
#pragma unroll
        for (int n = 0; n < NF; ++n)
            bf[n] = lds_frag(&p0[BM * 32 + (brow0 + (n << 4)) * 32 + eoff]);
#pragma unroll
        for (int m = 0; m < MF; ++m)
            af[m] = lds_frag(&p0[(arow0 + (m << 4)) * 32 + eoff]);
#pragma unroll
        for (int m = 0; m < MF; ++m)
#pragma unroll
            for (int n = 0; n < NF; ++n)
                acc[m][n] = __builtin_amdgcn_mfma_f32_16x16x32_bf16(af[m], bf[n], acc[m][n], 0, 0, 0);
        if (t + 2 < nt) { WAIT_VM4; } else { WAIT_VM0; }
        BARRIER;
        u16* tp = p0; p0 = p1; p1 = p2; p2 = tp;
    }

    // ---- epilogue: swizzled LDS repack (EPH halves) -> coalesced stores
    u16* outp = (MODE == 4) ? Pout : Cb;
    const int ccol0 = wc * (NF * 16);
    const int crow0 = wr * (MF * 16);
    for (int h = 0; h < EPH; ++h) {
        if (EPH == 1 || wr == h) {
#pragma unroll
            for (int m = 0; m < MF; ++m) {
                int rb = (EPH == 1 ? crow0 : 0) + (m << 4) + ((lane >> 4) << 2);
#pragma unroll
                for (int n = 0; n < NF; ++n) {
                    int col = ccol0 + (n << 4) + ln15;
                    float bv = (MODE == 4) ? 0.f : bias[bcol + col];
#pragma unroll
                    for (int r = 0; r < 4; ++r) {
                        float v = acc[m][n][r] + bv;
                        if (MODE == 2) v = v > 0.f ? v : 0.f;
                        int row = rb + r;
                        SMEM[row * BN + (col ^ ((row & 3) << 3))] = f2b(v);
                    }
                }
            }
        }
        __syncthreads();
        constexpr int CHT = HR * BN / 8 / T;
#pragma unroll
        for (int k2 = 0; k2 < CHT; ++k2) {
            int c = tid + k2 * T;
            int row = c / (BN / 8), co = (c % (BN / 8)) * 8;
            u16x8 vv = *(const u16x8*)&SMEM[row * BN + (co ^ ((row & 3) << 3))];
            *(u16x8*)&outp[(long)(brow + h * HR + row) * ldc + bcol + co] = vv;
        }
        if (EPH == 2 && h == 0) __syncthreads();
    }
}

// ---------------- K^T V partial sums (t-chunked, f32 atomics) ----------------
__global__ __launch_bounds__(256) void ktv_partial(const u16* __restrict__ QKVB,
                                                   float* __restrict__ KTVF) {
    __shared__ __align__(16) u16 Ks[64 * 64];
    __shared__ __align__(16) u16 Vs[64 * 64];
    int tid = threadIdx.x;
    int tc = blockIdx.x, bh = blockIdx.y;
    int b = bh >> 4, h = bh & 15;
    int j = tid & 63, i0 = (tid >> 6) * 16;
    float acc[16] = {};
    for (int st = 0; st < 4; ++st) {
        int t0 = tc * 256 + st * 64;
        __syncthreads();
#pragma unroll
        for (int i = 0; i < 2; ++i) {
            int c = i * 256 + tid;
            long base = (long)(b * 2048 + t0 + (c >> 3)) * 3072 + h * 64 + (c & 7) * 8;
            *(u16x8*)&Ks[c * 8] = *(const u16x8*)&QKVB[base + 1024];
            *(u16x8*)&Vs[c * 8] = *(const u16x8*)&QKVB[base + 2048];
        }
        __syncthreads();
        for (int tt = 0; tt < 64; ++tt) {
            float vj = b2f(Vs[tt * 64 + j]);
            u16x8 k0 = *(const u16x8*)&Ks[tt * 64 + i0];
            u16x8 k1 = *(const u16x8*)&Ks[tt * 64 + i0 + 8];
#pragma unroll
            for (int r = 0; r < 8; ++r) acc[r] += b2f(k0[r]) * vj;
#pragma unroll
            for (int r = 0; r < 8; ++r) acc[r + 8] += b2f(k1[r]) * vj;
        }
    }
#pragma unroll
    for (int r = 0; r < 16; ++r)
        atomicAdd(&KTVF[bh * 4096 + (i0 + r) * 64 + j], acc[r]);
}

// KTVT[bh][n][k] = KTVF[bh][k][n] * 0.125 (fold 1/sqrt(64))
__global__ __launch_bounds__(256) void cast_ktv(const float* __restrict__ KTVF,
                                                u16* __restrict__ KTVT) {
    int idx = blockIdx.x * 256 + threadIdx.x;   // < 32*4096
    int bh = idx >> 12, r = idx & 4095;
    int n = r >> 6, k = r & 63;
    KTVT[idx] = f2b(KTVF[bh * 4096 + k * 64 + n] * 0.125f);
}

// ---------------- batched attn GEMM: cat[t, h*64+e'] = Q[t,:] @ KTVT[e',:] -------
__global__ __launch_bounds__(256) void attn_gemm(const u16* __restrict__ QKVB,
                                                 const u16* __restrict__ KTVT,
                                                 u16* __restrict__ cat) {
    __shared__ __align__(16) u16 Qs[64 * 64];
    __shared__ __align__(16) u16 Bs[64 * 64];
    int tid = threadIdx.x, wid = tid >> 6, lane = tid & 63;
    int rt = blockIdx.x, bh = blockIdx.y;
    int b = bh >> 4, h = bh & 15;
    long qbase = (long)(b * 2048 + rt * 64) * 3072 + h * 64;
#pragma unroll
    for (int i = 0; i < 2; ++i) {
        int c = i * 256 + tid;
        gload_lds16(QKVB + qbase + (c >> 3) * 3072 + (c & 7) * 8, &Qs[(i * 256 + wid * 64) * 8]);
        gload_lds16(KTVT + bh * 4096 + c * 8, &Bs[(i * 256 + wid * 64) * 8]);
    }
    __syncthreads();
    f32x4 acc[4] = {};
#pragma unroll
    for (int kk = 0; kk < 2; ++kk) {
        bf16x8 a = lds_frag(&Qs[(wid * 16 + (lane & 15)) * 64 + kk * 32 + (lane >> 4) * 8]);
#pragma unroll
        for (int n = 0; n < 4; ++n) {
            bf16x8 bb = lds_frag(&Bs[(n * 16 + (lane & 15)) * 64 + kk * 32 + (lane >> 4) * 8]);
            acc[n] = __builtin_amdgcn_mfma_f32_16x16x32_bf16(a, bb, acc[n], 0, 0, 0);
        }
    }
#pragma unroll
    for (int n = 0; n < 4; ++n)
#pragma unroll
        for (int r = 0; r < 4; ++r) {
            int row = rt * 64 + wid * 16 + (lane >> 4) * 4 + r;
            int col = h * 64 + n * 16 + (lane & 15);
            cat[(long)(b * 2048 + row) * 1024 + col] = f2b(acc[n][r]);
        }
}

// ---------------- layernorm kernels ----------------
__device__ __forceinline__ void block_reduce2(float& a, float& b) {
    __syncthreads();
#pragma unroll
    for (int off = 32; off; off >>= 1) {
        a += __shfl_down(a, off);
        b += __shfl_down(b, off);
    }
    __shared__ float sa[4], sb[4];
    int wid = threadIdx.x >> 6, lane = threadIdx.x & 63;
    if (lane == 0) { sa[wid] = a; sb[wid] = b; }
    __syncthreads();
    a = sa[0] + sa[1] + sa[2] + sa[3];
    b = sb[0] + sb[1] + sb[2] + sb[3];
}

// out1 = LN(x + (q0+q1 + bp)) ; write f32 + bf16  (q* = bf16 partials)
__global__ __launch_bounds__(256) void ln1_kernel(
    const float* __restrict__ x,
    const u16* __restrict__ q0, const u16* __restrict__ q1,
    const float* __restrict__ bp,
    const float* __restrict__ g, const float* __restrict__ bt,
    float* __restrict__ out1f, u16* __restrict__ out1b) {
    int row = blockIdx.x, tid = threadIdx.x;
    long base = (long)row * 1024 + tid * 4;
    float4 xv = *(const float4*)&x[base];
    u16x4 a0 = *(const u16x4*)&q0[base];
    u16x4 a1 = *(const u16x4*)&q1[base];
    float4 bb = *(const float4*)&bp[tid * 4];
    float xa[4] = { xv.x, xv.y, xv.z, xv.w };
    float bba[4] = { bb.x, bb.y, bb.z, bb.w };
    float s[4];
#pragma unroll
    for (int r = 0; r < 4; ++r)
        s[r] = xa[r] + b2f(a0[r]) + b2f(a1[r]) + bba[r];
    float sum = s[0] + s[1] + s[2] + s[3];
    float sq = s[0] * s[0] + s[1] * s[1] + s[2] * s[2] + s[3] * s[3];
    block_reduce2(sum, sq);
    float mu = sum * (1.f / 1024.f);
    float var = sq * (1.f / 1024.f) - mu * mu;
    float rs = rsqrtf(var + 1e-5f);
    float o0 = (s[0] - mu) * rs * g[tid * 4 + 0] + bt[tid * 4 + 0];
    float o1 = (s[1] - mu) * rs * g[tid * 4 + 1] + bt[tid * 4 + 1];
    float o2 = (s[2] - mu) * rs * g[tid * 4 + 2] + bt[tid * 4 + 2];
    float o3 = (s[3] - mu) * rs * g[tid * 4 + 3] + bt[tid * 4 + 3];
    float4 of; of.x = o0; of.y = o1; of.z = o2; of.w = o3;
    u16x4 ob = (u16x4){ f2b(o0), f2b(o1), f2b(o2), f2b(o3) };
    *(float4*)&out1f[base] = of;
    *(u16x4*)&out1b[base] = ob;
}

// ff = (q0+q1)+b2 (bf16 partials); ffo = LN(out1+ff); out2 = LN(out1+ffo)
__global__ __launch_bounds__(256) void lnf_kernel(
    const float* __restrict__ out1f,
    const u16* __restrict__ q0, const u16* __restrict__ q1,
    const float* __restrict__ b2,
    const float* __restrict__ lnfg, const float* __restrict__ lnfb,
    const float* __restrict__ ln2g, const float* __restrict__ ln2b,
    float* __restrict__ out2) {
    int row = blockIdx.x, tid = threadIdx.x;
    long base = (long)row * 1024 + tid * 4;
    float4 o1 = *(const float4*)&out1f[base];
    u16x4 a0 = *(const u16x4*)&q0[base];
    u16x4 a1 = *(const u16x4*)&q1[base];
    float4 bb = *(const float4*)&b2[tid * 4];
    float o1a[4] = { o1.x, o1.y, o1.z, o1.w };
    float bba[4] = { bb.x, bb.y, bb.z, bb.w };
    float s1[4];
#pragma unroll
    for (int r = 0; r < 4; ++r)
        s1[r] = o1a[r] + b2f(a0[r]) + b2f(a1[r]) + bba[r];
    float sum = s1[0] + s1[1] + s1[2] + s1[3];
    float sq = s1[0] * s1[0] + s1[1] * s1[1] + s1[2] * s1[2] + s1[3] * s1[3];
    block_reduce2(sum, sq);
    float mu = sum * (1.f / 1024.f);
    float rs = rsqrtf(sq * (1.f / 1024.f) - mu * mu + 1e-5f);
    float s2[4];
#pragma unroll
    for (int r = 0; r < 4; ++r) {
        float ffo = (s1[r] - mu) * rs * lnfg[tid * 4 + r] + lnfb[tid * 4 + r];
        s2[r] = o1a[r] + ffo;
    }
    float sum2 = s2[0] + s2[1] + s2[2] + s2[3];
    float sq2 = s2[0] * s2[0] + s2[1] * s2[1] + s2[2] * s2[2] + s2[3] * s2[3];
    block_reduce2(sum2, sq2);
    float mu2 = sum2 * (1.f / 1024.f);
    float rs2 = rsqrtf(sq2 * (1.f / 1024.f) - mu2 * mu2 + 1e-5f);
    float4 o;
    o.x = (s2[0] - mu2) * rs2 * ln2g[tid * 4 + 0] + ln2b[tid * 4 + 0];
    o.y = (s2[1] - mu2) * rs2 * ln2g[tid * 4 + 1] + ln2b[tid * 4 + 1];
    o.z = (s2[2] - mu2) * rs2 * ln2g[tid * 4 + 2] + ln2b[tid * 4 + 2];
    o.w = (s2[3] - mu2) * rs2 * ln2g[tid * 4 + 3] + ln2b[tid * 4 + 3];
    *(float4*)&out2[base] = o;
}

// ---------------- launcher ----------------
extern "C" void kernel_launch(void* const* d_in, const int* in_sizes, int n_in,
                              void* d_out, int out_size, void* d_ws, size_t ws_size,
                              hipStream_t stream) {
    const float* x    = (const float*)d_in[0];
    const float* wq   = (const float*)d_in[1];
    const float* bq   = (const float*)d_in[2];
    const float* wk   = (const float*)d_in[3];
    const float* bk   = (const float*)d_in[4];
    const float* wv   = (const float*)d_in[5];
    const float* bv   = (const float*)d_in[6];
    const float* wp   = (const float*)d_in[7];
    const float* bp   = (const float*)d_in[8];
    const float* w1   = (const float*)d_in[9];
    const float* b1   = (const float*)d_in[10];
    const float* w2   = (const float*)d_in[11];
    const float* b2   = (const float*)d_in[12];
    const float* ln1g = (const float*)d_in[13];
    const float* ln1b = (const float*)d_in[14];
    const float* lnfg = (const float*)d_in[15];
    const float* lnfb = (const float*)d_in[16];
    const float* ln2g = (const float*)d_in[17];
    const float* ln2b = (const float*)d_in[18];

    float* out2 = (float*)d_out;
    float* kv   = (float*)d_out + 4194304;   // Kc then Vc

    // workspace layout (bytes). Liveness:
    char* ws = (char*)d_ws;
    u16*   XB     = (u16*)  (ws + 0);          // 8 MB (dead after G1); CAT (dead after G3); Q5_0
    u16*   CAT    = XB;
    u16*   WQKVT  = (u16*)  (ws + 8388608);    // 6.3 MB (dead after G1)
    float* BQKV   = (float*)(ws + 14680064);   // 12 KB (dead after G1)
    u16*   WPT    = (u16*)  (ws + 14692352);   // 2 MB (dead after G3)
    u16*   W1T    = (u16*)  (ws + 16789504);   // 8 MB (dead after G4)
    u16*   W2T    = (u16*)  (ws + 25178112);   // 8 MB (live through G5)
    float* KTVF   = (float*)(ws + 33566720);   // 512 KB
    u16*   KTVT   = (u16*)  (ws + 34091008);   // 256 KB
    u16*   QKVB   = (u16*)  (ws + 34353152);   // 24 MB (dead after attn/kv_expand); OUT1B
    u16*   OUT1B  = QKVB;
    u16*   Q3_0   = (u16*)  (ws + 59518976);   // 8 MB (dead after ln1)
    u16*   Q3_1   = (u16*)  (ws + 67907584);   // 8 MB (dead after ln1)
    float* OUT1F  = (float*)(ws + 76296192);   // 16 MB (live to lnf)
    u16*   H1     = (u16*)  (ws + 93073408);   // 32 MB (live through G5)
    u16*   Q5_0   = (u16*)  (ws + 0);          // 8 MB (over XB/CAT, dead after G3)
    u16*   Q5_1   = (u16*)  (ws + 34353152);   // 8 MB (over OUT1B, dead after G4)
    (void)ws_size; (void)in_sizes; (void)n_in; (void)out_size;

    hipMemsetAsync(KTVF, 0, 32 * 4096 * 4, stream);
    cast_x_kernel<<<4096, 256, 0, stream>>>(x, XB);
    tr_wqkv<<<dim3(32, 2, 48), 256, 0, stream>>>(wq, wk, wv, WQKVT);
    prep_bias<<<12, 256, 0, stream>>>(bq, bk, bv, BQKV);
    transpose_cast<<<dim3(32, 32), 256, 0, stream>>>(wp, WPT, 1024, 1024);
    transpose_cast<<<dim3(128, 32), 256, 0, stream>>>(w1, W1T, 1024, 4096);
    transpose_cast<<<dim3(32, 128), 256, 0, stream>>>(w2, W2T, 4096, 1024);

    // G1: QKV = X @ Wqkv + b  (128x384 tile, grid 256, col-outer XCD swizzle)
    gemmV<1, 2, 4, 4, 6, true><<<256, 512, 0, stream>>>(
        XB, WQKVT, BQKV, QKVB, nullptr, nullptr,
        4096, 3072, 1024, 1024, 1024, 3072, 0);
    kv_expand<<<4096, 256, 0, stream>>>(QKVB, kv);
    ktv_partial<<<dim3(8, 32), 256, 0, stream>>>(QKVB, KTVF);
    cast_ktv<<<512, 256, 0, stream>>>(KTVF, KTVT);
    attn_gemm<<<dim3(32, 32), 256, 0, stream>>>(QKVB, KTVT, CAT);

    // G3: out = cat @ wp (128x128 tile, split-K x2, 512 blocks, row-outer)
    gemmV<4, 2, 2, 4, 4, false><<<512, 256, 0, stream>>>(
        CAT, WPT, nullptr, nullptr, Q3_0, Q3_1,
        4096, 1024, 1024, 1024, 1024, 1024, 512);
    ln1_kernel<<<4096, 256, 0, stream>>>(x, Q3_0, Q3_1, bp, ln1g, ln1b, OUT1F, OUT1B);

    // G4: h1 = relu(out1 @ w1 + b1) (256x256 tile, grid 256, row-outer)
    gemmV<2, 2, 4, 8, 4, false><<<256, 512, 0, stream>>>(
        OUT1B, W1T, b1, H1, nullptr, nullptr,
        4096, 4096, 1024, 1024, 1024, 4096, 0);
    // G5: ff = h1 @ w2 (128x128 tile, split-K x2 over K=4096, 512 blocks, row-outer)
    gemmV<4, 2, 2, 4, 4, false><<<512, 256, 0, stream>>>(
        H1, W2T, nullptr, nullptr, Q5_0, Q5_1,
        4096, 1024, 4096, 4096, 4096, 1024, 2048);
    lnf_kernel<<<4096, 256, 0, stream>>>(OUT1F, Q5_0, Q5_1, b2,
                                         lnfg, lnfb, ln2g, ln2b, out2);
}

// Round 9
// 207.576 us; speedup vs baseline: 1.0754x; 1.0754x over previous
//
#include <hip/hip_runtime.h>

typedef unsigned short u16;
typedef __attribute__((ext_vector_type(4))) float f32x4;
typedef __attribute__((ext_vector_type(8))) __bf16 bf16x8;
typedef __attribute__((ext_vector_type(8))) unsigned short u16x8;
typedef __attribute__((ext_vector_type(4))) unsigned short u16x4;

// ---------- scalar bf16 helpers ----------
__device__ __forceinline__ u16 f2b(float f) {
    unsigned int u = __builtin_bit_cast(unsigned int, f);
    u = (u + 0x7FFFu + ((u >> 16) & 1u)) >> 16;
    return (u16)u;
}
__device__ __forceinline__ float b2f(u16 h) {
    unsigned int u = ((unsigned int)h) << 16;
    return __builtin_bit_cast(float, u);
}

// async global->LDS, 16B per lane; LDS dest is wave-uniform base (+lane*16 by HW)
__device__ __forceinline__ void gload_lds16(const u16* g, u16* l) {
    __builtin_amdgcn_global_load_lds(
        (const __attribute__((address_space(1))) void*)g,
        (__attribute__((address_space(3))) void*)l,
        16, 0, 0);
}

__device__ __forceinline__ bf16x8 lds_frag(const u16* p) {
    u16x8 t = *(const u16x8*)p;
    return __builtin_bit_cast(bf16x8, t);
}

#define FENCE asm volatile("" ::: "memory")
#define BARRIER do { FENCE; __builtin_amdgcn_s_barrier(); FENCE; \
                     __builtin_amdgcn_sched_barrier(0); } while (0)
#define SCHED0 __builtin_amdgcn_sched_barrier(0)
#define LGKM0 do { asm volatile("s_waitcnt lgkmcnt(0)" ::: "memory"); \
                   __builtin_amdgcn_sched_barrier(0); } while (0)
#define WAIT_VM8 do { asm volatile("s_waitcnt vmcnt(8)" ::: "memory"); \
                      __builtin_amdgcn_sched_barrier(0); } while (0)
#define WAIT_VM0 do { asm volatile("s_waitcnt vmcnt(0)" ::: "memory"); \
                      __builtin_amdgcn_sched_barrier(0); } while (0)

// ---------------- prep kernels ----------------
__global__ __launch_bounds__(256) void cast_x_kernel(const float* __restrict__ in,
                                                     u16* __restrict__ out) {
    int i = (blockIdx.x * 256 + threadIdx.x) * 4;
    float4 v = *(const float4*)&in[i];
    u16x4 o = { f2b(v.x), f2b(v.y), f2b(v.z), f2b(v.w) };
    *(u16x4*)&out[i] = o;
}

// WT[(sel*1024 + h*64 + e)][d] = w_sel[h][d][e]  — LDS-tiled transpose
__global__ __launch_bounds__(256) void tr_wqkv(const float* __restrict__ wq,
                                               const float* __restrict__ wk,
                                               const float* __restrict__ wv,
                                               u16* __restrict__ WT) {
    __shared__ float tile[32][33];
    int z = blockIdx.z;                    // 0..47 = sel*16 + h
    int sel = z >> 4, h = z & 15;
    const float* w = (sel == 0) ? wq : (sel == 1) ? wk : wv;
    w += (long)h * 65536;                  // [1024][64]
    int tx = threadIdx.x & 31, ty = threadIdx.x >> 5;
    int d0 = blockIdx.x * 32, e0 = blockIdx.y * 32;
#pragma unroll
    for (int i = 0; i < 32; i += 8)
        tile[ty + i][tx] = w[(long)(d0 + ty + i) * 64 + e0 + tx];
    __syncthreads();
#pragma unroll
    for (int i = 0; i < 32; i += 8)
        WT[((long)(sel * 1024 + h * 64 + e0 + ty + i)) * 1024 + d0 + tx] = f2b(tile[tx][ty + i]);
}

// merged: wp/w1/w2 transposes (out[c][r] = bf16(in[r][c])) + QKV bias pack
__global__ __launch_bounds__(256) void transpose_cast3(
    const float* __restrict__ wp, const float* __restrict__ w1, const float* __restrict__ w2,
    const float* __restrict__ bq, const float* __restrict__ bk, const float* __restrict__ bv,
    u16* __restrict__ WPT, u16* __restrict__ W1T, u16* __restrict__ W2T,
    float* __restrict__ BI) {
    int bid = blockIdx.x;
    if (bid >= 9216) {   // bias pack: 12 blocks
        int i = (bid - 9216) * 256 + threadIdx.x;   // < 3072
        const float* b = (i < 1024) ? bq : (i < 2048) ? bk : bv;
        BI[i] = b[((i & 1023) >> 6) * 64 + (i & 63)];
        return;
    }
    const float* in; u16* out; int C, R, bx, by;
    if (bid < 1024)      { in = wp; out = WPT; R = 1024; C = 1024; bx = bid & 31;  by = bid >> 5; }
    else if (bid < 5120) { int b = bid - 1024; in = w1; out = W1T; R = 1024; C = 4096; bx = b & 127; by = b >> 7; }
    else                 { int b = bid - 5120; in = w2; out = W2T; R = 4096; C = 1024; bx = b & 31;  by = b >> 5; }
    __shared__ float tile[32][33];
    int tx = threadIdx.x & 31, ty = threadIdx.x >> 5;   // 32 x 8
    int r0 = by * 32, c0 = bx * 32;
#pragma unroll
    for (int i = 0; i < 32; i += 8)
        tile[ty + i][tx] = in[(long)(r0 + ty + i) * C + c0 + tx];
    __syncthreads();
#pragma unroll
    for (int i = 0; i < 32; i += 8)
        out[(long)(c0 + ty + i) * R + r0 + tx] = f2b(tile[tx][ty + i]);
}

// ---------------- templated tiled GEMM, sub-phase pipelined (LDS || MFMA) -----
// C[M,N] = A[M,K] @ BT[N,K]^T. Tile BM=WM*MF*16, BN=WN*NF*16, BK=64, T=WM*WN*64.
// MODE 1: +bias, bf16 out + f32 KV side-write for cols>=1024 (G1).
// MODE 2: +bias, relu (G4). MODE 4: 2-way split-K bf16 partials to Q0/Q1 (G3,G5).
// Pipeline (R7-proven): 4 sub-phases per K-tile; sub-phase s issues ds_reads for
// s+1 into the alternate register frag buffer, then MFMAs current frags; compiler
// emits progressive counted lgkmcnt. 2 barriers/tile; counted vmcnt only.
// LDS byte-swizzle col^=(row&7)<<4 via inverse-swizzled global src (rule #21).
// Epilogue: acc -> swizzled LDS repack -> coalesced u16x8 stores (+f32 KV for MODE 1).
template <int MODE, int WM, int WN, int MF, int NF, bool COLOUT>
__global__ __launch_bounds__(WM * WN * 64, 2) void gemmT(
    const u16* __restrict__ A, const u16* __restrict__ BT, const float* __restrict__ bias,
    u16* __restrict__ Cb, float* __restrict__ KV,
    u16* __restrict__ Q0, u16* __restrict__ Q1,
    int M, int N, int K, int lda, int ldb, int ldc, int kchunk) {
    constexpr int T   = WM * WN * 64;
    constexpr int BM  = WM * MF * 16;
    constexpr int BN  = WN * NF * 16;
    constexpr int RPI = T / 8;            // rows per gload instr
    constexpr int LA  = BM / RPI;         // gload instrs per A K-tile
    constexpr int LB  = BN / RPI;
    constexpr int EPI = T * 8;            // LDS elems per gload instr
    constexpr int MFH = MF / 2;
    constexpr int ASZ = BM * 64, BSZ = BN * 64;
    __shared__ __align__(16) u16 SMEM[2 * ASZ + 2 * BSZ];
    u16* As0 = SMEM;
    u16* As1 = SMEM + ASZ;
    u16* Bs0 = SMEM + 2 * ASZ;
    u16* Bs1 = SMEM + 2 * ASZ + BSZ;
    const int tid = threadIdx.x;
    const int lane = tid & 63;
    const int wid = tid >> 6;
    const int wr = wid / WN, wc = wid % WN;
    const int ntile = N / BN;
    const int mtile = M / BM;
    int bid = blockIdx.x;
    int kb = 0, ksz = K;
    u16* Pout = Q0;
    if (MODE == 4) {
        int tiles = mtile * ntile;
        int sk = bid / tiles; bid -= sk * tiles;
        kb = sk * kchunk;
        int rem = K - kb; ksz = rem < kchunk ? rem : kchunk;
        Pout = sk ? Q1 : Q0;
    }
    // XCD-chunked bijective swizzle (tile count multiple of 8)
    {
        int q = (mtile * ntile) >> 3;
        bid = (bid & 7) * q + (bid >> 3);
    }
    int bi, bj;
    if (COLOUT) { bj = bid / mtile; bi = bid % mtile; }   // XCD owns B col-panels (G1)
    else        { bi = bid / ntile; bj = bid % ntile; }   // XCD owns A row-panels
    const int brow = bi * BM, bcol = bj * BN;
    const int nt = ksz >> 6;              // BK=64 tiles

    // ---- staging addressing (inverse-swizzled global source, linear LDS dest)
    const int srow = tid >> 3;
    const int scol = ((tid & 7) ^ (srow & 7)) << 3;
    const u16* ag = A + (long)(brow + srow) * lda + kb + scol;
    const u16* bg = BT + (long)(bcol + srow) * ldb + kb + scol;
    const long aI = (long)RPI * lda, bI = (long)RPI * ldb;
    const int sdst = tid << 3;

    auto STAGE = [&](u16* lA, u16* lB, int t) {
#pragma unroll
        for (int j = 0; j < LA; ++j)
            gload_lds16(ag + ((long)t << 6) + j * aI, &lA[j * EPI + sdst]);
#pragma unroll
        for (int j = 0; j < LB; ++j)
            gload_lds16(bg + ((long)t << 6) + j * bI, &lB[j * EPI + sdst]);
    };

    f32x4 acc[MF][NF] = {};
    bf16x8 af0[MFH], af1[MFH], bf0[NF], bf1[NF];

    // ---- fragment read addressing (swizzled)
    const int ln15 = lane & 15;
    const int eoff = (((lane >> 4) << 3) ^ ((lane & 7) << 3));
    const int arow0 = wr * (MF * 16) + ln15;
    const int brow0 = wc * (NF * 16) + ln15;

#define RD_A(dst, S, kh, mh)                                                   \
    _Pragma("unroll") for (int m4 = 0; m4 < MFH; ++m4)                         \
        dst[m4] = lds_frag(&(S)[((arow0 + (((mh) * MFH + m4) << 4)) << 6) +    \
                                (eoff ^ ((kh) << 5))]);
#define RD_B(dst, S, kh)                                                       \
    _Pragma("unroll") for (int n = 0; n < NF; ++n)                             \
        dst[n] = lds_frag(&(S)[((brow0 + (n << 4)) << 6) + (eoff ^ ((kh) << 5))]);
#define MM(a, b, mh) do {                                                      \
    __builtin_amdgcn_s_setprio(1);                                             \
    _Pragma("unroll") for (int m4 = 0; m4 < MFH; ++m4)                         \
        _Pragma("unroll") for (int n = 0; n < NF; ++n)                         \
            acc[(mh) * MFH + m4][n] = __builtin_amdgcn_mfma_f32_16x16x32_bf16( \
                a[m4], b[n], acc[(mh) * MFH + m4][n], 0, 0, 0);                \
    __builtin_amdgcn_s_setprio(0);                                             \
} while (0)

    // ---- prologue: stage t0 + t1; retire t0; initial frags
    STAGE(As0, Bs0, 0);
    if (nt > 1) { STAGE(As1, Bs1, 1); WAIT_VM8; } else { WAIT_VM0; }
    BARRIER;
    RD_B(bf0, Bs0, 0);
    RD_A(af0, As0, 0, 0);

    u16 *Ac = As0, *Bc = Bs0, *Ao = As1, *Bo = Bs1;
    for (int t = 0; t < nt; ++t) {
        const bool hasN = (t + 1 < nt);
        const bool hasNN = (t + 2 < nt);
        // s0: compute (kh0, mh0); prefetch (kh0, mh1)
        RD_A(af1, Ac, 0, 1);
        MM(af0, bf0, 0);
        SCHED0;
        // s1: compute (kh0, mh1); prefetch kh1 B + (kh1, mh0)
        RD_B(bf1, Bc, 1);
        RD_A(af0, Ac, 1, 0);
        MM(af1, bf0, 1);
        SCHED0;
        // s2: compute (kh1, mh0); prefetch (kh1, mh1)
        RD_A(af1, Ac, 1, 1);
        MM(af0, bf1, 0);
        WAIT_VM0;            // stage(t+1 -> other slot) retired
        BARRIER;             // B1: next tile visible
        // s3: compute (kh1, mh1); prefetch next tile (kh0) from other slot
        if (hasN) { RD_B(bf0, Bo, 0); RD_A(af0, Ao, 0, 0); }
        MM(af1, bf1, 1);
        BARRIER;             // B2: all waves done reading current slot
        if (hasNN) STAGE(Ac, Bc, t + 2);
        SCHED0;
        u16* tp;
        tp = Ac; Ac = Ao; Ao = tp;
        tp = Bc; Bc = Bo; Bo = tp;
    }

    // ---- epilogue: swizzled LDS repack -> coalesced stores
    const int crow0 = wr * (MF * 16), ccol0 = wc * (NF * 16);
#pragma unroll
    for (int m = 0; m < MF; ++m) {
        int rbase = crow0 + (m << 4) + ((lane >> 4) << 2);
#pragma unroll
        for (int n = 0; n < NF; ++n) {
            int col = ccol0 + (n << 4) + ln15;
            float bv = (MODE == 4) ? 0.f : bias[bcol + col];
#pragma unroll
            for (int r = 0; r < 4; ++r) {
                float v = acc[m][n][r] + bv;
                if (MODE == 2) v = v > 0.f ? v : 0.f;
                int row = rbase + r;
                SMEM[row * BN + (col ^ ((row & 7) << 3))] = f2b(v);
            }
        }
    }
    LGKM0;
    BARRIER;
    u16* outp = (MODE == 4) ? Pout : Cb;
    constexpr int CHT = BM * BN / 8 / T;
#pragma unroll
    for (int k = 0; k < CHT; ++k) {
        int c = tid + k * T;
        int row = c / (BN / 8), co = (c % (BN / 8)) * 8;
        u16x8 vv = *(const u16x8*)&SMEM[row * BN + (co ^ ((row & 7) << 3))];
        *(u16x8*)&outp[(long)(brow + row) * ldc + bcol + co] = vv;
        if (MODE == 1) {
            int cg = bcol + co;        // 8-chunks never straddle 1024-boundaries
            if (cg >= 1024) {
                int cc = cg - 1024;
                long kbase = (long)(cc >> 10) * 4194304 + (long)(brow + row) * 1024 + (cc & 1023);
                float4 f0 = { b2f(vv[0]), b2f(vv[1]), b2f(vv[2]), b2f(vv[3]) };
                float4 f1 = { b2f(vv[4]), b2f(vv[5]), b2f(vv[6]), b2f(vv[7]) };
                *(float4*)&KV[kbase] = f0;
                *(float4*)&KV[kbase + 4] = f1;
            }
        }
    }
#undef RD_A
#undef RD_B
#undef MM
}

// ---------------- K^T V partial sums (t-chunked, f32 atomics) ----------------
__global__ __launch_bounds__(256) void ktv_partial(const u16* __restrict__ QKVB,
                                                   float* __restrict__ KTVF) {
    __shared__ __align__(16) u16 Ks[64 * 64];
    __shared__ __align__(16) u16 Vs[64 * 64];
    int tid = threadIdx.x;
    int tc = blockIdx.x, bh = blockIdx.y;
    int b = bh >> 4, h = bh & 15;
    int j = tid & 63, i0 = (tid >> 6) * 16;
    float acc[16] = {};
    for (int st = 0; st < 4; ++st) {
        int t0 = tc * 256 + st * 64;
        __syncthreads();
#pragma unroll
        for (int i = 0; i < 2; ++i) {
            int c = i * 256 + tid;
            long base = (long)(b * 2048 + t0 + (c >> 3)) * 3072 + h * 64 + (c & 7) * 8;
            *(u16x8*)&Ks[c * 8] = *(const u16x8*)&QKVB[base + 1024];
            *(u16x8*)&Vs[c * 8] = *(const u16x8*)&QKVB[base + 2048];
        }
        __syncthreads();
        for (int tt = 0; tt < 64; ++tt) {
            float vj = b2f(Vs[tt * 64 + j]);
            u16x8 k0 = *(const u16x8*)&Ks[tt * 64 + i0];
            u16x8 k1 = *(const u16x8*)&Ks[tt * 64 + i0 + 8];
#pragma unroll
            for (int r = 0; r < 8; ++r) acc[r] += b2f(k0[r]) * vj;
#pragma unroll
            for (int r = 0; r < 8; ++r) acc[r + 8] += b2f(k1[r]) * vj;
        }
    }
#pragma unroll
    for (int r = 0; r < 16; ++r)
        atomicAdd(&KTVF[bh * 4096 + (i0 + r) * 64 + j], acc[r]);
}

// KTVT[bh][n][k] = KTVF[bh][k][n] * 0.125 (fold 1/sqrt(64))
__global__ __launch_bounds__(256) void cast_ktv(const float* __restrict__ KTVF,
                                                u16* __restrict__ KTVT) {
    int idx = blockIdx.x * 256 + threadIdx.x;   // < 32*4096
    int bh = idx >> 12, r = idx & 4095;
    int n = r >> 6, k = r & 63;
    KTVT[idx] = f2b(KTVF[bh * 4096 + k * 64 + n] * 0.125f);
}

// ---------------- batched attn GEMM: cat[t, h*64+e'] = Q[t,:] @ KTVT[e',:] -------
__global__ __launch_bounds__(256) void attn_gemm(const u16* __restrict__ QKVB,
                                                 const u16* __restrict__ KTVT,
                                                 u16* __restrict__ cat) {
    __shared__ __align__(16) u16 Qs[64 * 64];
    __shared__ __align__(16) u16 Bs[64 * 64];
    int tid = threadIdx.x, wid = tid >> 6, lane = tid & 63;
    int rt = blockIdx.x, bh = blockIdx.y;
    int b = bh >> 4, h = bh & 15;
    long qbase = (long)(b * 2048 + rt * 64) * 3072 + h * 64;
#pragma unroll
    for (int i = 0; i < 2; ++i) {
        int c = i * 256 + tid;
        gload_lds16(QKVB + qbase + (c >> 3) * 3072 + (c & 7) * 8, &Qs[(i * 256 + wid * 64) * 8]);
        gload_lds16(KTVT + bh * 4096 + c * 8, &Bs[(i * 256 + wid * 64) * 8]);
    }
    __syncthreads();
    f32x4 acc[4] = {};
#pragma unroll
    for (int kk = 0; kk < 2; ++kk) {
        bf16x8 a = lds_frag(&Qs[(wid * 16 + (lane & 15)) * 64 + kk * 32 + (lane >> 4) * 8]);
#pragma unroll
        for (int n = 0; n < 4; ++n) {
            bf16x8 bb = lds_frag(&Bs[(n * 16 + (lane & 15)) * 64 + kk * 32 + (lane >> 4) * 8]);
            acc[n] = __builtin_amdgcn_mfma_f32_16x16x32_bf16(a, bb, acc[n], 0, 0, 0);
        }
    }
#pragma unroll
    for (int n = 0; n < 4; ++n)
#pragma unroll
        for (int r = 0; r < 4; ++r) {
            int row = rt * 64 + wid * 16 + (lane >> 4) * 4 + r;
            int col = h * 64 + n * 16 + (lane & 15);
            cat[(long)(b * 2048 + row) * 1024 + col] = f2b(acc[n][r]);
        }
}

// ---------------- layernorm kernels ----------------
__device__ __forceinline__ void block_reduce2(float& a, float& b) {
    __syncthreads();
#pragma unroll
    for (int off = 32; off; off >>= 1) {
        a += __shfl_down(a, off);
        b += __shfl_down(b, off);
    }
    __shared__ float sa[4], sb[4];
    int wid = threadIdx.x >> 6, lane = threadIdx.x & 63;
    if (lane == 0) { sa[wid] = a; sb[wid] = b; }
    __syncthreads();
    a = sa[0] + sa[1] + sa[2] + sa[3];
    b = sb[0] + sb[1] + sb[2] + sb[3];
}

// out1 = LN(x + (q0+q1 + bp)) ; write f32 + bf16  (q* = bf16 partials)
__global__ __launch_bounds__(256) void ln1_kernel(
    const float* __restrict__ x,
    const u16* __restrict__ q0, const u16* __restrict__ q1,
    const float* __restrict__ bp,
    const float* __restrict__ g, const float* __restrict__ bt,
    float* __restrict__ out1f, u16* __restrict__ out1b) {
    int row = blockIdx.x, tid = threadIdx.x;
    long base = (long)row * 1024 + tid * 4;
    float4 xv = *(const float4*)&x[base];
    u16x4 a0 = *(const u16x4*)&q0[base];
    u16x4 a1 = *(const u16x4*)&q1[base];
    float4 bb = *(const float4*)&bp[tid * 4];
    float xa[4] = { xv.x, xv.y, xv.z, xv.w };
    float bba[4] = { bb.x, bb.y, bb.z, bb.w };
    float s[4];
#pragma unroll
    for (int r = 0; r < 4; ++r)
        s[r] = xa[r] + b2f(a0[r]) + b2f(a1[r]) + bba[r];
    float sum = s[0] + s[1] + s[2] + s[3];
    float sq = s[0] * s[0] + s[1] * s[1] + s[2] * s[2] + s[3] * s[3];
    block_reduce2(sum, sq);
    float mu = sum * (1.f / 1024.f);
    float var = sq * (1.f / 1024.f) - mu * mu;
    float rs = rsqrtf(var + 1e-5f);
    float o0 = (s[0] - mu) * rs * g[tid * 4 + 0] + bt[tid * 4 + 0];
    float o1 = (s[1] - mu) * rs * g[tid * 4 + 1] + bt[tid * 4 + 1];
    float o2 = (s[2] - mu) * rs * g[tid * 4 + 2] + bt[tid * 4 + 2];
    float o3 = (s[3] - mu) * rs * g[tid * 4 + 3] + bt[tid * 4 + 3];
    float4 of; of.x = o0; of.y = o1; of.z = o2; of.w = o3;
    u16x4 ob = (u16x4){ f2b(o0), f2b(o1), f2b(o2), f2b(o3) };
    *(float4*)&out1f[base] = of;
    *(u16x4*)&out1b[base] = ob;
}

// ff = (q0+q1)+b2 (bf16 partials); ffo = LN(out1+ff); out2 = LN(out1+ffo)
__global__ __launch_bounds__(256) void lnf_kernel(
    const float* __restrict__ out1f,
    const u16* __restrict__ q0, const u16* __restrict__ q1,
    const float* __restrict__ b2,
    const float* __restrict__ lnfg, const float* __restrict__ lnfb,
    const float* __restrict__ ln2g, const float* __restrict__ ln2b,
    float* __restrict__ out2) {
    int row = blockIdx.x, tid = threadIdx.x;
    long base = (long)row * 1024 + tid * 4;
    float4 o1 = *(const float4*)&out1f[base];
    u16x4 a0 = *(const u16x4*)&q0[base];
    u16x4 a1 = *(const u16x4*)&q1[base];
    float4 bb = *(const float4*)&b2[tid * 4];
    float o1a[4] = { o1.x, o1.y, o1.z, o1.w };
    float bba[4] = { bb.x, bb.y, bb.z, bb.w };
    float s1[4];
#pragma unroll
    for (int r = 0; r < 4; ++r)
        s1[r] = o1a[r] + b2f(a0[r]) + b2f(a1[r]) + bba[r];
    float sum = s1[0] + s1[1] + s1[2] + s1[3];
    float sq = s1[0] * s1[0] + s1[1] * s1[1] + s1[2] * s1[2] + s1[3] * s1[3];
    block_reduce2(sum, sq);
    float mu = sum * (1.f / 1024.f);
    float rs = rsqrtf(sq * (1.f / 1024.f) - mu * mu + 1e-5f);
    float s2[4];
#pragma unroll
    for (int r = 0; r < 4; ++r) {
        float ffo = (s1[r] - mu) * rs * lnfg[tid * 4 + r] + lnfb[tid * 4 + r];
        s2[r] = o1a[r] + ffo;
    }
    float sum2 = s2[0] + s2[1] + s2[2] + s2[3];
    float sq2 = s2[0] * s2[0] + s2[1] * s2[1] + s2[2] * s2[2] + s2[3] * s2[3];
    block_reduce2(sum2, sq2);
    float mu2 = sum2 * (1.f / 1024.f);
    float rs2 = rsqrtf(sq2 * (1.f / 1024.f) - mu2 * mu2 + 1e-5f);
    float4 o;
    o.x = (s2[0] - mu2) * rs2 * ln2g[tid * 4 + 0] + ln2b[tid * 4 + 0];
    o.y = (s2[1] - mu2) * rs2 * ln2g[tid * 4 + 1] + ln2b[tid * 4 + 1];
    o.z = (s2[2] - mu2) * rs2 * ln2g[tid * 4 + 2] + ln2b[tid * 4 + 2];
    o.w = (s2[3] - mu2) * rs2 * ln2g[tid * 4 + 3] + ln2b[tid * 4 + 3];
    *(float4*)&out2[base] = o;
}

// ---------------- launcher ----------------
extern "C" void kernel_launch(void* const* d_in, const int* in_sizes, int n_in,
                              void* d_out, int out_size, void* d_ws, size_t ws_size,
                              hipStream_t stream) {
    const float* x    = (const float*)d_in[0];
    const float* wq   = (const float*)d_in[1];
    const float* bq   = (const float*)d_in[2];
    const float* wk   = (const float*)d_in[3];
    const float* bk   = (const float*)d_in[4];
    const float* wv   = (const float*)d_in[5];
    const float* bv   = (const float*)d_in[6];
    const float* wp   = (const float*)d_in[7];
    const float* bp   = (const float*)d_in[8];
    const float* w1   = (const float*)d_in[9];
    const float* b1   = (const float*)d_in[10];
    const float* w2   = (const float*)d_in[11];
    const float* b2   = (const float*)d_in[12];
    const float* ln1g = (const float*)d_in[13];
    const float* ln1b = (const float*)d_in[14];
    const float* lnfg = (const float*)d_in[15];
    const float* lnfb = (const float*)d_in[16];
    const float* ln2g = (const float*)d_in[17];
    const float* ln2b = (const float*)d_in[18];

    float* out2 = (float*)d_out;
    float* kv   = (float*)d_out + 4194304;   // Kc then Vc

    // workspace layout (bytes). Liveness:
    char* ws = (char*)d_ws;
    u16*   XB     = (u16*)  (ws + 0);          // 8 MB (dead after G1); CAT (dead after G3); Q5_0
    u16*   CAT    = XB;
    u16*   WQKVT  = (u16*)  (ws + 8388608);    // 6.3 MB (dead after G1)
    float* BQKV   = (float*)(ws + 14680064);   // 12 KB (dead after G1)
    u16*   WPT    = (u16*)  (ws + 14692352);   // 2 MB (dead after G3)
    u16*   W1T    = (u16*)  (ws + 16789504);   // 8 MB (dead after G4)
    u16*   W2T    = (u16*)  (ws + 25178112);   // 8 MB (live through G5)
    float* KTVF   = (float*)(ws + 33566720);   // 512 KB
    u16*   KTVT   = (u16*)  (ws + 34091008);   // 256 KB
    u16*   QKVB   = (u16*)  (ws + 34353152);   // 24 MB (dead after attn); OUT1B
    u16*   OUT1B  = QKVB;
    u16*   Q3_0   = (u16*)  (ws + 59518976);   // 8 MB (dead after ln1)
    u16*   Q3_1   = (u16*)  (ws + 67907584);   // 8 MB (dead after ln1)
    float* OUT1F  = (float*)(ws + 76296192);   // 16 MB (live to lnf)
    u16*   H1     = (u16*)  (ws + 93073408);   // 32 MB (live through G5)
    u16*   Q5_0   = (u16*)  (ws + 0);          // 8 MB (over XB/CAT, dead after G3)
    u16*   Q5_1   = (u16*)  (ws + 34353152);   // 8 MB (over OUT1B, dead after G4)
    (void)ws_size; (void)in_sizes; (void)n_in; (void)out_size;

    hipMemsetAsync(KTVF, 0, 32 * 4096 * 4, stream);
    cast_x_kernel<<<4096, 256, 0, stream>>>(x, XB);
    tr_wqkv<<<dim3(32, 2, 48), 256, 0, stream>>>(wq, wk, wv, WQKVT);
    transpose_cast3<<<9228, 256, 0, stream>>>(wp, w1, w2, bq, bk, bv,
                                              WPT, W1T, W2T, BQKV);

    // G1: QKV = X @ Wqkv + b  (128x384 tile, grid 256, col-outer; f32 KV side-out)
    gemmT<1, 2, 4, 4, 6, true><<<256, 512, 0, stream>>>(
        XB, WQKVT, BQKV, QKVB, kv, nullptr, nullptr,
        4096, 3072, 1024, 1024, 1024, 3072, 0);
    ktv_partial<<<dim3(8, 32), 256, 0, stream>>>(QKVB, KTVF);
    cast_ktv<<<512, 256, 0, stream>>>(KTVF, KTVT);
    attn_gemm<<<dim3(32, 32), 256, 0, stream>>>(QKVB, KTVT, CAT);

    // G3: out = cat @ wp (128x128 tile, split-K x2, 512 blocks, row-outer)
    gemmT<4, 2, 2, 4, 4, false><<<512, 256, 0, stream>>>(
        CAT, WPT, nullptr, nullptr, nullptr, Q3_0, Q3_1,
        4096, 1024, 1024, 1024, 1024, 1024, 512);
    ln1_kernel<<<4096, 256, 0, stream>>>(x, Q3_0, Q3_1, bp, ln1g, ln1b, OUT1F, OUT1B);

    // G4: h1 = relu(out1 @ w1 + b1) (128x128 tile, grid 1024, 2 blocks/CU, row-outer)
    gemmT<2, 2, 2, 4, 4, false><<<1024, 256, 0, stream>>>(
        OUT1B, W1T, b1, H1, nullptr, nullptr, nullptr,
        4096, 4096, 1024, 1024, 1024, 4096, 0);
    // G5: ff = h1 @ w2 (128x128 tile, split-K x2 over K=4096, 512 blocks, row-outer)
    gemmT<4, 2, 2, 4, 4, false><<<512, 256, 0, stream>>>(
        H1, W2T, nullptr, nullptr, nullptr, Q5_0, Q5_1,
        4096, 1024, 4096, 4096, 4096, 1024, 2048);
    lnf_kernel<<<4096, 256, 0, stream>>>(OUT1F, Q5_0, Q5_1, b2,
                                         lnfg, lnfb, ln2g, ln2b, out2);
}

// Round 10
// 205.013 us; speedup vs baseline: 1.0889x; 1.0125x over previous
//
#include <hip/hip_runtime.h>

typedef unsigned short u16;
typedef __attribute__((ext_vector_type(4))) float f32x4;
typedef __attribute__((ext_vector_type(8))) __bf16 bf16x8;
typedef __attribute__((ext_vector_type(8))) unsigned short u16x8;
typedef __attribute__((ext_vector_type(4))) unsigned short u16x4;

// ---------- scalar bf16 helpers ----------
__device__ __forceinline__ u16 f2b(float f) {
    unsigned int u = __builtin_bit_cast(unsigned int, f);
    u = (u + 0x7FFFu + ((u >> 16) & 1u)) >> 16;
    return (u16)u;
}
__device__ __forceinline__ float b2f(u16 h) {
    unsigned int u = ((unsigned int)h) << 16;
    return __builtin_bit_cast(float, u);
}

// async global->LDS, 16B per lane; LDS dest is wave-uniform base (+lane*16 by HW)
__device__ __forceinline__ void gload_lds16(const u16* g, u16* l) {
    __builtin_amdgcn_global_load_lds(
        (const __attribute__((address_space(1))) void*)g,
        (__attribute__((address_space(3))) void*)l,
        16, 0, 0);
}

__device__ __forceinline__ bf16x8 lds_frag(const u16* p) {
    u16x8 t = *(const u16x8*)p;
    return __builtin_bit_cast(bf16x8, t);
}

#define FENCE asm volatile("" ::: "memory")
#define BARRIER do { FENCE; __builtin_amdgcn_s_barrier(); FENCE; \
                     __builtin_amdgcn_sched_barrier(0); } while (0)
#define SCHED0 __builtin_amdgcn_sched_barrier(0)
#define LGKM0 do { asm volatile("s_waitcnt lgkmcnt(0)" ::: "memory"); \
                   __builtin_amdgcn_sched_barrier(0); } while (0)
#define WAIT_VM8 do { asm volatile("s_waitcnt vmcnt(8)" ::: "memory"); \
                      __builtin_amdgcn_sched_barrier(0); } while (0)
#define WAIT_VM0 do { asm volatile("s_waitcnt vmcnt(0)" ::: "memory"); \
                      __builtin_amdgcn_sched_barrier(0); } while (0)

// ---------------- prep kernels ----------------
__global__ __launch_bounds__(256) void cast_x_kernel(const float* __restrict__ in,
                                                     u16* __restrict__ out) {
    int i = (blockIdx.x * 256 + threadIdx.x) * 4;
    float4 v = *(const float4*)&in[i];
    u16x4 o = { f2b(v.x), f2b(v.y), f2b(v.z), f2b(v.w) };
    *(u16x4*)&out[i] = o;
}

// WT[(sel*1024 + h*64 + e)][d] = w_sel[h][d][e]  — LDS-tiled transpose
__global__ __launch_bounds__(256) void tr_wqkv(const float* __restrict__ wq,
                                               const float* __restrict__ wk,
                                               const float* __restrict__ wv,
                                               u16* __restrict__ WT) {
    __shared__ float tile[32][33];
    int z = blockIdx.z;                    // 0..47 = sel*16 + h
    int sel = z >> 4, h = z & 15;
    const float* w = (sel == 0) ? wq : (sel == 1) ? wk : wv;
    w += (long)h * 65536;                  // [1024][64]
    int tx = threadIdx.x & 31, ty = threadIdx.x >> 5;
    int d0 = blockIdx.x * 32, e0 = blockIdx.y * 32;
#pragma unroll
    for (int i = 0; i < 32; i += 8)
        tile[ty + i][tx] = w[(long)(d0 + ty + i) * 64 + e0 + tx];
    __syncthreads();
#pragma unroll
    for (int i = 0; i < 32; i += 8)
        WT[((long)(sel * 1024 + h * 64 + e0 + ty + i)) * 1024 + d0 + tx] = f2b(tile[tx][ty + i]);
}

// merged: wp/w1/w2 transposes (out[c][r] = bf16(in[r][c])) + QKV bias pack
__global__ __launch_bounds__(256) void transpose_cast3(
    const float* __restrict__ wp, const float* __restrict__ w1, const float* __restrict__ w2,
    const float* __restrict__ bq, const float* __restrict__ bk, const float* __restrict__ bv,
    u16* __restrict__ WPT, u16* __restrict__ W1T, u16* __restrict__ W2T,
    float* __restrict__ BI) {
    int bid = blockIdx.x;
    if (bid >= 9216) {   // bias pack: 12 blocks
        int i = (bid - 9216) * 256 + threadIdx.x;   // < 3072
        const float* b = (i < 1024) ? bq : (i < 2048) ? bk : bv;
        BI[i] = b[((i & 1023) >> 6) * 64 + (i & 63)];
        return;
    }
    const float* in; u16* out; int C, R, bx, by;
    if (bid < 1024)      { in = wp; out = WPT; R = 1024; C = 1024; bx = bid & 31;  by = bid >> 5; }
    else if (bid < 5120) { int b = bid - 1024; in = w1; out = W1T; R = 1024; C = 4096; bx = b & 127; by = b >> 7; }
    else                 { int b = bid - 5120; in = w2; out = W2T; R = 4096; C = 1024; bx = b & 31;  by = b >> 5; }
    __shared__ float tile[32][33];
    int tx = threadIdx.x & 31, ty = threadIdx.x >> 5;   // 32 x 8
    int r0 = by * 32, c0 = bx * 32;
#pragma unroll
    for (int i = 0; i < 32; i += 8)
        tile[ty + i][tx] = in[(long)(r0 + ty + i) * C + c0 + tx];
    __syncthreads();
#pragma unroll
    for (int i = 0; i < 32; i += 8)
        out[(long)(c0 + ty + i) * R + r0 + tx] = f2b(tile[tx][ty + i]);
}

// ---------------- templated tiled GEMM, sub-phase pipelined (LDS || MFMA) -----
// C[M,N] = A[M,K] @ BT[N,K]^T. Tile BM=WM*MF*16, BN=WN*NF*16, BK=64, T=WM*WN*64.
// MODE 1: +bias, bf16 out + f32 KV side-write for cols>=1024 (G1).
// MODE 2: +bias, relu (G4). MODE 4: 2-way split-K bf16 partials to Q0/Q1 (G5).
// MODE 5: MODE4 + batch-B: rows >= M/2 use BT2 = (const u16*)Cb (G3 batched wp).
// Pipeline (R7-proven): 4 sub-phases per K-tile; sub-phase s issues ds_reads for
// s+1 into the alternate register frag buffer, then MFMAs current frags; compiler
// emits progressive counted lgkmcnt. 2 barriers/tile; counted vmcnt only.
// LDS byte-swizzle col^=(row&7)<<4 via inverse-swizzled global src (rule #21).
// Epilogue: acc -> swizzled LDS repack -> coalesced u16x8 stores (+f32 KV for MODE 1).
template <int MODE, int WM, int WN, int MF, int NF, bool COLOUT>
__global__ __launch_bounds__(WM * WN * 64, 2) void gemmT(
    const u16* __restrict__ A, const u16* __restrict__ BT, const float* __restrict__ bias,
    u16* __restrict__ Cb, float* __restrict__ KV,
    u16* __restrict__ Q0, u16* __restrict__ Q1,
    int M, int N, int K, int lda, int ldb, int ldc, int kchunk) {
    constexpr int T   = WM * WN * 64;
    constexpr int BM  = WM * MF * 16;
    constexpr int BN  = WN * NF * 16;
    constexpr int RPI = T / 8;            // rows per gload instr
    constexpr int LA  = BM / RPI;         // gload instrs per A K-tile
    constexpr int LB  = BN / RPI;
    constexpr int EPI = T * 8;            // LDS elems per gload instr
    constexpr int MFH = MF / 2;
    constexpr int ASZ = BM * 64, BSZ = BN * 64;
    __shared__ __align__(16) u16 SMEM[2 * ASZ + 2 * BSZ];
    u16* As0 = SMEM;
    u16* As1 = SMEM + ASZ;
    u16* Bs0 = SMEM + 2 * ASZ;
    u16* Bs1 = SMEM + 2 * ASZ + BSZ;
    const int tid = threadIdx.x;
    const int lane = tid & 63;
    const int wid = tid >> 6;
    const int wr = wid / WN, wc = wid % WN;
    const int ntile = N / BN;
    const int mtile = M / BM;
    int bid = blockIdx.x;
    int kb = 0, ksz = K;
    u16* Pout = Q0;
    if (MODE == 4 || MODE == 5) {
        int tiles = mtile * ntile;
        int sk = bid / tiles; bid -= sk * tiles;
        kb = sk * kchunk;
        int rem = K - kb; ksz = rem < kchunk ? rem : kchunk;
        Pout = sk ? Q1 : Q0;
    }
    // XCD-chunked bijective swizzle (tile count multiple of 8)
    {
        int q = (mtile * ntile) >> 3;
        bid = (bid & 7) * q + (bid >> 3);
    }
    int bi, bj;
    if (COLOUT) { bj = bid / mtile; bi = bid % mtile; }   // XCD owns B col-panels (G1)
    else        { bi = bid / ntile; bj = bid % ntile; }   // XCD owns A row-panels
    const int brow = bi * BM, bcol = bj * BN;
    const int nt = ksz >> 6;              // BK=64 tiles
    const u16* BTe = BT;
    if (MODE == 5 && brow >= (M >> 1)) BTe = (const u16*)Cb;   // batch-1 B panel

    // ---- staging addressing (inverse-swizzled global source, linear LDS dest)
    const int srow = tid >> 3;
    const int scol = ((tid & 7) ^ (srow & 7)) << 3;
    const u16* ag = A + (long)(brow + srow) * lda + kb + scol;
    const u16* bg = BTe + (long)(bcol + srow) * ldb + kb + scol;
    const long aI = (long)RPI * lda, bI = (long)RPI * ldb;
    const int sdst = tid << 3;

    auto STAGE = [&](u16* lA, u16* lB, int t) {
#pragma unroll
        for (int j = 0; j < LA; ++j)
            gload_lds16(ag + ((long)t << 6) + j * aI, &lA[j * EPI + sdst]);
#pragma unroll
        for (int j = 0; j < LB; ++j)
            gload_lds16(bg + ((long)t << 6) + j * bI, &lB[j * EPI + sdst]);
    };

    f32x4 acc[MF][NF] = {};
    bf16x8 af0[MFH], af1[MFH], bf0[NF], bf1[NF];

    // ---- fragment read addressing (swizzled)
    const int ln15 = lane & 15;
    const int eoff = (((lane >> 4) << 3) ^ ((lane & 7) << 3));
    const int arow0 = wr * (MF * 16) + ln15;
    const int brow0 = wc * (NF * 16) + ln15;

#define RD_A(dst, S, kh, mh)                                                   \
    _Pragma("unroll") for (int m4 = 0; m4 < MFH; ++m4)                         \
        dst[m4] = lds_frag(&(S)[((arow0 + (((mh) * MFH + m4) << 4)) << 6) +    \
                                (eoff ^ ((kh) << 5))]);
#define RD_B(dst, S, kh)                                                       \
    _Pragma("unroll") for (int n = 0; n < NF; ++n)                             \
        dst[n] = lds_frag(&(S)[((brow0 + (n << 4)) << 6) + (eoff ^ ((kh) << 5))]);
#define MM(a, b, mh) do {                                                      \
    __builtin_amdgcn_s_setprio(1);                                             \
    _Pragma("unroll") for (int m4 = 0; m4 < MFH; ++m4)                         \
        _Pragma("unroll") for (int n = 0; n < NF; ++n)                         \
            acc[(mh) * MFH + m4][n] = __builtin_amdgcn_mfma_f32_16x16x32_bf16( \
                a[m4], b[n], acc[(mh) * MFH + m4][n], 0, 0, 0);                \
    __builtin_amdgcn_s_setprio(0);                                             \
} while (0)

    // ---- prologue: stage t0 + t1; retire t0; initial frags
    STAGE(As0, Bs0, 0);
    if (nt > 1) { STAGE(As1, Bs1, 1); WAIT_VM8; } else { WAIT_VM0; }
    BARRIER;
    RD_B(bf0, Bs0, 0);
    RD_A(af0, As0, 0, 0);

    u16 *Ac = As0, *Bc = Bs0, *Ao = As1, *Bo = Bs1;
    for (int t = 0; t < nt; ++t) {
        const bool hasN = (t + 1 < nt);
        const bool hasNN = (t + 2 < nt);
        // s0: compute (kh0, mh0); prefetch (kh0, mh1)
        RD_A(af1, Ac, 0, 1);
        MM(af0, bf0, 0);
        SCHED0;
        // s1: compute (kh0, mh1); prefetch kh1 B + (kh1, mh0)
        RD_B(bf1, Bc, 1);
        RD_A(af0, Ac, 1, 0);
        MM(af1, bf0, 1);
        SCHED0;
        // s2: compute (kh1, mh0); prefetch (kh1, mh1)
        RD_A(af1, Ac, 1, 1);
        MM(af0, bf1, 0);
        WAIT_VM0;            // stage(t+1 -> other slot) retired
        BARRIER;             // B1: next tile visible
        // s3: compute (kh1, mh1); prefetch next tile (kh0) from other slot
        if (hasN) { RD_B(bf0, Bo, 0); RD_A(af0, Ao, 0, 0); }
        MM(af1, bf1, 1);
        BARRIER;             // B2: all waves done reading current slot
        if (hasNN) STAGE(Ac, Bc, t + 2);
        SCHED0;
        u16* tp;
        tp = Ac; Ac = Ao; Ao = tp;
        tp = Bc; Bc = Bo; Bo = tp;
    }

    // ---- epilogue: swizzled LDS repack -> coalesced stores
    const int crow0 = wr * (MF * 16), ccol0 = wc * (NF * 16);
#pragma unroll
    for (int m = 0; m < MF; ++m) {
        int rbase = crow0 + (m << 4) + ((lane >> 4) << 2);
#pragma unroll
        for (int n = 0; n < NF; ++n) {
            int col = ccol0 + (n << 4) + ln15;
            float bv = (MODE == 4 || MODE == 5) ? 0.f : bias[bcol + col];
#pragma unroll
            for (int r = 0; r < 4; ++r) {
                float v = acc[m][n][r] + bv;
                if (MODE == 2) v = v > 0.f ? v : 0.f;
                int row = rbase + r;
                SMEM[row * BN + (col ^ ((row & 7) << 3))] = f2b(v);
            }
        }
    }
    LGKM0;
    BARRIER;
    u16* outp = (MODE == 4 || MODE == 5) ? Pout : Cb;
    constexpr int CHT = BM * BN / 8 / T;
#pragma unroll
    for (int k = 0; k < CHT; ++k) {
        int c = tid + k * T;
        int row = c / (BN / 8), co = (c % (BN / 8)) * 8;
        u16x8 vv = *(const u16x8*)&SMEM[row * BN + (co ^ ((row & 7) << 3))];
        *(u16x8*)&outp[(long)(brow + row) * ldc + bcol + co] = vv;
        if (MODE == 1) {
            int cg = bcol + co;        // 8-chunks never straddle 1024-boundaries
            if (cg >= 1024) {
                int cc = cg - 1024;
                long kbase = (long)(cc >> 10) * 4194304 + (long)(brow + row) * 1024 + (cc & 1023);
                float4 f0 = { b2f(vv[0]), b2f(vv[1]), b2f(vv[2]), b2f(vv[3]) };
                float4 f1 = { b2f(vv[4]), b2f(vv[5]), b2f(vv[6]), b2f(vv[7]) };
                *(float4*)&KV[kbase] = f0;
                *(float4*)&KV[kbase + 4] = f1;
            }
        }
    }
#undef RD_A
#undef RD_B
#undef MM
}

// ---------------- K^T V partial sums (t-chunked, f32 atomics) ----------------
__global__ __launch_bounds__(256) void ktv_partial(const u16* __restrict__ QKVB,
                                                   float* __restrict__ KTVF) {
    __shared__ __align__(16) u16 Ks[64 * 64];
    __shared__ __align__(16) u16 Vs[64 * 64];
    int tid = threadIdx.x;
    int tc = blockIdx.x, bh = blockIdx.y;
    int b = bh >> 4, h = bh & 15;
    int j = tid & 63, i0 = (tid >> 6) * 16;
    float acc[16] = {};
    for (int st = 0; st < 4; ++st) {
        int t0 = tc * 256 + st * 64;
        __syncthreads();
#pragma unroll
        for (int i = 0; i < 2; ++i) {
            int c = i * 256 + tid;
            long base = (long)(b * 2048 + t0 + (c >> 3)) * 3072 + h * 64 + (c & 7) * 8;
            *(u16x8*)&Ks[c * 8] = *(const u16x8*)&QKVB[base + 1024];
            *(u16x8*)&Vs[c * 8] = *(const u16x8*)&QKVB[base + 2048];
        }
        __syncthreads();
        for (int tt = 0; tt < 64; ++tt) {
            float vj = b2f(Vs[tt * 64 + j]);
            u16x8 k0 = *(const u16x8*)&Ks[tt * 64 + i0];
            u16x8 k1 = *(const u16x8*)&Ks[tt * 64 + i0 + 8];
#pragma unroll
            for (int r = 0; r < 8; ++r) acc[r] += b2f(k0[r]) * vj;
#pragma unroll
            for (int r = 0; r < 8; ++r) acc[r + 8] += b2f(k1[r]) * vj;
        }
    }
#pragma unroll
    for (int r = 0; r < 16; ++r)
        atomicAdd(&KTVF[bh * 4096 + (i0 + r) * 64 + j], acc[r]);
}

// ---------------- fold KTV into wp: WPBT[b][j][h*64+e] = sum_e' KTV[bh][e][e']*0.125
//                  * wp[(h*64+e')][j]   (wp accessed via WPT[j][d])
// grid (4 j-tiles, 32 bh); 256 thr, 4 waves; per wave 64 j rows.
__global__ __launch_bounds__(256) void wpb_kernel(const float* __restrict__ KTVF,
                                                  const u16* __restrict__ WPT,
                                                  u16* __restrict__ WPBT) {
    __shared__ __align__(16) u16 Ks[64 * 72];   // padded rows (72) to break bank conflicts
    int tid = threadIdx.x, lane = tid & 63, w = tid >> 6;
    int jt = blockIdx.x, bh = blockIdx.y;
    int b = bh >> 4, h = bh & 15;
    const float* kt = KTVF + bh * 4096;
    {   // load + scale(0.125) + cast 16 f32/thread into padded LDS
        int idx = tid * 16;
        int e = idx >> 6, ep = idx & 63;
        float4 v0 = *(const float4*)&kt[idx];
        float4 v1 = *(const float4*)&kt[idx + 4];
        float4 v2 = *(const float4*)&kt[idx + 8];
        float4 v3 = *(const float4*)&kt[idx + 12];
        u16x8 o0 = { f2b(v0.x * 0.125f), f2b(v0.y * 0.125f), f2b(v0.z * 0.125f), f2b(v0.w * 0.125f),
                     f2b(v1.x * 0.125f), f2b(v1.y * 0.125f), f2b(v1.z * 0.125f), f2b(v1.w * 0.125f) };
        u16x8 o1 = { f2b(v2.x * 0.125f), f2b(v2.y * 0.125f), f2b(v2.z * 0.125f), f2b(v2.w * 0.125f),
                     f2b(v3.x * 0.125f), f2b(v3.y * 0.125f), f2b(v3.z * 0.125f), f2b(v3.w * 0.125f) };
        *(u16x8*)&Ks[e * 72 + ep] = o0;
        *(u16x8*)&Ks[e * 72 + ep + 8] = o1;
    }
    __syncthreads();
    int ln15 = lane & 15, l4 = lane >> 4;
    bf16x8 bf[4][2];
#pragma unroll
    for (int n = 0; n < 4; ++n)
#pragma unroll
        for (int kh = 0; kh < 2; ++kh)
            bf[n][kh] = lds_frag(&Ks[(n * 16 + ln15) * 72 + kh * 32 + l4 * 8]);
    int j0 = jt * 256 + w * 64;
    f32x4 acc[4][4] = {};
#pragma unroll
    for (int m = 0; m < 4; ++m) {
        const u16* ap = &WPT[(long)(j0 + m * 16 + ln15) * 1024 + h * 64 + l4 * 8];
        bf16x8 a0 = __builtin_bit_cast(bf16x8, *(const u16x8*)ap);
        bf16x8 a1 = __builtin_bit_cast(bf16x8, *(const u16x8*)(ap + 32));
#pragma unroll
        for (int n = 0; n < 4; ++n) {
            acc[m][n] = __builtin_amdgcn_mfma_f32_16x16x32_bf16(a0, bf[n][0], acc[m][n], 0, 0, 0);
            acc[m][n] = __builtin_amdgcn_mfma_f32_16x16x32_bf16(a1, bf[n][1], acc[m][n], 0, 0, 0);
        }
    }
#pragma unroll
    for (int m = 0; m < 4; ++m)
#pragma unroll
        for (int n = 0; n < 4; ++n)
#pragma unroll
            for (int r = 0; r < 4; ++r)
                WPBT[(long)b * 1048576 + (long)(j0 + m * 16 + l4 * 4 + r) * 1024 +
                     h * 64 + n * 16 + ln15] = f2b(acc[m][n][r]);
}

// ---------------- layernorm kernels ----------------
__device__ __forceinline__ void block_reduce2(float& a, float& b) {
    __syncthreads();
#pragma unroll
    for (int off = 32; off; off >>= 1) {
        a += __shfl_down(a, off);
        b += __shfl_down(b, off);
    }
    __shared__ float sa[4], sb[4];
    int wid = threadIdx.x >> 6, lane = threadIdx.x & 63;
    if (lane == 0) { sa[wid] = a; sb[wid] = b; }
    __syncthreads();
    a = sa[0] + sa[1] + sa[2] + sa[3];
    b = sb[0] + sb[1] + sb[2] + sb[3];
}

// out1 = LN(x + (q0+q1 + bp)) ; write f32 + bf16  (q* = bf16 partials)
__global__ __launch_bounds__(256) void ln1_kernel(
    const float* __restrict__ x,
    const u16* __restrict__ q0, const u16* __restrict__ q1,
    const float* __restrict__ bp,
    const float* __restrict__ g, const float* __restrict__ bt,
    float* __restrict__ out1f, u16* __restrict__ out1b) {
    int row = blockIdx.x, tid = threadIdx.x;
    long base = (long)row * 1024 + tid * 4;
    float4 xv = *(const float4*)&x[base];
    u16x4 a0 = *(const u16x4*)&q0[base];
    u16x4 a1 = *(const u16x4*)&q1[base];
    float4 bb = *(const float4*)&bp[tid * 4];
    float xa[4] = { xv.x, xv.y, xv.z, xv.w };
    float bba[4] = { bb.x, bb.y, bb.z, bb.w };
    float s[4];
#pragma unroll
    for (int r = 0; r < 4; ++r)
        s[r] = xa[r] + b2f(a0[r]) + b2f(a1[r]) + bba[r];
    float sum = s[0] + s[1] + s[2] + s[3];
    float sq = s[0] * s[0] + s[1] * s[1] + s[2] * s[2] + s[3] * s[3];
    block_reduce2(sum, sq);
    float mu = sum * (1.f / 1024.f);
    float var = sq * (1.f / 1024.f) - mu * mu;
    float rs = rsqrtf(var + 1e-5f);
    float o0 = (s[0] - mu) * rs * g[tid * 4 + 0] + bt[tid * 4 + 0];
    float o1 = (s[1] - mu) * rs * g[tid * 4 + 1] + bt[tid * 4 + 1];
    float o2 = (s[2] - mu) * rs * g[tid * 4 + 2] + bt[tid * 4 + 2];
    float o3 = (s[3] - mu) * rs * g[tid * 4 + 3] + bt[tid * 4 + 3];
    float4 of; of.x = o0; of.y = o1; of.z = o2; of.w = o3;
    u16x4 ob = (u16x4){ f2b(o0), f2b(o1), f2b(o2), f2b(o3) };
    *(float4*)&out1f[base] = of;
    *(u16x4*)&out1b[base] = ob;
}

// ff = (q0+q1)+b2 (bf16 partials); ffo = LN(out1+ff); out2 = LN(out1+ffo)
__global__ __launch_bounds__(256) void lnf_kernel(
    const float* __restrict__ out1f,
    const u16* __restrict__ q0, const u16* __restrict__ q1,
    const float* __restrict__ b2,
    const float* __restrict__ lnfg, const float* __restrict__ lnfb,
    const float* __restrict__ ln2g, const float* __restrict__ ln2b,
    float* __restrict__ out2) {
    int row = blockIdx.x, tid = threadIdx.x;
    long base = (long)row * 1024 + tid * 4;
    float4 o1 = *(const float4*)&out1f[base];
    u16x4 a0 = *(const u16x4*)&q0[base];
    u16x4 a1 = *(const u16x4*)&q1[base];
    float4 bb = *(const float4*)&b2[tid * 4];
    float o1a[4] = { o1.x, o1.y, o1.z, o1.w };
    float bba[4] = { bb.x, bb.y, bb.z, bb.w };
    float s1[4];
#pragma unroll
    for (int r = 0; r < 4; ++r)
        s1[r] = o1a[r] + b2f(a0[r]) + b2f(a1[r]) + bba[r];
    float sum = s1[0] + s1[1] + s1[2] + s1[3];
    float sq = s1[0] * s1[0] + s1[1] * s1[1] + s1[2] * s1[2] + s1[3] * s1[3];
    block_reduce2(sum, sq);
    float mu = sum * (1.f / 1024.f);
    float rs = rsqrtf(sq * (1.f / 1024.f) - mu * mu + 1e-5f);
    float s2[4];
#pragma unroll
    for (int r = 0; r < 4; ++r) {
        float ffo = (s1[r] - mu) * rs * lnfg[tid * 4 + r] + lnfb[tid * 4 + r];
        s2[r] = o1a[r] + ffo;
    }
    float sum2 = s2[0] + s2[1] + s2[2] + s2[3];
    float sq2 = s2[0] * s2[0] + s2[1] * s2[1] + s2[2] * s2[2] + s2[3] * s2[3];
    block_reduce2(sum2, sq2);
    float mu2 = sum2 * (1.f / 1024.f);
    float rs2 = rsqrtf(sq2 * (1.f / 1024.f) - mu2 * mu2 + 1e-5f);
    float4 o;
    o.x = (s2[0] - mu2) * rs2 * ln2g[tid * 4 + 0] + ln2b[tid * 4 + 0];
    o.y = (s2[1] - mu2) * rs2 * ln2g[tid * 4 + 1] + ln2b[tid * 4 + 1];
    o.z = (s2[2] - mu2) * rs2 * ln2g[tid * 4 + 2] + ln2b[tid * 4 + 2];
    o.w = (s2[3] - mu2) * rs2 * ln2g[tid * 4 + 3] + ln2b[tid * 4 + 3];
    *(float4*)&out2[base] = o;
}

// ---------------- launcher ----------------
extern "C" void kernel_launch(void* const* d_in, const int* in_sizes, int n_in,
                              void* d_out, int out_size, void* d_ws, size_t ws_size,
                              hipStream_t stream) {
    const float* x    = (const float*)d_in[0];
    const float* wq   = (const float*)d_in[1];
    const float* bq   = (const float*)d_in[2];
    const float* wk   = (const float*)d_in[3];
    const float* bk   = (const float*)d_in[4];
    const float* wv   = (const float*)d_in[5];
    const float* bv   = (const float*)d_in[6];
    const float* wp   = (const float*)d_in[7];
    const float* bp   = (const float*)d_in[8];
    const float* w1   = (const float*)d_in[9];
    const float* b1   = (const float*)d_in[10];
    const float* w2   = (const float*)d_in[11];
    const float* b2   = (const float*)d_in[12];
    const float* ln1g = (const float*)d_in[13];
    const float* ln1b = (const float*)d_in[14];
    const float* lnfg = (const float*)d_in[15];
    const float* lnfb = (const float*)d_in[16];
    const float* ln2g = (const float*)d_in[17];
    const float* ln2b = (const float*)d_in[18];

    float* out2 = (float*)d_out;
    float* kv   = (float*)d_out + 4194304;   // Kc then Vc

    // workspace layout (bytes). Liveness:
    char* ws = (char*)d_ws;
    u16*   XB     = (u16*)  (ws + 0);          // 8 MB (dead after G1); WPBT (dead after G3); Q5_0
    u16*   WPBT   = XB;                        // 4 MB: 2 batches x 1024x1024 bf16
    u16*   WQKVT  = (u16*)  (ws + 8388608);    // 6.3 MB (dead after G1)
    float* BQKV   = (float*)(ws + 14680064);   // 12 KB (dead after G1)
    u16*   WPT    = (u16*)  (ws + 14692352);   // 2 MB (dead after wpb)
    u16*   W1T    = (u16*)  (ws + 16789504);   // 8 MB (dead after G4)
    u16*   W2T    = (u16*)  (ws + 25178112);   // 8 MB (live through G5)
    float* KTVF   = (float*)(ws + 33566720);   // 512 KB (dead after wpb)
    u16*   QKVB   = (u16*)  (ws + 34353152);   // 24 MB (dead after G3); OUT1B
    u16*   OUT1B  = QKVB;
    u16*   Q3_0   = (u16*)  (ws + 59518976);   // 8 MB (dead after ln1)
    u16*   Q3_1   = (u16*)  (ws + 67907584);   // 8 MB (dead after ln1)
    float* OUT1F  = (float*)(ws + 76296192);   // 16 MB (live to lnf)
    u16*   H1     = (u16*)  (ws + 93073408);   // 32 MB (live through G5)
    u16*   Q5_0   = (u16*)  (ws + 0);          // 8 MB (over XB/WPBT, dead after G3)
    u16*   Q5_1   = (u16*)  (ws + 34353152);   // 8 MB (over OUT1B, dead after G4)
    (void)ws_size; (void)in_sizes; (void)n_in; (void)out_size;

    hipMemsetAsync(KTVF, 0, 32 * 4096 * 4, stream);
    cast_x_kernel<<<4096, 256, 0, stream>>>(x, XB);
    tr_wqkv<<<dim3(32, 2, 48), 256, 0, stream>>>(wq, wk, wv, WQKVT);
    transpose_cast3<<<9228, 256, 0, stream>>>(wp, w1, w2, bq, bk, bv,
                                              WPT, W1T, W2T, BQKV);

    // G1: QKV = X @ Wqkv + b  (128x384 tile, grid 256, col-outer; f32 KV side-out)
    gemmT<1, 2, 4, 4, 6, true><<<256, 512, 0, stream>>>(
        XB, WQKVT, BQKV, QKVB, kv, nullptr, nullptr,
        4096, 3072, 1024, 1024, 1024, 3072, 0);
    ktv_partial<<<dim3(8, 32), 256, 0, stream>>>(QKVB, KTVF);
    // fold (KTV*s) into wp per (b,h): WPBT[b] = block-stacked KTV_h @ wp_h
    wpb_kernel<<<dim3(4, 32), 256, 0, stream>>>(KTVF, WPT, WPBT);

    // G3: out[b] = Q[b] @ WPBT[b]  (A = QKVB Q-cols, lda=3072; batch-B by row half;
    //     128x128 tile, split-K x2, 512 blocks, row-outer)
    gemmT<5, 2, 2, 4, 4, false><<<512, 256, 0, stream>>>(
        QKVB, WPBT, nullptr, (u16*)(WPBT + 1048576), nullptr, Q3_0, Q3_1,
        4096, 1024, 1024, 3072, 1024, 1024, 512);
    ln1_kernel<<<4096, 256, 0, stream>>>(x, Q3_0, Q3_1, bp, ln1g, ln1b, OUT1F, OUT1B);

    // G4: h1 = relu(out1 @ w1 + b1) (128x128 tile, grid 1024, 2 blocks/CU, row-outer)
    gemmT<2, 2, 2, 4, 4, false><<<1024, 256, 0, stream>>>(
        OUT1B, W1T, b1, H1, nullptr, nullptr, nullptr,
        4096, 4096, 1024, 1024, 1024, 4096, 0);
    // G5: ff = h1 @ w2 (128x128 tile, split-K x2 over K=4096, 512 blocks, row-outer)
    gemmT<4, 2, 2, 4, 4, false><<<512, 256, 0, stream>>>(
        H1, W2T, nullptr, nullptr, nullptr, Q5_0, Q5_1,
        4096, 1024, 4096, 4096, 4096, 1024, 2048);
    lnf_kernel<<<4096, 256, 0, stream>>>(OUT1F, Q5_0, Q5_1, b2,
                                         lnfg, lnfb, ln2g, ln2b, out2);
}

// Round 11
// 196.533 us; speedup vs baseline: 1.1358x; 1.0432x over previous
//
#include <hip/hip_runtime.h>

typedef unsigned short u16;
typedef __attribute__((ext_vector_type(4))) float f32x4;
typedef __attribute__((ext_vector_type(8))) __bf16 bf16x8;
typedef __attribute__((ext_vector_type(8))) unsigned short u16x8;
typedef __attribute__((ext_vector_type(4))) unsigned short u16x4;

// ---------- scalar bf16 helpers ----------
__device__ __forceinline__ u16 f2b(float f) {
    unsigned int u = __builtin_bit_cast(unsigned int, f);
    u = (u + 0x7FFFu + ((u >> 16) & 1u)) >> 16;
    return (u16)u;
}
__device__ __forceinline__ float b2f(u16 h) {
    unsigned int u = ((unsigned int)h) << 16;
    return __builtin_bit_cast(float, u);
}

// async global->LDS, 16B per lane; LDS dest is wave-uniform base (+lane*16 by HW)
__device__ __forceinline__ void gload_lds16(const u16* g, u16* l) {
    __builtin_amdgcn_global_load_lds(
        (const __attribute__((address_space(1))) void*)g,
        (__attribute__((address_space(3))) void*)l,
        16, 0, 0);
}

__device__ __forceinline__ bf16x8 lds_frag(const u16* p) {
    u16x8 t = *(const u16x8*)p;
    return __builtin_bit_cast(bf16x8, t);
}

#define FENCE asm volatile("" ::: "memory")
#define BARRIER do { FENCE; __builtin_amdgcn_s_barrier(); FENCE; \
                     __builtin_amdgcn_sched_barrier(0); } while (0)
#define SCHED0 __builtin_amdgcn_sched_barrier(0)
#define LGKM0 do { asm volatile("s_waitcnt lgkmcnt(0)" ::: "memory"); \
                   __builtin_amdgcn_sched_barrier(0); } while (0)
#define WAIT_VM8 do { asm volatile("s_waitcnt vmcnt(8)" ::: "memory"); \
                      __builtin_amdgcn_sched_barrier(0); } while (0)
#define WAIT_VM0 do { asm volatile("s_waitcnt vmcnt(0)" ::: "memory"); \
                      __builtin_amdgcn_sched_barrier(0); } while (0)

// ---------------- prep kernels ----------------
__global__ __launch_bounds__(256) void cast_x_kernel(const float* __restrict__ in,
                                                     u16* __restrict__ out) {
    int i = (blockIdx.x * 256 + threadIdx.x) * 4;
    float4 v = *(const float4*)&in[i];
    u16x4 o = { f2b(v.x), f2b(v.y), f2b(v.z), f2b(v.w) };
    *(u16x4*)&out[i] = o;
}

// WT[(sel*1024 + h*64 + e)][d] = w_sel[h][d][e]  — LDS-tiled transpose
__global__ __launch_bounds__(256) void tr_wqkv(const float* __restrict__ wq,
                                               const float* __restrict__ wk,
                                               const float* __restrict__ wv,
                                               u16* __restrict__ WT) {
    __shared__ float tile[32][33];
    int z = blockIdx.z;                    // 0..47 = sel*16 + h
    int sel = z >> 4, h = z & 15;
    const float* w = (sel == 0) ? wq : (sel == 1) ? wk : wv;
    w += (long)h * 65536;                  // [1024][64]
    int tx = threadIdx.x & 31, ty = threadIdx.x >> 5;
    int d0 = blockIdx.x * 32, e0 = blockIdx.y * 32;
#pragma unroll
    for (int i = 0; i < 32; i += 8)
        tile[ty + i][tx] = w[(long)(d0 + ty + i) * 64 + e0 + tx];
    __syncthreads();
#pragma unroll
    for (int i = 0; i < 32; i += 8)
        WT[((long)(sel * 1024 + h * 64 + e0 + ty + i)) * 1024 + d0 + tx] = f2b(tile[tx][ty + i]);
}

// merged: wp/w1/w2 transposes (out[c][r] = bf16(in[r][c])) + QKV bias pack
__global__ __launch_bounds__(256) void transpose_cast3(
    const float* __restrict__ wp, const float* __restrict__ w1, const float* __restrict__ w2,
    const float* __restrict__ bq, const float* __restrict__ bk, const float* __restrict__ bv,
    u16* __restrict__ WPT, u16* __restrict__ W1T, u16* __restrict__ W2T,
    float* __restrict__ BI) {
    int bid = blockIdx.x;
    if (bid >= 9216) {   // bias pack: 12 blocks
        int i = (bid - 9216) * 256 + threadIdx.x;   // < 3072
        const float* b = (i < 1024) ? bq : (i < 2048) ? bk : bv;
        BI[i] = b[((i & 1023) >> 6) * 64 + (i & 63)];
        return;
    }
    const float* in; u16* out; int C, R, bx, by;
    if (bid < 1024)      { in = wp; out = WPT; R = 1024; C = 1024; bx = bid & 31;  by = bid >> 5; }
    else if (bid < 5120) { int b = bid - 1024; in = w1; out = W1T; R = 1024; C = 4096; bx = b & 127; by = b >> 7; }
    else                 { int b = bid - 5120; in = w2; out = W2T; R = 4096; C = 1024; bx = b & 31;  by = b >> 5; }
    __shared__ float tile[32][33];
    int tx = threadIdx.x & 31, ty = threadIdx.x >> 5;   // 32 x 8
    int r0 = by * 32, c0 = bx * 32;
#pragma unroll
    for (int i = 0; i < 32; i += 8)
        tile[ty + i][tx] = in[(long)(r0 + ty + i) * C + c0 + tx];
    __syncthreads();
#pragma unroll
    for (int i = 0; i < 32; i += 8)
        out[(long)(c0 + ty + i) * R + r0 + tx] = f2b(tile[tx][ty + i]);
}

// ---------------- templated tiled GEMM, sub-phase pipelined (LDS || MFMA) -----
// C[M,N] = A[M,K] @ BT[N,K]^T. Tile BM=WM*MF*16, BN=WN*NF*16, BK=64, T=WM*WN*64.
// MODE 1: +bias, bf16 out + f32 KV side-write for cols>=1024 (G1).
// MODE 2: +bias, relu (G4). MODE 4: 2-way split-K bf16 partials to Q0/Q1 (G5).
// MODE 5: MODE4 + batch-B: rows >= M/2 use BT2 = (const u16*)Cb (G3 batched wp).
// Pipeline (R7-proven): 4 sub-phases per K-tile; sub-phase s issues ds_reads for
// s+1 into the alternate register frag buffer, then MFMAs current frags; compiler
// emits progressive counted lgkmcnt. 2 barriers/tile; counted vmcnt only.
// LDS byte-swizzle col^=(row&7)<<4 via inverse-swizzled global src (rule #21).
// Epilogue: acc -> swizzled LDS repack -> coalesced u16x8 stores (+f32 KV for MODE 1).
template <int MODE, int WM, int WN, int MF, int NF, bool COLOUT>
__global__ __launch_bounds__(WM * WN * 64, 2) void gemmT(
    const u16* __restrict__ A, const u16* __restrict__ BT, const float* __restrict__ bias,
    u16* __restrict__ Cb, float* __restrict__ KV,
    u16* __restrict__ Q0, u16* __restrict__ Q1,
    int M, int N, int K, int lda, int ldb, int ldc, int kchunk) {
    constexpr int T   = WM * WN * 64;
    constexpr int BM  = WM * MF * 16;
    constexpr int BN  = WN * NF * 16;
    constexpr int RPI = T / 8;            // rows per gload instr
    constexpr int LA  = BM / RPI;         // gload instrs per A K-tile
    constexpr int LB  = BN / RPI;
    constexpr int EPI = T * 8;            // LDS elems per gload instr
    constexpr int MFH = MF / 2;
    constexpr int ASZ = BM * 64, BSZ = BN * 64;
    __shared__ __align__(16) u16 SMEM[2 * ASZ + 2 * BSZ];
    u16* As0 = SMEM;
    u16* As1 = SMEM + ASZ;
    u16* Bs0 = SMEM + 2 * ASZ;
    u16* Bs1 = SMEM + 2 * ASZ + BSZ;
    const int tid = threadIdx.x;
    const int lane = tid & 63;
    const int wid = tid >> 6;
    const int wr = wid / WN, wc = wid % WN;
    const int ntile = N / BN;
    const int mtile = M / BM;
    int bid = blockIdx.x;
    int kb = 0, ksz = K;
    u16* Pout = Q0;
    if (MODE == 4 || MODE == 5) {
        int tiles = mtile * ntile;
        int sk = bid / tiles; bid -= sk * tiles;
        kb = sk * kchunk;
        int rem = K - kb; ksz = rem < kchunk ? rem : kchunk;
        Pout = sk ? Q1 : Q0;
    }
    // XCD-chunked bijective swizzle (tile count multiple of 8)
    {
        int q = (mtile * ntile) >> 3;
        bid = (bid & 7) * q + (bid >> 3);
    }
    int bi, bj;
    if (COLOUT) { bj = bid / mtile; bi = bid % mtile; }   // XCD owns B col-panels (G1)
    else        { bi = bid / ntile; bj = bid % ntile; }   // XCD owns A row-panels
    const int brow = bi * BM, bcol = bj * BN;
    const int nt = ksz >> 6;              // BK=64 tiles
    const u16* BTe = BT;
    if (MODE == 5 && brow >= (M >> 1)) BTe = (const u16*)Cb;   // batch-1 B panel

    // ---- staging addressing (inverse-swizzled global source, linear LDS dest)
    const int srow = tid >> 3;
    const int scol = ((tid & 7) ^ (srow & 7)) << 3;
    const u16* ag = A + (long)(brow + srow) * lda + kb + scol;
    const u16* bg = BTe + (long)(bcol + srow) * ldb + kb + scol;
    const long aI = (long)RPI * lda, bI = (long)RPI * ldb;
    const int sdst = tid << 3;

    auto STAGE = [&](u16* lA, u16* lB, int t) {
#pragma unroll
        for (int j = 0; j < LA; ++j)
            gload_lds16(ag + ((long)t << 6) + j * aI, &lA[j * EPI + sdst]);
#pragma unroll
        for (int j = 0; j < LB; ++j)
            gload_lds16(bg + ((long)t << 6) + j * bI, &lB[j * EPI + sdst]);
    };

    f32x4 acc[MF][NF] = {};
    bf16x8 af0[MFH], af1[MFH], bf0[NF], bf1[NF];

    // ---- fragment read addressing (swizzled)
    const int ln15 = lane & 15;
    const int eoff = (((lane >> 4) << 3) ^ ((lane & 7) << 3));
    const int arow0 = wr * (MF * 16) + ln15;
    const int brow0 = wc * (NF * 16) + ln15;

#define RD_A(dst, S, kh, mh)                                                   \
    _Pragma("unroll") for (int m4 = 0; m4 < MFH; ++m4)                         \
        dst[m4] = lds_frag(&(S)[((arow0 + (((mh) * MFH + m4) << 4)) << 6) +    \
                                (eoff ^ ((kh) << 5))]);
#define RD_B(dst, S, kh)                                                       \
    _Pragma("unroll") for (int n = 0; n < NF; ++n)                             \
        dst[n] = lds_frag(&(S)[((brow0 + (n << 4)) << 6) + (eoff ^ ((kh) << 5))]);
#define MM(a, b, mh) do {                                                      \
    __builtin_amdgcn_s_setprio(1);                                             \
    _Pragma("unroll") for (int m4 = 0; m4 < MFH; ++m4)                         \
        _Pragma("unroll") for (int n = 0; n < NF; ++n)                         \
            acc[(mh) * MFH + m4][n] = __builtin_amdgcn_mfma_f32_16x16x32_bf16( \
                a[m4], b[n], acc[(mh) * MFH + m4][n], 0, 0, 0);                \
    __builtin_amdgcn_s_setprio(0);                                             \
} while (0)

    // ---- prologue: stage t0 + t1; retire t0; initial frags
    STAGE(As0, Bs0, 0);
    if (nt > 1) { STAGE(As1, Bs1, 1); WAIT_VM8; } else { WAIT_VM0; }
    BARRIER;
    RD_B(bf0, Bs0, 0);
    RD_A(af0, As0, 0, 0);

    u16 *Ac = As0, *Bc = Bs0, *Ao = As1, *Bo = Bs1;
    for (int t = 0; t < nt; ++t) {
        const bool hasN = (t + 1 < nt);
        const bool hasNN = (t + 2 < nt);
        // s0: compute (kh0, mh0); prefetch (kh0, mh1)
        RD_A(af1, Ac, 0, 1);
        MM(af0, bf0, 0);
        SCHED0;
        // s1: compute (kh0, mh1); prefetch kh1 B + (kh1, mh0)
        RD_B(bf1, Bc, 1);
        RD_A(af0, Ac, 1, 0);
        MM(af1, bf0, 1);
        SCHED0;
        // s2: compute (kh1, mh0); prefetch (kh1, mh1)
        RD_A(af1, Ac, 1, 1);
        MM(af0, bf1, 0);
        WAIT_VM0;            // stage(t+1 -> other slot) retired
        BARRIER;             // B1: next tile visible
        // s3: compute (kh1, mh1); prefetch next tile (kh0) from other slot
        if (hasN) { RD_B(bf0, Bo, 0); RD_A(af0, Ao, 0, 0); }
        MM(af1, bf1, 1);
        BARRIER;             // B2: all waves done reading current slot
        if (hasNN) STAGE(Ac, Bc, t + 2);
        SCHED0;
        u16* tp;
        tp = Ac; Ac = Ao; Ao = tp;
        tp = Bc; Bc = Bo; Bo = tp;
    }

    // ---- epilogue: swizzled LDS repack -> coalesced stores
    const int crow0 = wr * (MF * 16), ccol0 = wc * (NF * 16);
#pragma unroll
    for (int m = 0; m < MF; ++m) {
        int rbase = crow0 + (m << 4) + ((lane >> 4) << 2);
#pragma unroll
        for (int n = 0; n < NF; ++n) {
            int col = ccol0 + (n << 4) + ln15;
            float bv = (MODE == 4 || MODE == 5) ? 0.f : bias[bcol + col];
#pragma unroll
            for (int r = 0; r < 4; ++r) {
                float v = acc[m][n][r] + bv;
                if (MODE == 2) v = v > 0.f ? v : 0.f;
                int row = rbase + r;
                SMEM[row * BN + (col ^ ((row & 7) << 3))] = f2b(v);
            }
        }
    }
    LGKM0;
    BARRIER;
    u16* outp = (MODE == 4 || MODE == 5) ? Pout : Cb;
    constexpr int CHT = BM * BN / 8 / T;
#pragma unroll
    for (int k = 0; k < CHT; ++k) {
        int c = tid + k * T;
        int row = c / (BN / 8), co = (c % (BN / 8)) * 8;
        u16x8 vv = *(const u16x8*)&SMEM[row * BN + (co ^ ((row & 7) << 3))];
        *(u16x8*)&outp[(long)(brow + row) * ldc + bcol + co] = vv;
        if (MODE == 1) {
            int cg = bcol + co;        // 8-chunks never straddle 1024-boundaries
            if (cg >= 1024) {
                int cc = cg - 1024;
                long kbase = (long)(cc >> 10) * 4194304 + (long)(brow + row) * 1024 + (cc & 1023);
                float4 f0 = { b2f(vv[0]), b2f(vv[1]), b2f(vv[2]), b2f(vv[3]) };
                float4 f1 = { b2f(vv[4]), b2f(vv[5]), b2f(vv[6]), b2f(vv[7]) };
                *(float4*)&KV[kbase] = f0;
                *(float4*)&KV[kbase + 4] = f1;
            }
        }
    }
#undef RD_A
#undef RD_B
#undef MM
}

// ---------------- K^T V partial sums (t-chunked, f32 atomics) ----------------
// grid (16 tchunks of 128, 32 bh)
__global__ __launch_bounds__(256) void ktv_partial(const u16* __restrict__ QKVB,
                                                   float* __restrict__ KTVF) {
    __shared__ __align__(16) u16 Ks[64 * 64];
    __shared__ __align__(16) u16 Vs[64 * 64];
    int tid = threadIdx.x;
    int tc = blockIdx.x, bh = blockIdx.y;
    int b = bh >> 4, h = bh & 15;
    int j = tid & 63, i0 = (tid >> 6) * 16;
    float acc[16] = {};
    for (int st = 0; st < 2; ++st) {
        int t0 = tc * 128 + st * 64;
        __syncthreads();
#pragma unroll
        for (int i = 0; i < 2; ++i) {
            int c = i * 256 + tid;
            long base = (long)(b * 2048 + t0 + (c >> 3)) * 3072 + h * 64 + (c & 7) * 8;
            *(u16x8*)&Ks[c * 8] = *(const u16x8*)&QKVB[base + 1024];
            *(u16x8*)&Vs[c * 8] = *(const u16x8*)&QKVB[base + 2048];
        }
        __syncthreads();
        for (int tt = 0; tt < 64; ++tt) {
            float vj = b2f(Vs[tt * 64 + j]);
            u16x8 k0 = *(const u16x8*)&Ks[tt * 64 + i0];
            u16x8 k1 = *(const u16x8*)&Ks[tt * 64 + i0 + 8];
#pragma unroll
            for (int r = 0; r < 8; ++r) acc[r] += b2f(k0[r]) * vj;
#pragma unroll
            for (int r = 0; r < 8; ++r) acc[r + 8] += b2f(k1[r]) * vj;
        }
    }
#pragma unroll
    for (int r = 0; r < 16; ++r)
        atomicAdd(&KTVF[bh * 4096 + (i0 + r) * 64 + j], acc[r]);
}

// ---------------- fold KTV into wp: WPBT[b][j][h*64+e] = sum_e' KTV[bh][e][e']*0.125
//                  * wp[(h*64+e')][j]   (wp accessed via WPT[j][d])
// grid (4 j-tiles, 32 bh); 256 thr, 4 waves; per wave 64 j rows.
__global__ __launch_bounds__(256) void wpb_kernel(const float* __restrict__ KTVF,
                                                  const u16* __restrict__ WPT,
                                                  u16* __restrict__ WPBT) {
    __shared__ __align__(16) u16 Ks[64 * 72];   // padded rows (72) to break bank conflicts
    int tid = threadIdx.x, lane = tid & 63, w = tid >> 6;
    int jt = blockIdx.x, bh = blockIdx.y;
    int b = bh >> 4, h = bh & 15;
    const float* kt = KTVF + bh * 4096;
    {   // load + scale(0.125) + cast 16 f32/thread into padded LDS
        int idx = tid * 16;
        int e = idx >> 6, ep = idx & 63;
        float4 v0 = *(const float4*)&kt[idx];
        float4 v1 = *(const float4*)&kt[idx + 4];
        float4 v2 = *(const float4*)&kt[idx + 8];
        float4 v3 = *(const float4*)&kt[idx + 12];
        u16x8 o0 = { f2b(v0.x * 0.125f), f2b(v0.y * 0.125f), f2b(v0.z * 0.125f), f2b(v0.w * 0.125f),
                     f2b(v1.x * 0.125f), f2b(v1.y * 0.125f), f2b(v1.z * 0.125f), f2b(v1.w * 0.125f) };
        u16x8 o1 = { f2b(v2.x * 0.125f), f2b(v2.y * 0.125f), f2b(v2.z * 0.125f), f2b(v2.w * 0.125f),
                     f2b(v3.x * 0.125f), f2b(v3.y * 0.125f), f2b(v3.z * 0.125f), f2b(v3.w * 0.125f) };
        *(u16x8*)&Ks[e * 72 + ep] = o0;
        *(u16x8*)&Ks[e * 72 + ep + 8] = o1;
    }
    __syncthreads();
    int ln15 = lane & 15, l4 = lane >> 4;
    bf16x8 bf[4][2];
#pragma unroll
    for (int n = 0; n < 4; ++n)
#pragma unroll
        for (int kh = 0; kh < 2; ++kh)
            bf[n][kh] = lds_frag(&Ks[(n * 16 + ln15) * 72 + kh * 32 + l4 * 8]);
    int j0 = jt * 256 + w * 64;
    f32x4 acc[4][4] = {};
#pragma unroll
    for (int m = 0; m < 4; ++m) {
        const u16* ap = &WPT[(long)(j0 + m * 16 + ln15) * 1024 + h * 64 + l4 * 8];
        bf16x8 a0 = __builtin_bit_cast(bf16x8, *(const u16x8*)ap);
        bf16x8 a1 = __builtin_bit_cast(bf16x8, *(const u16x8*)(ap + 32));
#pragma unroll
        for (int n = 0; n < 4; ++n) {
            acc[m][n] = __builtin_amdgcn_mfma_f32_16x16x32_bf16(a0, bf[n][0], acc[m][n], 0, 0, 0);
            acc[m][n] = __builtin_amdgcn_mfma_f32_16x16x32_bf16(a1, bf[n][1], acc[m][n], 0, 0, 0);
        }
    }
#pragma unroll
    for (int m = 0; m < 4; ++m)
#pragma unroll
        for (int n = 0; n < 4; ++n)
#pragma unroll
            for (int r = 0; r < 4; ++r)
                WPBT[(long)b * 1048576 + (long)(j0 + m * 16 + l4 * 4 + r) * 1024 +
                     h * 64 + n * 16 + ln15] = f2b(acc[m][n][r]);
}

// ---------------- layernorm kernels ----------------
__device__ __forceinline__ void block_reduce2(float& a, float& b) {
    __syncthreads();
#pragma unroll
    for (int off = 32; off; off >>= 1) {
        a += __shfl_down(a, off);
        b += __shfl_down(b, off);
    }
    __shared__ float sa[4], sb[4];
    int wid = threadIdx.x >> 6, lane = threadIdx.x & 63;
    if (lane == 0) { sa[wid] = a; sb[wid] = b; }
    __syncthreads();
    a = sa[0] + sa[1] + sa[2] + sa[3];
    b = sb[0] + sb[1] + sb[2] + sb[3];
}

// out1 = LN(x + (q0+q1 + bp)) ; write bf16 only  (q* = bf16 partials)
__global__ __launch_bounds__(256) void ln1_kernel(
    const float* __restrict__ x,
    const u16* __restrict__ q0, const u16* __restrict__ q1,
    const float* __restrict__ bp,
    const float* __restrict__ g, const float* __restrict__ bt,
    u16* __restrict__ out1b) {
    int row = blockIdx.x, tid = threadIdx.x;
    long base = (long)row * 1024 + tid * 4;
    float4 xv = *(const float4*)&x[base];
    u16x4 a0 = *(const u16x4*)&q0[base];
    u16x4 a1 = *(const u16x4*)&q1[base];
    float4 bb = *(const float4*)&bp[tid * 4];
    float xa[4] = { xv.x, xv.y, xv.z, xv.w };
    float bba[4] = { bb.x, bb.y, bb.z, bb.w };
    float s[4];
#pragma unroll
    for (int r = 0; r < 4; ++r)
        s[r] = xa[r] + b2f(a0[r]) + b2f(a1[r]) + bba[r];
    float sum = s[0] + s[1] + s[2] + s[3];
    float sq = s[0] * s[0] + s[1] * s[1] + s[2] * s[2] + s[3] * s[3];
    block_reduce2(sum, sq);
    float mu = sum * (1.f / 1024.f);
    float var = sq * (1.f / 1024.f) - mu * mu;
    float rs = rsqrtf(var + 1e-5f);
    float o0 = (s[0] - mu) * rs * g[tid * 4 + 0] + bt[tid * 4 + 0];
    float o1 = (s[1] - mu) * rs * g[tid * 4 + 1] + bt[tid * 4 + 1];
    float o2 = (s[2] - mu) * rs * g[tid * 4 + 2] + bt[tid * 4 + 2];
    float o3 = (s[3] - mu) * rs * g[tid * 4 + 3] + bt[tid * 4 + 3];
    u16x4 ob = (u16x4){ f2b(o0), f2b(o1), f2b(o2), f2b(o3) };
    *(u16x4*)&out1b[base] = ob;
}

// ff = (q0+q1)+b2 (bf16 partials); ffo = LN(out1+ff); out2 = LN(out1+ffo)
// out1 read as bf16 (out1b)
__global__ __launch_bounds__(256) void lnf_kernel(
    const u16* __restrict__ out1b,
    const u16* __restrict__ q0, const u16* __restrict__ q1,
    const float* __restrict__ b2,
    const float* __restrict__ lnfg, const float* __restrict__ lnfb,
    const float* __restrict__ ln2g, const float* __restrict__ ln2b,
    float* __restrict__ out2) {
    int row = blockIdx.x, tid = threadIdx.x;
    long base = (long)row * 1024 + tid * 4;
    u16x4 o1v = *(const u16x4*)&out1b[base];
    u16x4 a0 = *(const u16x4*)&q0[base];
    u16x4 a1 = *(const u16x4*)&q1[base];
    float4 bb = *(const float4*)&b2[tid * 4];
    float o1a[4] = { b2f(o1v[0]), b2f(o1v[1]), b2f(o1v[2]), b2f(o1v[3]) };
    float bba[4] = { bb.x, bb.y, bb.z, bb.w };
    float s1[4];
#pragma unroll
    for (int r = 0; r < 4; ++r)
        s1[r] = o1a[r] + b2f(a0[r]) + b2f(a1[r]) + bba[r];
    float sum = s1[0] + s1[1] + s1[2] + s1[3];
    float sq = s1[0] * s1[0] + s1[1] * s1[1] + s1[2] * s1[2] + s1[3] * s1[3];
    block_reduce2(sum, sq);
    float mu = sum * (1.f / 1024.f);
    float rs = rsqrtf(sq * (1.f / 1024.f) - mu * mu + 1e-5f);
    float s2[4];
#pragma unroll
    for (int r = 0; r < 4; ++r) {
        float ffo = (s1[r] - mu) * rs * lnfg[tid * 4 + r] + lnfb[tid * 4 + r];
        s2[r] = o1a[r] + ffo;
    }
    float sum2 = s2[0] + s2[1] + s2[2] + s2[3];
    float sq2 = s2[0] * s2[0] + s2[1] * s2[1] + s2[2] * s2[2] + s2[3] * s2[3];
    block_reduce2(sum2, sq2);
    float mu2 = sum2 * (1.f / 1024.f);
    float rs2 = rsqrtf(sq2 * (1.f / 1024.f) - mu2 * mu2 + 1e-5f);
    float4 o;
    o.x = (s2[0] - mu2) * rs2 * ln2g[tid * 4 + 0] + ln2b[tid * 4 + 0];
    o.y = (s2[1] - mu2) * rs2 * ln2g[tid * 4 + 1] + ln2b[tid * 4 + 1];
    o.z = (s2[2] - mu2) * rs2 * ln2g[tid * 4 + 2] + ln2b[tid * 4 + 2];
    o.w = (s2[3] - mu2) * rs2 * ln2g[tid * 4 + 3] + ln2b[tid * 4 + 3];
    *(float4*)&out2[base] = o;
}

// ---------------- launcher ----------------
extern "C" void kernel_launch(void* const* d_in, const int* in_sizes, int n_in,
                              void* d_out, int out_size, void* d_ws, size_t ws_size,
                              hipStream_t stream) {
    const float* x    = (const float*)d_in[0];
    const float* wq   = (const float*)d_in[1];
    const float* bq   = (const float*)d_in[2];
    const float* wk   = (const float*)d_in[3];
    const float* bk   = (const float*)d_in[4];
    const float* wv   = (const float*)d_in[5];
    const float* bv   = (const float*)d_in[6];
    const float* wp   = (const float*)d_in[7];
    const float* bp   = (const float*)d_in[8];
    const float* w1   = (const float*)d_in[9];
    const float* b1   = (const float*)d_in[10];
    const float* w2   = (const float*)d_in[11];
    const float* b2   = (const float*)d_in[12];
    const float* ln1g = (const float*)d_in[13];
    const float* ln1b = (const float*)d_in[14];
    const float* lnfg = (const float*)d_in[15];
    const float* lnfb = (const float*)d_in[16];
    const float* ln2g = (const float*)d_in[17];
    const float* ln2b = (const float*)d_in[18];

    float* out2 = (float*)d_out;
    float* kv   = (float*)d_out + 4194304;   // Kc then Vc

    // workspace layout (bytes). Liveness:
    char* ws = (char*)d_ws;
    u16*   XB     = (u16*)  (ws + 0);          // 8 MB (dead after G1); WPBT (dead after G3); Q5_0
    u16*   WPBT   = XB;                        // 4 MB: 2 batches x 1024x1024 bf16
    u16*   WQKVT  = (u16*)  (ws + 8388608);    // 6.3 MB (dead after G1)
    float* BQKV   = (float*)(ws + 14680064);   // 12 KB (dead after G1)
    u16*   WPT    = (u16*)  (ws + 14692352);   // 2 MB (dead after wpb)
    u16*   W1T    = (u16*)  (ws + 16789504);   // 8 MB (dead after G4)
    u16*   W2T    = (u16*)  (ws + 25178112);   // 8 MB (live through G5)
    float* KTVF   = (float*)(ws + 33566720);   // 512 KB (dead after wpb)
    u16*   QKVB   = (u16*)  (ws + 34353152);   // 24 MB (dead after G3); OUT1B (live to lnf)
    u16*   OUT1B  = QKVB;
    u16*   Q3_0   = (u16*)  (ws + 59518976);   // 8 MB (dead after ln1); then Q5 use ok
    u16*   Q3_1   = (u16*)  (ws + 67907584);   // 8 MB (dead after ln1)
    u16*   Q5_1   = (u16*)  (ws + 76296192);   // 8 MB (freed OUT1F region)
    u16*   H1     = (u16*)  (ws + 93073408);   // 32 MB (live through G5)
    u16*   Q5_0   = (u16*)  (ws + 0);          // 8 MB (over XB/WPBT, dead after G3)
    (void)ws_size; (void)in_sizes; (void)n_in; (void)out_size;

    hipMemsetAsync(KTVF, 0, 32 * 4096 * 4, stream);
    cast_x_kernel<<<4096, 256, 0, stream>>>(x, XB);
    tr_wqkv<<<dim3(32, 2, 48), 256, 0, stream>>>(wq, wk, wv, WQKVT);
    transpose_cast3<<<9228, 256, 0, stream>>>(wp, w1, w2, bq, bk, bv,
                                              WPT, W1T, W2T, BQKV);

    // G1: QKV = X @ Wqkv + b  (128x384 tile, grid 256, col-outer; f32 KV side-out)
    gemmT<1, 2, 4, 4, 6, true><<<256, 512, 0, stream>>>(
        XB, WQKVT, BQKV, QKVB, kv, nullptr, nullptr,
        4096, 3072, 1024, 1024, 1024, 3072, 0);
    ktv_partial<<<dim3(16, 32), 256, 0, stream>>>(QKVB, KTVF);
    // fold (KTV*s) into wp per (b,h): WPBT[b] = block-stacked KTV_h @ wp_h
    wpb_kernel<<<dim3(4, 32), 256, 0, stream>>>(KTVF, WPT, WPBT);

    // G3: out[b] = Q[b] @ WPBT[b]  (A = QKVB Q-cols, lda=3072; batch-B by row half;
    //     128x128 tile, split-K x2, 512 blocks, row-outer)
    gemmT<5, 2, 2, 4, 4, false><<<512, 256, 0, stream>>>(
        QKVB, WPBT, nullptr, (u16*)(WPBT + 1048576), nullptr, Q3_0, Q3_1,
        4096, 1024, 1024, 3072, 1024, 1024, 512);
    ln1_kernel<<<4096, 256, 0, stream>>>(x, Q3_0, Q3_1, bp, ln1g, ln1b, OUT1B);

    // G4: h1 = relu(out1 @ w1 + b1) (256x256 tile, grid 256, 512 thr — R7-proven)
    gemmT<2, 2, 4, 8, 4, false><<<256, 512, 0, stream>>>(
        OUT1B, W1T, b1, H1, nullptr, nullptr, nullptr,
        4096, 4096, 1024, 1024, 1024, 4096, 0);
    // G5: ff = h1 @ w2 (128x128 tile, split-K x2 over K=4096, 512 blocks, row-outer)
    gemmT<4, 2, 2, 4, 4, false><<<512, 256, 0, stream>>>(
        H1, W2T, nullptr, nullptr, nullptr, Q5_0, Q5_1,
        4096, 1024, 4096, 4096, 4096, 1024, 2048);
    lnf_kernel<<<4096, 256, 0, stream>>>(OUT1B, Q5_0, Q5_1, b2,
                                         lnfg, lnfb, ln2g, ln2b, out2);
}

// Round 12
// 193.565 us; speedup vs baseline: 1.1533x; 1.0153x over previous
//
#include <hip/hip_runtime.h>

typedef unsigned short u16;
typedef __attribute__((ext_vector_type(4))) float f32x4;
typedef __attribute__((ext_vector_type(8))) __bf16 bf16x8;
typedef __attribute__((ext_vector_type(8))) unsigned short u16x8;
typedef __attribute__((ext_vector_type(4))) unsigned short u16x4;

// ---------- scalar bf16 helpers ----------
__device__ __forceinline__ u16 f2b(float f) {
    unsigned int u = __builtin_bit_cast(unsigned int, f);
    u = (u + 0x7FFFu + ((u >> 16) & 1u)) >> 16;
    return (u16)u;
}
__device__ __forceinline__ float b2f(u16 h) {
    unsigned int u = ((unsigned int)h) << 16;
    return __builtin_bit_cast(float, u);
}

// async global->LDS, 16B per lane; LDS dest is wave-uniform base (+lane*16 by HW)
__device__ __forceinline__ void gload_lds16(const u16* g, u16* l) {
    __builtin_amdgcn_global_load_lds(
        (const __attribute__((address_space(1))) void*)g,
        (__attribute__((address_space(3))) void*)l,
        16, 0, 0);
}

__device__ __forceinline__ bf16x8 lds_frag(const u16* p) {
    u16x8 t = *(const u16x8*)p;
    return __builtin_bit_cast(bf16x8, t);
}

#define FENCE asm volatile("" ::: "memory")
#define BARRIER do { FENCE; __builtin_amdgcn_s_barrier(); FENCE; \
                     __builtin_amdgcn_sched_barrier(0); } while (0)
#define SCHED0 __builtin_amdgcn_sched_barrier(0)
#define LGKM0 do { asm volatile("s_waitcnt lgkmcnt(0)" ::: "memory"); \
                   __builtin_amdgcn_sched_barrier(0); } while (0)
#define WAIT_VM8 do { asm volatile("s_waitcnt vmcnt(8)" ::: "memory"); \
                      __builtin_amdgcn_sched_barrier(0); } while (0)
#define WAIT_VM0 do { asm volatile("s_waitcnt vmcnt(0)" ::: "memory"); \
                      __builtin_amdgcn_sched_barrier(0); } while (0)

// ---------------- merged prep kernel: one dispatch ----------------
// blocks [0,4096): cast x -> bf16
// [4096,7168): tr_wqkv (48 z x 64 sub)
// [7168,16384): wp/w1/w2 transposes
// [16384,16396): QKV bias pack
__global__ __launch_bounds__(256) void prep_all(
    const float* __restrict__ x, u16* __restrict__ XB,
    const float* __restrict__ wq, const float* __restrict__ wk, const float* __restrict__ wv,
    u16* __restrict__ WQKVT,
    const float* __restrict__ wp, const float* __restrict__ w1, const float* __restrict__ w2,
    u16* __restrict__ WPT, u16* __restrict__ W1T, u16* __restrict__ W2T,
    const float* __restrict__ bq, const float* __restrict__ bk, const float* __restrict__ bv,
    float* __restrict__ BI) {
    int bid = blockIdx.x;
    if (bid < 4096) {
        int i = (bid * 256 + threadIdx.x) * 4;
        float4 v = *(const float4*)&x[i];
        u16x4 o = { f2b(v.x), f2b(v.y), f2b(v.z), f2b(v.w) };
        *(u16x4*)&XB[i] = o;
        return;
    }
    if (bid >= 16384) {
        int i = (bid - 16384) * 256 + threadIdx.x;   // < 3072
        const float* b = (i < 1024) ? bq : (i < 2048) ? bk : bv;
        BI[i] = b[((i & 1023) >> 6) * 64 + (i & 63)];
        return;
    }
    __shared__ float tile[32][33];
    int tx = threadIdx.x & 31, ty = threadIdx.x >> 5;
    if (bid < 7168) {   // tr_wqkv
        int r = bid - 4096;
        int z = r >> 6, sub = r & 63;
        int sel = z >> 4, h = z & 15;
        const float* w = (sel == 0) ? wq : (sel == 1) ? wk : wv;
        w += (long)h * 65536;              // [1024][64]
        int d0 = (sub & 31) * 32, e0 = (sub >> 5) * 32;
#pragma unroll
        for (int i = 0; i < 32; i += 8)
            tile[ty + i][tx] = w[(long)(d0 + ty + i) * 64 + e0 + tx];
        __syncthreads();
#pragma unroll
        for (int i = 0; i < 32; i += 8)
            WQKVT[((long)(sel * 1024 + h * 64 + e0 + ty + i)) * 1024 + d0 + tx] =
                f2b(tile[tx][ty + i]);
        return;
    }
    int b0 = bid - 7168;
    const float* in; u16* out; int C, R, bx, by;
    if (b0 < 1024)      { in = wp; out = WPT; R = 1024; C = 1024; bx = b0 & 31;  by = b0 >> 5; }
    else if (b0 < 5120) { int b = b0 - 1024; in = w1; out = W1T; R = 1024; C = 4096; bx = b & 127; by = b >> 7; }
    else                { int b = b0 - 5120; in = w2; out = W2T; R = 4096; C = 1024; bx = b & 31;  by = b >> 5; }
    int r0 = by * 32, c0 = bx * 32;
#pragma unroll
    for (int i = 0; i < 32; i += 8)
        tile[ty + i][tx] = in[(long)(r0 + ty + i) * C + c0 + tx];
    __syncthreads();
#pragma unroll
    for (int i = 0; i < 32; i += 8)
        out[(long)(c0 + ty + i) * R + r0 + tx] = f2b(tile[tx][ty + i]);
}

// ---------------- templated tiled GEMM, sub-phase pipelined (LDS || MFMA) -----
// C[M,N] = A[M,K] @ BT[N,K]^T. Tile BM=WM*MF*16, BN=WN*NF*16, BK=64, T=WM*WN*64.
// MODE 1: +bias, bf16 out + f32 KV side-write for cols>=1024 (G1).
// MODE 2: +bias, relu (G4). MODE 4: 2-way split-K bf16 partials to Q0/Q1 (G5).
// MODE 5: MODE4 + batch-B: rows >= M/2 use BT2 = (const u16*)Cb (G3 batched wp).
// Pipeline (R7-proven): 4 sub-phases per K-tile; sub-phase s issues ds_reads for
// s+1 into the alternate register frag buffer, then MFMAs current frags; compiler
// emits progressive counted lgkmcnt. 2 barriers/tile; counted vmcnt only.
// LDS byte-swizzle col^=(row&7)<<4 via inverse-swizzled global src (rule #21).
// Epilogue: acc -> swizzled LDS repack -> coalesced u16x8 stores (+f32 KV for MODE 1).
template <int MODE, int WM, int WN, int MF, int NF, bool COLOUT>
__global__ __launch_bounds__(WM * WN * 64, 2) void gemmT(
    const u16* __restrict__ A, const u16* __restrict__ BT, const float* __restrict__ bias,
    u16* __restrict__ Cb, float* __restrict__ KV,
    u16* __restrict__ Q0, u16* __restrict__ Q1,
    int M, int N, int K, int lda, int ldb, int ldc, int kchunk) {
    constexpr int T   = WM * WN * 64;
    constexpr int BM  = WM * MF * 16;
    constexpr int BN  = WN * NF * 16;
    constexpr int RPI = T / 8;            // rows per gload instr
    constexpr int LA  = BM / RPI;         // gload instrs per A K-tile
    constexpr int LB  = BN / RPI;
    constexpr int EPI = T * 8;            // LDS elems per gload instr
    constexpr int MFH = MF / 2;
    constexpr int ASZ = BM * 64, BSZ = BN * 64;
    __shared__ __align__(16) u16 SMEM[2 * ASZ + 2 * BSZ];
    u16* As0 = SMEM;
    u16* As1 = SMEM + ASZ;
    u16* Bs0 = SMEM + 2 * ASZ;
    u16* Bs1 = SMEM + 2 * ASZ + BSZ;
    const int tid = threadIdx.x;
    const int lane = tid & 63;
    const int wid = tid >> 6;
    const int wr = wid / WN, wc = wid % WN;
    const int ntile = N / BN;
    const int mtile = M / BM;
    int bid = blockIdx.x;
    int kb = 0, ksz = K;
    u16* Pout = Q0;
    if (MODE == 4 || MODE == 5) {
        int tiles = mtile * ntile;
        int sk = bid / tiles; bid -= sk * tiles;
        kb = sk * kchunk;
        int rem = K - kb; ksz = rem < kchunk ? rem : kchunk;
        Pout = sk ? Q1 : Q0;
    }
    // XCD-chunked bijective swizzle (tile count multiple of 8)
    {
        int q = (mtile * ntile) >> 3;
        bid = (bid & 7) * q + (bid >> 3);
    }
    int bi, bj;
    if (COLOUT) { bj = bid / mtile; bi = bid % mtile; }   // XCD owns B col-panels (G1)
    else        { bi = bid / ntile; bj = bid % ntile; }   // XCD owns A row-panels
    const int brow = bi * BM, bcol = bj * BN;
    const int nt = ksz >> 6;              // BK=64 tiles
    const u16* BTe = BT;
    if (MODE == 5 && brow >= (M >> 1)) BTe = (const u16*)Cb;   // batch-1 B panel

    // ---- staging addressing (inverse-swizzled global source, linear LDS dest)
    const int srow = tid >> 3;
    const int scol = ((tid & 7) ^ (srow & 7)) << 3;
    const u16* ag = A + (long)(brow + srow) * lda + kb + scol;
    const u16* bg = BTe + (long)(bcol + srow) * ldb + kb + scol;
    const long aI = (long)RPI * lda, bI = (long)RPI * ldb;
    const int sdst = tid << 3;

    auto STAGE = [&](u16* lA, u16* lB, int t) {
#pragma unroll
        for (int j = 0; j < LA; ++j)
            gload_lds16(ag + ((long)t << 6) + j * aI, &lA[j * EPI + sdst]);
#pragma unroll
        for (int j = 0; j < LB; ++j)
            gload_lds16(bg + ((long)t << 6) + j * bI, &lB[j * EPI + sdst]);
    };

    f32x4 acc[MF][NF] = {};
    bf16x8 af0[MFH], af1[MFH], bf0[NF], bf1[NF];

    // ---- fragment read addressing (swizzled)
    const int ln15 = lane & 15;
    const int eoff = (((lane >> 4) << 3) ^ ((lane & 7) << 3));
    const int arow0 = wr * (MF * 16) + ln15;
    const int brow0 = wc * (NF * 16) + ln15;

#define RD_A(dst, S, kh, mh)                                                   \
    _Pragma("unroll") for (int m4 = 0; m4 < MFH; ++m4)                         \
        dst[m4] = lds_frag(&(S)[((arow0 + (((mh) * MFH + m4) << 4)) << 6) +    \
                                (eoff ^ ((kh) << 5))]);
#define RD_B(dst, S, kh)                                                       \
    _Pragma("unroll") for (int n = 0; n < NF; ++n)                             \
        dst[n] = lds_frag(&(S)[((brow0 + (n << 4)) << 6) + (eoff ^ ((kh) << 5))]);
#define MM(a, b, mh) do {                                                      \
    __builtin_amdgcn_s_setprio(1);                                             \
    _Pragma("unroll") for (int m4 = 0; m4 < MFH; ++m4)                         \
        _Pragma("unroll") for (int n = 0; n < NF; ++n)                         \
            acc[(mh) * MFH + m4][n] = __builtin_amdgcn_mfma_f32_16x16x32_bf16( \
                a[m4], b[n], acc[(mh) * MFH + m4][n], 0, 0, 0);                \
    __builtin_amdgcn_s_setprio(0);                                             \
} while (0)

    // ---- prologue: stage t0 + t1; retire t0; initial frags
    STAGE(As0, Bs0, 0);
    if (nt > 1) { STAGE(As1, Bs1, 1); WAIT_VM8; } else { WAIT_VM0; }
    BARRIER;
    RD_B(bf0, Bs0, 0);
    RD_A(af0, As0, 0, 0);

    u16 *Ac = As0, *Bc = Bs0, *Ao = As1, *Bo = Bs1;
    for (int t = 0; t < nt; ++t) {
        const bool hasN = (t + 1 < nt);
        const bool hasNN = (t + 2 < nt);
        // s0: compute (kh0, mh0); prefetch (kh0, mh1)
        RD_A(af1, Ac, 0, 1);
        MM(af0, bf0, 0);
        SCHED0;
        // s1: compute (kh0, mh1); prefetch kh1 B + (kh1, mh0)
        RD_B(bf1, Bc, 1);
        RD_A(af0, Ac, 1, 0);
        MM(af1, bf0, 1);
        SCHED0;
        // s2: compute (kh1, mh0); prefetch (kh1, mh1)
        RD_A(af1, Ac, 1, 1);
        MM(af0, bf1, 0);
        WAIT_VM0;            // stage(t+1 -> other slot) retired
        BARRIER;             // B1: next tile visible
        // s3: compute (kh1, mh1); prefetch next tile (kh0) from other slot
        if (hasN) { RD_B(bf0, Bo, 0); RD_A(af0, Ao, 0, 0); }
        MM(af1, bf1, 1);
        BARRIER;             // B2: all waves done reading current slot
        if (hasNN) STAGE(Ac, Bc, t + 2);
        SCHED0;
        u16* tp;
        tp = Ac; Ac = Ao; Ao = tp;
        tp = Bc; Bc = Bo; Bo = tp;
    }

    // ---- epilogue: swizzled LDS repack -> coalesced stores
    const int crow0 = wr * (MF * 16), ccol0 = wc * (NF * 16);
#pragma unroll
    for (int m = 0; m < MF; ++m) {
        int rbase = crow0 + (m << 4) + ((lane >> 4) << 2);
#pragma unroll
        for (int n = 0; n < NF; ++n) {
            int col = ccol0 + (n << 4) + ln15;
            float bv = (MODE == 4 || MODE == 5) ? 0.f : bias[bcol + col];
#pragma unroll
            for (int r = 0; r < 4; ++r) {
                float v = acc[m][n][r] + bv;
                if (MODE == 2) v = v > 0.f ? v : 0.f;
                int row = rbase + r;
                SMEM[row * BN + (col ^ ((row & 7) << 3))] = f2b(v);
            }
        }
    }
    LGKM0;
    BARRIER;
    u16* outp = (MODE == 4 || MODE == 5) ? Pout : Cb;
    constexpr int CHT = BM * BN / 8 / T;
#pragma unroll
    for (int k = 0; k < CHT; ++k) {
        int c = tid + k * T;
        int row = c / (BN / 8), co = (c % (BN / 8)) * 8;
        u16x8 vv = *(const u16x8*)&SMEM[row * BN + (co ^ ((row & 7) << 3))];
        *(u16x8*)&outp[(long)(brow + row) * ldc + bcol + co] = vv;
        if (MODE == 1) {
            int cg = bcol + co;        // 8-chunks never straddle 1024-boundaries
            if (cg >= 1024) {
                int cc = cg - 1024;
                long kbase = (long)(cc >> 10) * 4194304 + (long)(brow + row) * 1024 + (cc & 1023);
                float4 f0 = { b2f(vv[0]), b2f(vv[1]), b2f(vv[2]), b2f(vv[3]) };
                float4 f1 = { b2f(vv[4]), b2f(vv[5]), b2f(vv[6]), b2f(vv[7]) };
                *(float4*)&KV[kbase] = f0;
                *(float4*)&KV[kbase + 4] = f1;
            }
        }
    }
#undef RD_A
#undef RD_B
#undef MM
}

// ---------------- K^T V partial sums (t-chunked, f32 atomics) ----------------
// grid (16 tchunks of 128, 32 bh)
__global__ __launch_bounds__(256) void ktv_partial(const u16* __restrict__ QKVB,
                                                   float* __restrict__ KTVF) {
    __shared__ __align__(16) u16 Ks[64 * 64];
    __shared__ __align__(16) u16 Vs[64 * 64];
    int tid = threadIdx.x;
    int tc = blockIdx.x, bh = blockIdx.y;
    int b = bh >> 4, h = bh & 15;
    int j = tid & 63, i0 = (tid >> 6) * 16;
    float acc[16] = {};
    for (int st = 0; st < 2; ++st) {
        int t0 = tc * 128 + st * 64;
        __syncthreads();
#pragma unroll
        for (int i = 0; i < 2; ++i) {
            int c = i * 256 + tid;
            long base = (long)(b * 2048 + t0 + (c >> 3)) * 3072 + h * 64 + (c & 7) * 8;
            *(u16x8*)&Ks[c * 8] = *(const u16x8*)&QKVB[base + 1024];
            *(u16x8*)&Vs[c * 8] = *(const u16x8*)&QKVB[base + 2048];
        }
        __syncthreads();
        for (int tt = 0; tt < 64; ++tt) {
            float vj = b2f(Vs[tt * 64 + j]);
            u16x8 k0 = *(const u16x8*)&Ks[tt * 64 + i0];
            u16x8 k1 = *(const u16x8*)&Ks[tt * 64 + i0 + 8];
#pragma unroll
            for (int r = 0; r < 8; ++r) acc[r] += b2f(k0[r]) * vj;
#pragma unroll
            for (int r = 0; r < 8; ++r) acc[r + 8] += b2f(k1[r]) * vj;
        }
    }
#pragma unroll
    for (int r = 0; r < 16; ++r)
        atomicAdd(&KTVF[bh * 4096 + (i0 + r) * 64 + j], acc[r]);
}

// ---------------- fold KTV into wp: WPBT[b][j][h*64+e] = sum_e' KTV[bh][e][e']*0.125
//                  * wp[(h*64+e')][j]   (wp accessed via WPT[j][d])
// grid (4 j-tiles, 32 bh); 256 thr, 4 waves; per wave 64 j rows.
__global__ __launch_bounds__(256) void wpb_kernel(const float* __restrict__ KTVF,
                                                  const u16* __restrict__ WPT,
                                                  u16* __restrict__ WPBT) {
    __shared__ __align__(16) u16 Ks[64 * 72];   // padded rows (72) to break bank conflicts
    int tid = threadIdx.x, lane = tid & 63, w = tid >> 6;
    int jt = blockIdx.x, bh = blockIdx.y;
    int b = bh >> 4, h = bh & 15;
    const float* kt = KTVF + bh * 4096;
    {   // load + scale(0.125) + cast 16 f32/thread into padded LDS
        int idx = tid * 16;
        int e = idx >> 6, ep = idx & 63;
        float4 v0 = *(const float4*)&kt[idx];
        float4 v1 = *(const float4*)&kt[idx + 4];
        float4 v2 = *(const float4*)&kt[idx + 8];
        float4 v3 = *(const float4*)&kt[idx + 12];
        u16x8 o0 = { f2b(v0.x * 0.125f), f2b(v0.y * 0.125f), f2b(v0.z * 0.125f), f2b(v0.w * 0.125f),
                     f2b(v1.x * 0.125f), f2b(v1.y * 0.125f), f2b(v1.z * 0.125f), f2b(v1.w * 0.125f) };
        u16x8 o1 = { f2b(v2.x * 0.125f), f2b(v2.y * 0.125f), f2b(v2.z * 0.125f), f2b(v2.w * 0.125f),
                     f2b(v3.x * 0.125f), f2b(v3.y * 0.125f), f2b(v3.z * 0.125f), f2b(v3.w * 0.125f) };
        *(u16x8*)&Ks[e * 72 + ep] = o0;
        *(u16x8*)&Ks[e * 72 + ep + 8] = o1;
    }
    __syncthreads();
    int ln15 = lane & 15, l4 = lane >> 4;
    bf16x8 bf[4][2];
#pragma unroll
    for (int n = 0; n < 4; ++n)
#pragma unroll
        for (int kh = 0; kh < 2; ++kh)
            bf[n][kh] = lds_frag(&Ks[(n * 16 + ln15) * 72 + kh * 32 + l4 * 8]);
    int j0 = jt * 256 + w * 64;
    f32x4 acc[4][4] = {};
#pragma unroll
    for (int m = 0; m < 4; ++m) {
        const u16* ap = &WPT[(long)(j0 + m * 16 + ln15) * 1024 + h * 64 + l4 * 8];
        bf16x8 a0 = __builtin_bit_cast(bf16x8, *(const u16x8*)ap);
        bf16x8 a1 = __builtin_bit_cast(bf16x8, *(const u16x8*)(ap + 32));
#pragma unroll
        for (int n = 0; n < 4; ++n) {
            acc[m][n] = __builtin_amdgcn_mfma_f32_16x16x32_bf16(a0, bf[n][0], acc[m][n], 0, 0, 0);
            acc[m][n] = __builtin_amdgcn_mfma_f32_16x16x32_bf16(a1, bf[n][1], acc[m][n], 0, 0, 0);
        }
    }
#pragma unroll
    for (int m = 0; m < 4; ++m)
#pragma unroll
        for (int n = 0; n < 4; ++n)
#pragma unroll
            for (int r = 0; r < 4; ++r)
                WPBT[(long)b * 1048576 + (long)(j0 + m * 16 + l4 * 4 + r) * 1024 +
                     h * 64 + n * 16 + ln15] = f2b(acc[m][n][r]);
}

// ---------------- layernorm kernels ----------------
__device__ __forceinline__ void block_reduce2(float& a, float& b) {
    __syncthreads();
#pragma unroll
    for (int off = 32; off; off >>= 1) {
        a += __shfl_down(a, off);
        b += __shfl_down(b, off);
    }
    __shared__ float sa[4], sb[4];
    int wid = threadIdx.x >> 6, lane = threadIdx.x & 63;
    if (lane == 0) { sa[wid] = a; sb[wid] = b; }
    __syncthreads();
    a = sa[0] + sa[1] + sa[2] + sa[3];
    b = sb[0] + sb[1] + sb[2] + sb[3];
}

// out1 = LN(x + (q0+q1 + bp)) ; write bf16 only  (q* = bf16 partials)
__global__ __launch_bounds__(256) void ln1_kernel(
    const float* __restrict__ x,
    const u16* __restrict__ q0, const u16* __restrict__ q1,
    const float* __restrict__ bp,
    const float* __restrict__ g, const float* __restrict__ bt,
    u16* __restrict__ out1b) {
    int row = blockIdx.x, tid = threadIdx.x;
    long base = (long)row * 1024 + tid * 4;
    float4 xv = *(const float4*)&x[base];
    u16x4 a0 = *(const u16x4*)&q0[base];
    u16x4 a1 = *(const u16x4*)&q1[base];
    float4 bb = *(const float4*)&bp[tid * 4];
    float xa[4] = { xv.x, xv.y, xv.z, xv.w };
    float bba[4] = { bb.x, bb.y, bb.z, bb.w };
    float s[4];
#pragma unroll
    for (int r = 0; r < 4; ++r)
        s[r] = xa[r] + b2f(a0[r]) + b2f(a1[r]) + bba[r];
    float sum = s[0] + s[1] + s[2] + s[3];
    float sq = s[0] * s[0] + s[1] * s[1] + s[2] * s[2] + s[3] * s[3];
    block_reduce2(sum, sq);
    float mu = sum * (1.f / 1024.f);
    float var = sq * (1.f / 1024.f) - mu * mu;
    float rs = rsqrtf(var + 1e-5f);
    float o0 = (s[0] - mu) * rs * g[tid * 4 + 0] + bt[tid * 4 + 0];
    float o1 = (s[1] - mu) * rs * g[tid * 4 + 1] + bt[tid * 4 + 1];
    float o2 = (s[2] - mu) * rs * g[tid * 4 + 2] + bt[tid * 4 + 2];
    float o3 = (s[3] - mu) * rs * g[tid * 4 + 3] + bt[tid * 4 + 3];
    u16x4 ob = (u16x4){ f2b(o0), f2b(o1), f2b(o2), f2b(o3) };
    *(u16x4*)&out1b[base] = ob;
}

// ff = (q0+q1)+b2 (bf16 partials); ffo = LN(out1+ff); out2 = LN(out1+ffo)
// out1 read as bf16 (out1b)
__global__ __launch_bounds__(256) void lnf_kernel(
    const u16* __restrict__ out1b,
    const u16* __restrict__ q0, const u16* __restrict__ q1,
    const float* __restrict__ b2,
    const float* __restrict__ lnfg, const float* __restrict__ lnfb,
    const float* __restrict__ ln2g, const float* __restrict__ ln2b,
    float* __restrict__ out2) {
    int row = blockIdx.x, tid = threadIdx.x;
    long base = (long)row * 1024 + tid * 4;
    u16x4 o1v = *(const u16x4*)&out1b[base];
    u16x4 a0 = *(const u16x4*)&q0[base];
    u16x4 a1 = *(const u16x4*)&q1[base];
    float4 bb = *(const float4*)&b2[tid * 4];
    float o1a[4] = { b2f(o1v[0]), b2f(o1v[1]), b2f(o1v[2]), b2f(o1v[3]) };
    float bba[4] = { bb.x, bb.y, bb.z, bb.w };
    float s1[4];
#pragma unroll
    for (int r = 0; r < 4; ++r)
        s1[r] = o1a[r] + b2f(a0[r]) + b2f(a1[r]) + bba[r];
    float sum = s1[0] + s1[1] + s1[2] + s1[3];
    float sq = s1[0] * s1[0] + s1[1] * s1[1] + s1[2] * s1[2] + s1[3] * s1[3];
    block_reduce2(sum, sq);
    float mu = sum * (1.f / 1024.f);
    float rs = rsqrtf(sq * (1.f / 1024.f) - mu * mu + 1e-5f);
    float s2[4];
#pragma unroll
    for (int r = 0; r < 4; ++r) {
        float ffo = (s1[r] - mu) * rs * lnfg[tid * 4 + r] + lnfb[tid * 4 + r];
        s2[r] = o1a[r] + ffo;
    }
    float sum2 = s2[0] + s2[1] + s2[2] + s2[3];
    float sq2 = s2[0] * s2[0] + s2[1] * s2[1] + s2[2] * s2[2] + s2[3] * s2[3];
    block_reduce2(sum2, sq2);
    float mu2 = sum2 * (1.f / 1024.f);
    float rs2 = rsqrtf(sq2 * (1.f / 1024.f) - mu2 * mu2 + 1e-5f);
    float4 o;
    o.x = (s2[0] - mu2) * rs2 * ln2g[tid * 4 + 0] + ln2b[tid * 4 + 0];
    o.y = (s2[1] - mu2) * rs2 * ln2g[tid * 4 + 1] + ln2b[tid * 4 + 1];
    o.z = (s2[2] - mu2) * rs2 * ln2g[tid * 4 + 2] + ln2b[tid * 4 + 2];
    o.w = (s2[3] - mu2) * rs2 * ln2g[tid * 4 + 3] + ln2b[tid * 4 + 3];
    *(float4*)&out2[base] = o;
}

// ---------------- launcher ----------------
extern "C" void kernel_launch(void* const* d_in, const int* in_sizes, int n_in,
                              void* d_out, int out_size, void* d_ws, size_t ws_size,
                              hipStream_t stream) {
    const float* x    = (const float*)d_in[0];
    const float* wq   = (const float*)d_in[1];
    const float* bq   = (const float*)d_in[2];
    const float* wk   = (const float*)d_in[3];
    const float* bk   = (const float*)d_in[4];
    const float* wv   = (const float*)d_in[5];
    const float* bv   = (const float*)d_in[6];
    const float* wp   = (const float*)d_in[7];
    const float* bp   = (const float*)d_in[8];
    const float* w1   = (const float*)d_in[9];
    const float* b1   = (const float*)d_in[10];
    const float* w2   = (const float*)d_in[11];
    const float* b2   = (const float*)d_in[12];
    const float* ln1g = (const float*)d_in[13];
    const float* ln1b = (const float*)d_in[14];
    const float* lnfg = (const float*)d_in[15];
    const float* lnfb = (const float*)d_in[16];
    const float* ln2g = (const float*)d_in[17];
    const float* ln2b = (const float*)d_in[18];

    float* out2 = (float*)d_out;
    float* kv   = (float*)d_out + 4194304;   // Kc then Vc

    // workspace layout (bytes). Liveness:
    char* ws = (char*)d_ws;
    u16*   XB     = (u16*)  (ws + 0);          // 8 MB (dead after G1); WPBT (dead after G3); Q5_0
    u16*   WPBT   = XB;                        // 4 MB: 2 batches x 1024x1024 bf16
    u16*   WQKVT  = (u16*)  (ws + 8388608);    // 6.3 MB (dead after G1)
    float* BQKV   = (float*)(ws + 14680064);   // 12 KB (dead after G1)
    u16*   WPT    = (u16*)  (ws + 14692352);   // 2 MB (dead after wpb)
    u16*   W1T    = (u16*)  (ws + 16789504);   // 8 MB (dead after G4)
    u16*   W2T    = (u16*)  (ws + 25178112);   // 8 MB (live through G5)
    float* KTVF   = (float*)(ws + 33566720);   // 512 KB (dead after wpb)
    u16*   QKVB   = (u16*)  (ws + 34353152);   // 24 MB (dead after G3); OUT1B (live to lnf)
    u16*   OUT1B  = QKVB;
    u16*   Q3_0   = (u16*)  (ws + 59518976);   // 8 MB (dead after ln1)
    u16*   Q3_1   = (u16*)  (ws + 67907584);   // 8 MB (dead after ln1)
    u16*   Q5_1   = (u16*)  (ws + 76296192);   // 8 MB
    u16*   H1     = (u16*)  (ws + 93073408);   // 32 MB (live through G5)
    u16*   Q5_0   = (u16*)  (ws + 0);          // 8 MB (over XB/WPBT, dead after G3)
    (void)ws_size; (void)in_sizes; (void)n_in; (void)out_size;

    hipMemsetAsync(KTVF, 0, 32 * 4096 * 4, stream);
    prep_all<<<16396, 256, 0, stream>>>(x, XB, wq, wk, wv, WQKVT,
                                        wp, w1, w2, WPT, W1T, W2T,
                                        bq, bk, bv, BQKV);

    // G1: QKV = X @ Wqkv + b  (256x256 tile, grid 192, col-outer; f32 KV side-out)
    gemmT<1, 2, 4, 8, 4, true><<<192, 512, 0, stream>>>(
        XB, WQKVT, BQKV, QKVB, kv, nullptr, nullptr,
        4096, 3072, 1024, 1024, 1024, 3072, 0);
    ktv_partial<<<dim3(16, 32), 256, 0, stream>>>(QKVB, KTVF);
    // fold (KTV*s) into wp per (b,h): WPBT[b] = block-stacked KTV_h @ wp_h
    wpb_kernel<<<dim3(4, 32), 256, 0, stream>>>(KTVF, WPT, WPBT);

    // G3: out[b] = Q[b] @ WPBT[b]  (A = QKVB Q-cols, lda=3072; batch-B by row half;
    //     128x128 tile, split-K x2, 512 blocks, row-outer)
    gemmT<5, 2, 2, 4, 4, false><<<512, 256, 0, stream>>>(
        QKVB, WPBT, nullptr, (u16*)(WPBT + 1048576), nullptr, Q3_0, Q3_1,
        4096, 1024, 1024, 3072, 1024, 1024, 512);
    ln1_kernel<<<4096, 256, 0, stream>>>(x, Q3_0, Q3_1, bp, ln1g, ln1b, OUT1B);

    // G4: h1 = relu(out1 @ w1 + b1) (256x256 tile, grid 256, 512 thr — R7-proven)
    gemmT<2, 2, 4, 8, 4, false><<<256, 512, 0, stream>>>(
        OUT1B, W1T, b1, H1, nullptr, nullptr, nullptr,
        4096, 4096, 1024, 1024, 1024, 4096, 0);
    // G5: ff = h1 @ w2 (128x128 tile, split-K x2 over K=4096, 512 blocks, row-outer)
    gemmT<4, 2, 2, 4, 4, false><<<512, 256, 0, stream>>>(
        H1, W2T, nullptr, nullptr, nullptr, Q5_0, Q5_1,
        4096, 1024, 4096, 4096, 4096, 1024, 2048);
    lnf_kernel<<<4096, 256, 0, stream>>>(OUT1B, Q5_0, Q5_1, b2,
                                         lnfg, lnfb, ln2g, ln2b, out2);
}

// Round 13
// 192.775 us; speedup vs baseline: 1.1580x; 1.0041x over previous
//
#include <hip/hip_runtime.h>

typedef unsigned short u16;
typedef __attribute__((ext_vector_type(4))) float f32x4;
typedef __attribute__((ext_vector_type(8))) __bf16 bf16x8;
typedef __attribute__((ext_vector_type(8))) unsigned short u16x8;
typedef __attribute__((ext_vector_type(4))) unsigned short u16x4;

// ---------- scalar bf16 helpers ----------
__device__ __forceinline__ u16 f2b(float f) {
    unsigned int u = __builtin_bit_cast(unsigned int, f);
    u = (u + 0x7FFFu + ((u >> 16) & 1u)) >> 16;
    return (u16)u;
}
__device__ __forceinline__ float b2f(u16 h) {
    unsigned int u = ((unsigned int)h) << 16;
    return __builtin_bit_cast(float, u);
}

// async global->LDS, 16B per lane; LDS dest is wave-uniform base (+lane*16 by HW)
__device__ __forceinline__ void gload_lds16(const u16* g, u16* l) {
    __builtin_amdgcn_global_load_lds(
        (const __attribute__((address_space(1))) void*)g,
        (__attribute__((address_space(3))) void*)l,
        16, 0, 0);
}

__device__ __forceinline__ bf16x8 lds_frag(const u16* p) {
    u16x8 t = *(const u16x8*)p;
    return __builtin_bit_cast(bf16x8, t);
}

#define FENCE asm volatile("" ::: "memory")
#define BARRIER do { FENCE; __builtin_amdgcn_s_barrier(); FENCE; \
                     __builtin_amdgcn_sched_barrier(0); } while (0)
#define SCHED0 __builtin_amdgcn_sched_barrier(0)
#define LGKM0 do { asm volatile("s_waitcnt lgkmcnt(0)" ::: "memory"); \
                   __builtin_amdgcn_sched_barrier(0); } while (0)
#define WAIT_VM8 do { asm volatile("s_waitcnt vmcnt(8)" ::: "memory"); \
                      __builtin_amdgcn_sched_barrier(0); } while (0)
#define WAIT_VM0 do { asm volatile("s_waitcnt vmcnt(0)" ::: "memory"); \
                      __builtin_amdgcn_sched_barrier(0); } while (0)

// ---------------- merged prep kernel: one dispatch ----------------
// blocks [0,4096): cast x -> bf16
// [4096,7168): tr_wqkv (48 z x 64 sub)
// [7168,16384): wp/w1/w2 transposes
// [16384,16396): QKV bias pack
__global__ __launch_bounds__(256) void prep_all(
    const float* __restrict__ x, u16* __restrict__ XB,
    const float* __restrict__ wq, const float* __restrict__ wk, const float* __restrict__ wv,
    u16* __restrict__ WQKVT,
    const float* __restrict__ wp, const float* __restrict__ w1, const float* __restrict__ w2,
    u16* __restrict__ WPT, u16* __restrict__ W1T, u16* __restrict__ W2T,
    const float* __restrict__ bq, const float* __restrict__ bk, const float* __restrict__ bv,
    float* __restrict__ BI) {
    int bid = blockIdx.x;
    if (bid < 4096) {
        int i = (bid * 256 + threadIdx.x) * 4;
        float4 v = *(const float4*)&x[i];
        u16x4 o = { f2b(v.x), f2b(v.y), f2b(v.z), f2b(v.w) };
        *(u16x4*)&XB[i] = o;
        return;
    }
    if (bid >= 16384) {
        int i = (bid - 16384) * 256 + threadIdx.x;   // < 3072
        const float* b = (i < 1024) ? bq : (i < 2048) ? bk : bv;
        BI[i] = b[((i & 1023) >> 6) * 64 + (i & 63)];
        return;
    }
    __shared__ float tile[32][33];
    int tx = threadIdx.x & 31, ty = threadIdx.x >> 5;
    if (bid < 7168) {   // tr_wqkv
        int r = bid - 4096;
        int z = r >> 6, sub = r & 63;
        int sel = z >> 4, h = z & 15;
        const float* w = (sel == 0) ? wq : (sel == 1) ? wk : wv;
        w += (long)h * 65536;              // [1024][64]
        int d0 = (sub & 31) * 32, e0 = (sub >> 5) * 32;
#pragma unroll
        for (int i = 0; i < 32; i += 8)
            tile[ty + i][tx] = w[(long)(d0 + ty + i) * 64 + e0 + tx];
        __syncthreads();
#pragma unroll
        for (int i = 0; i < 32; i += 8)
            WQKVT[((long)(sel * 1024 + h * 64 + e0 + ty + i)) * 1024 + d0 + tx] =
                f2b(tile[tx][ty + i]);
        return;
    }
    int b0 = bid - 7168;
    const float* in; u16* out; int C, R, bx, by;
    if (b0 < 1024)      { in = wp; out = WPT; R = 1024; C = 1024; bx = b0 & 31;  by = b0 >> 5; }
    else if (b0 < 5120) { int b = b0 - 1024; in = w1; out = W1T; R = 1024; C = 4096; bx = b & 127; by = b >> 7; }
    else                { int b = b0 - 5120; in = w2; out = W2T; R = 4096; C = 1024; bx = b & 31;  by = b >> 5; }
    int r0 = by * 32, c0 = bx * 32;
#pragma unroll
    for (int i = 0; i < 32; i += 8)
        tile[ty + i][tx] = in[(long)(r0 + ty + i) * C + c0 + tx];
    __syncthreads();
#pragma unroll
    for (int i = 0; i < 32; i += 8)
        out[(long)(c0 + ty + i) * R + r0 + tx] = f2b(tile[tx][ty + i]);
}

// ---------------- templated tiled GEMM, sub-phase pipelined (LDS || MFMA) -----
// C[M,N] = A[M,K] @ BT[N,K]^T. Tile BM=WM*MF*16, BN=WN*NF*16, BK=64, T=WM*WN*64.
// MODE 1: +bias, bf16 out + f32 KV side-write for cols>=1024 (G1).
// MODE 2: +bias, relu (G4). MODE 4: 2-way split-K bf16 partials to Q0/Q1 (G5).
// MODE 5: MODE4 + batch-B: rows >= M/2 use BT2 = (const u16*)Cb (G3 batched wp).
// Pipeline (R7-proven): 4 sub-phases per K-tile; sub-phase s issues ds_reads for
// s+1 into the alternate register frag buffer, then MFMAs current frags; compiler
// emits progressive counted lgkmcnt. 2 barriers/tile; counted vmcnt only.
// LDS byte-swizzle col^=(row&7)<<4 via inverse-swizzled global src (rule #21).
// Epilogue: acc -> swizzled LDS repack -> coalesced u16x8 stores (+f32 KV for MODE 1).
template <int MODE, int WM, int WN, int MF, int NF, bool COLOUT>
__global__ __launch_bounds__(WM * WN * 64, 2) void gemmT(
    const u16* __restrict__ A, const u16* __restrict__ BT, const float* __restrict__ bias,
    u16* __restrict__ Cb, float* __restrict__ KV,
    u16* __restrict__ Q0, u16* __restrict__ Q1,
    int M, int N, int K, int lda, int ldb, int ldc, int kchunk) {
    constexpr int T   = WM * WN * 64;
    constexpr int BM  = WM * MF * 16;
    constexpr int BN  = WN * NF * 16;
    constexpr int RPI = T / 8;            // rows per gload instr
    constexpr int LA  = BM / RPI;         // gload instrs per A K-tile
    constexpr int LB  = BN / RPI;
    constexpr int EPI = T * 8;            // LDS elems per gload instr
    constexpr int MFH = MF / 2;
    constexpr int ASZ = BM * 64, BSZ = BN * 64;
    __shared__ __align__(16) u16 SMEM[2 * ASZ + 2 * BSZ];
    u16* As0 = SMEM;
    u16* As1 = SMEM + ASZ;
    u16* Bs0 = SMEM + 2 * ASZ;
    u16* Bs1 = SMEM + 2 * ASZ + BSZ;
    const int tid = threadIdx.x;
    const int lane = tid & 63;
    const int wid = tid >> 6;
    const int wr = wid / WN, wc = wid % WN;
    const int ntile = N / BN;
    const int mtile = M / BM;
    int bid = blockIdx.x;
    int kb = 0, ksz = K;
    u16* Pout = Q0;
    if (MODE == 4 || MODE == 5) {
        int tiles = mtile * ntile;
        int sk = bid / tiles; bid -= sk * tiles;
        kb = sk * kchunk;
        int rem = K - kb; ksz = rem < kchunk ? rem : kchunk;
        Pout = sk ? Q1 : Q0;
    }
    // XCD-chunked bijective swizzle (tile count multiple of 8)
    {
        int q = (mtile * ntile) >> 3;
        bid = (bid & 7) * q + (bid >> 3);
    }
    int bi, bj;
    if (COLOUT) { bj = bid / mtile; bi = bid % mtile; }   // XCD owns B col-panels (G1)
    else        { bi = bid / ntile; bj = bid % ntile; }   // XCD owns A row-panels
    const int brow = bi * BM, bcol = bj * BN;
    const int nt = ksz >> 6;              // BK=64 tiles
    const u16* BTe = BT;
    if (MODE == 5 && brow >= (M >> 1)) BTe = (const u16*)Cb;   // batch-1 B panel

    // ---- staging addressing (inverse-swizzled global source, linear LDS dest)
    const int srow = tid >> 3;
    const int scol = ((tid & 7) ^ (srow & 7)) << 3;
    const u16* ag = A + (long)(brow + srow) * lda + kb + scol;
    const u16* bg = BTe + (long)(bcol + srow) * ldb + kb + scol;
    const long aI = (long)RPI * lda, bI = (long)RPI * ldb;
    const int sdst = tid << 3;

    auto STAGE = [&](u16* lA, u16* lB, int t) {
#pragma unroll
        for (int j = 0; j < LA; ++j)
            gload_lds16(ag + ((long)t << 6) + j * aI, &lA[j * EPI + sdst]);
#pragma unroll
        for (int j = 0; j < LB; ++j)
            gload_lds16(bg + ((long)t << 6) + j * bI, &lB[j * EPI + sdst]);
    };

    f32x4 acc[MF][NF] = {};
    bf16x8 af0[MFH], af1[MFH], bf0[NF], bf1[NF];

    // ---- fragment read addressing (swizzled)
    const int ln15 = lane & 15;
    const int eoff = (((lane >> 4) << 3) ^ ((lane & 7) << 3));
    const int arow0 = wr * (MF * 16) + ln15;
    const int brow0 = wc * (NF * 16) + ln15;

#define RD_A(dst, S, kh, mh)                                                   \
    _Pragma("unroll") for (int m4 = 0; m4 < MFH; ++m4)                         \
        dst[m4] = lds_frag(&(S)[((arow0 + (((mh) * MFH + m4) << 4)) << 6) +    \
                                (eoff ^ ((kh) << 5))]);
#define RD_B(dst, S, kh)                                                       \
    _Pragma("unroll") for (int n = 0; n < NF; ++n)                             \
        dst[n] = lds_frag(&(S)[((brow0 + (n << 4)) << 6) + (eoff ^ ((kh) << 5))]);
#define MM(a, b, mh) do {                                                      \
    __builtin_amdgcn_s_setprio(1);                                             \
    _Pragma("unroll") for (int m4 = 0; m4 < MFH; ++m4)                         \
        _Pragma("unroll") for (int n = 0; n < NF; ++n)                         \
            acc[(mh) * MFH + m4][n] = __builtin_amdgcn_mfma_f32_16x16x32_bf16( \
                a[m4], b[n], acc[(mh) * MFH + m4][n], 0, 0, 0);                \
    __builtin_amdgcn_s_setprio(0);                                             \
} while (0)

    // ---- prologue: stage t0 + t1; retire t0; initial frags
    STAGE(As0, Bs0, 0);
    if (nt > 1) { STAGE(As1, Bs1, 1); WAIT_VM8; } else { WAIT_VM0; }
    BARRIER;
    RD_B(bf0, Bs0, 0);
    RD_A(af0, As0, 0, 0);

    u16 *Ac = As0, *Bc = Bs0, *Ao = As1, *Bo = Bs1;
    for (int t = 0; t < nt; ++t) {
        const bool hasN = (t + 1 < nt);
        const bool hasNN = (t + 2 < nt);
        // s0: compute (kh0, mh0); prefetch (kh0, mh1)
        RD_A(af1, Ac, 0, 1);
        MM(af0, bf0, 0);
        SCHED0;
        // s1: compute (kh0, mh1); prefetch kh1 B + (kh1, mh0)
        RD_B(bf1, Bc, 1);
        RD_A(af0, Ac, 1, 0);
        MM(af1, bf0, 1);
        SCHED0;
        // s2: compute (kh1, mh0); prefetch (kh1, mh1)
        RD_A(af1, Ac, 1, 1);
        MM(af0, bf1, 0);
        WAIT_VM0;            // stage(t+1 -> other slot) retired
        BARRIER;             // B1: next tile visible
        // s3: compute (kh1, mh1); prefetch next tile (kh0) from other slot
        if (hasN) { RD_B(bf0, Bo, 0); RD_A(af0, Ao, 0, 0); }
        MM(af1, bf1, 1);
        BARRIER;             // B2: all waves done reading current slot
        if (hasNN) STAGE(Ac, Bc, t + 2);
        SCHED0;
        u16* tp;
        tp = Ac; Ac = Ao; Ao = tp;
        tp = Bc; Bc = Bo; Bo = tp;
    }

    // ---- epilogue: swizzled LDS repack -> coalesced stores
    const int crow0 = wr * (MF * 16), ccol0 = wc * (NF * 16);
#pragma unroll
    for (int m = 0; m < MF; ++m) {
        int rbase = crow0 + (m << 4) + ((lane >> 4) << 2);
#pragma unroll
        for (int n = 0; n < NF; ++n) {
            int col = ccol0 + (n << 4) + ln15;
            float bv = (MODE == 4 || MODE == 5) ? 0.f : bias[bcol + col];
#pragma unroll
            for (int r = 0; r < 4; ++r) {
                float v = acc[m][n][r] + bv;
                if (MODE == 2) v = v > 0.f ? v : 0.f;
                int row = rbase + r;
                SMEM[row * BN + (col ^ ((row & 7) << 3))] = f2b(v);
            }
        }
    }
    LGKM0;
    BARRIER;
    u16* outp = (MODE == 4 || MODE == 5) ? Pout : Cb;
    constexpr int CHT = BM * BN / 8 / T;
#pragma unroll
    for (int k = 0; k < CHT; ++k) {
        int c = tid + k * T;
        int row = c / (BN / 8), co = (c % (BN / 8)) * 8;
        u16x8 vv = *(const u16x8*)&SMEM[row * BN + (co ^ ((row & 7) << 3))];
        *(u16x8*)&outp[(long)(brow + row) * ldc + bcol + co] = vv;
        if (MODE == 1) {
            int cg = bcol + co;        // 8-chunks never straddle 1024-boundaries
            if (cg >= 1024) {
                int cc = cg - 1024;
                long kbase = (long)(cc >> 10) * 4194304 + (long)(brow + row) * 1024 + (cc & 1023);
                float4 f0 = { b2f(vv[0]), b2f(vv[1]), b2f(vv[2]), b2f(vv[3]) };
                float4 f1 = { b2f(vv[4]), b2f(vv[5]), b2f(vv[6]), b2f(vv[7]) };
                *(float4*)&KV[kbase] = f0;
                *(float4*)&KV[kbase + 4] = f1;
            }
        }
    }
#undef RD_A
#undef RD_B
#undef MM
}

// ---------------- K^T V partial sums (t-chunked, f32 atomics) ----------------
// grid (16 tchunks of 128, 32 bh)
__global__ __launch_bounds__(256) void ktv_partial(const u16* __restrict__ QKVB,
                                                   float* __restrict__ KTVF) {
    __shared__ __align__(16) u16 Ks[64 * 64];
    __shared__ __align__(16) u16 Vs[64 * 64];
    int tid = threadIdx.x;
    int tc = blockIdx.x, bh = blockIdx.y;
    int b = bh >> 4, h = bh & 15;
    int j = tid & 63, i0 = (tid >> 6) * 16;
    float acc[16] = {};
    for (int st = 0; st < 2; ++st) {
        int t0 = tc * 128 + st * 64;
        __syncthreads();
#pragma unroll
        for (int i = 0; i < 2; ++i) {
            int c = i * 256 + tid;
            long base = (long)(b * 2048 + t0 + (c >> 3)) * 3072 + h * 64 + (c & 7) * 8;
            *(u16x8*)&Ks[c * 8] = *(const u16x8*)&QKVB[base + 1024];
            *(u16x8*)&Vs[c * 8] = *(const u16x8*)&QKVB[base + 2048];
        }
        __syncthreads();
        for (int tt = 0; tt < 64; ++tt) {
            float vj = b2f(Vs[tt * 64 + j]);
            u16x8 k0 = *(const u16x8*)&Ks[tt * 64 + i0];
            u16x8 k1 = *(const u16x8*)&Ks[tt * 64 + i0 + 8];
#pragma unroll
            for (int r = 0; r < 8; ++r) acc[r] += b2f(k0[r]) * vj;
#pragma unroll
            for (int r = 0; r < 8; ++r) acc[r + 8] += b2f(k1[r]) * vj;
        }
    }
#pragma unroll
    for (int r = 0; r < 16; ++r)
        atomicAdd(&KTVF[bh * 4096 + (i0 + r) * 64 + j], acc[r]);
}

// ---------------- fold KTV into wp: WPBT[b][j][h*64+e] = sum_e' KTV[bh][e][e']*0.125
//                  * wp[(h*64+e')][j]   (wp accessed via WPT[j][d])
// grid (4 j-tiles, 32 bh); 256 thr, 4 waves; per wave 64 j rows.
__global__ __launch_bounds__(256) void wpb_kernel(const float* __restrict__ KTVF,
                                                  const u16* __restrict__ WPT,
                                                  u16* __restrict__ WPBT) {
    __shared__ __align__(16) u16 Ks[64 * 72];   // padded rows (72) to break bank conflicts
    int tid = threadIdx.x, lane = tid & 63, w = tid >> 6;
    int jt = blockIdx.x, bh = blockIdx.y;
    int b = bh >> 4, h = bh & 15;
    const float* kt = KTVF + bh * 4096;
    {   // load + scale(0.125) + cast 16 f32/thread into padded LDS
        int idx = tid * 16;
        int e = idx >> 6, ep = idx & 63;
        float4 v0 = *(const float4*)&kt[idx];
        float4 v1 = *(const float4*)&kt[idx + 4];
        float4 v2 = *(const float4*)&kt[idx + 8];
        float4 v3 = *(const float4*)&kt[idx + 12];
        u16x8 o0 = { f2b(v0.x * 0.125f), f2b(v0.y * 0.125f), f2b(v0.z * 0.125f), f2b(v0.w * 0.125f),
                     f2b(v1.x * 0.125f), f2b(v1.y * 0.125f), f2b(v1.z * 0.125f), f2b(v1.w * 0.125f) };
        u16x8 o1 = { f2b(v2.x * 0.125f), f2b(v2.y * 0.125f), f2b(v2.z * 0.125f), f2b(v2.w * 0.125f),
                     f2b(v3.x * 0.125f), f2b(v3.y * 0.125f), f2b(v3.z * 0.125f), f2b(v3.w * 0.125f) };
        *(u16x8*)&Ks[e * 72 + ep] = o0;
        *(u16x8*)&Ks[e * 72 + ep + 8] = o1;
    }
    __syncthreads();
    int ln15 = lane & 15, l4 = lane >> 4;
    bf16x8 bf[4][2];
#pragma unroll
    for (int n = 0; n < 4; ++n)
#pragma unroll
        for (int kh = 0; kh < 2; ++kh)
            bf[n][kh] = lds_frag(&Ks[(n * 16 + ln15) * 72 + kh * 32 + l4 * 8]);
    int j0 = jt * 256 + w * 64;
    f32x4 acc[4][4] = {};
#pragma unroll
    for (int m = 0; m < 4; ++m) {
        const u16* ap = &WPT[(long)(j0 + m * 16 + ln15) * 1024 + h * 64 + l4 * 8];
        bf16x8 a0 = __builtin_bit_cast(bf16x8, *(const u16x8*)ap);
        bf16x8 a1 = __builtin_bit_cast(bf16x8, *(const u16x8*)(ap + 32));
#pragma unroll
        for (int n = 0; n < 4; ++n) {
            acc[m][n] = __builtin_amdgcn_mfma_f32_16x16x32_bf16(a0, bf[n][0], acc[m][n], 0, 0, 0);
            acc[m][n] = __builtin_amdgcn_mfma_f32_16x16x32_bf16(a1, bf[n][1], acc[m][n], 0, 0, 0);
        }
    }
#pragma unroll
    for (int m = 0; m < 4; ++m)
#pragma unroll
        for (int n = 0; n < 4; ++n)
#pragma unroll
            for (int r = 0; r < 4; ++r)
                WPBT[(long)b * 1048576 + (long)(j0 + m * 16 + l4 * 4 + r) * 1024 +
                     h * 64 + n * 16 + ln15] = f2b(acc[m][n][r]);
}

// ---------------- layernorm kernels ----------------
__device__ __forceinline__ void block_reduce2(float& a, float& b) {
    __syncthreads();
#pragma unroll
    for (int off = 32; off; off >>= 1) {
        a += __shfl_down(a, off);
        b += __shfl_down(b, off);
    }
    __shared__ float sa[4], sb[4];
    int wid = threadIdx.x >> 6, lane = threadIdx.x & 63;
    if (lane == 0) { sa[wid] = a; sb[wid] = b; }
    __syncthreads();
    a = sa[0] + sa[1] + sa[2] + sa[3];
    b = sb[0] + sb[1] + sb[2] + sb[3];
}

// out1 = LN(x + (q0+q1 + bp)) ; write bf16 only  (q* = bf16 partials)
__global__ __launch_bounds__(256) void ln1_kernel(
    const float* __restrict__ x,
    const u16* __restrict__ q0, const u16* __restrict__ q1,
    const float* __restrict__ bp,
    const float* __restrict__ g, const float* __restrict__ bt,
    u16* __restrict__ out1b) {
    int row = blockIdx.x, tid = threadIdx.x;
    long base = (long)row * 1024 + tid * 4;
    float4 xv = *(const float4*)&x[base];
    u16x4 a0 = *(const u16x4*)&q0[base];
    u16x4 a1 = *(const u16x4*)&q1[base];
    float4 bb = *(const float4*)&bp[tid * 4];
    float xa[4] = { xv.x, xv.y, xv.z, xv.w };
    float bba[4] = { bb.x, bb.y, bb.z, bb.w };
    float s[4];
#pragma unroll
    for (int r = 0; r < 4; ++r)
        s[r] = xa[r] + b2f(a0[r]) + b2f(a1[r]) + bba[r];
    float sum = s[0] + s[1] + s[2] + s[3];
    float sq = s[0] * s[0] + s[1] * s[1] + s[2] * s[2] + s[3] * s[3];
    block_reduce2(sum, sq);
    float mu = sum * (1.f / 1024.f);
    float var = sq * (1.f / 1024.f) - mu * mu;
    float rs = rsqrtf(var + 1e-5f);
    float o0 = (s[0] - mu) * rs * g[tid * 4 + 0] + bt[tid * 4 + 0];
    float o1 = (s[1] - mu) * rs * g[tid * 4 + 1] + bt[tid * 4 + 1];
    float o2 = (s[2] - mu) * rs * g[tid * 4 + 2] + bt[tid * 4 + 2];
    float o3 = (s[3] - mu) * rs * g[tid * 4 + 3] + bt[tid * 4 + 3];
    u16x4 ob = (u16x4){ f2b(o0), f2b(o1), f2b(o2), f2b(o3) };
    *(u16x4*)&out1b[base] = ob;
}

// ff = (q0+q1)+b2 (bf16 partials); ffo = LN(out1+ff); out2 = LN(out1+ffo)
// out1 read as bf16 (out1b)
__global__ __launch_bounds__(256) void lnf_kernel(
    const u16* __restrict__ out1b,
    const u16* __restrict__ q0, const u16* __restrict__ q1,
    const float* __restrict__ b2,
    const float* __restrict__ lnfg, const float* __restrict__ lnfb,
    const float* __restrict__ ln2g, const float* __restrict__ ln2b,
    float* __restrict__ out2) {
    int row = blockIdx.x, tid = threadIdx.x;
    long base = (long)row * 1024 + tid * 4;
    u16x4 o1v = *(const u16x4*)&out1b[base];
    u16x4 a0 = *(const u16x4*)&q0[base];
    u16x4 a1 = *(const u16x4*)&q1[base];
    float4 bb = *(const float4*)&b2[tid * 4];
    float o1a[4] = { b2f(o1v[0]), b2f(o1v[1]), b2f(o1v[2]), b2f(o1v[3]) };
    float bba[4] = { bb.x, bb.y, bb.z, bb.w };
    float s1[4];
#pragma unroll
    for (int r = 0; r < 4; ++r)
        s1[r] = o1a[r] + b2f(a0[r]) + b2f(a1[r]) + bba[r];
    float sum = s1[0] + s1[1] + s1[2] + s1[3];
    float sq = s1[0] * s1[0] + s1[1] * s1[1] + s1[2] * s1[2] + s1[3] * s1[3];
    block_reduce2(sum, sq);
    float mu = sum * (1.f / 1024.f);
    float rs = rsqrtf(sq * (1.f / 1024.f) - mu * mu + 1e-5f);
    float s2[4];
#pragma unroll
    for (int r = 0; r < 4; ++r) {
        float ffo = (s1[r] - mu) * rs * lnfg[tid * 4 + r] + lnfb[tid * 4 + r];
        s2[r] = o1a[r] + ffo;
    }
    float sum2 = s2[0] + s2[1] + s2[2] + s2[3];
    float sq2 = s2[0] * s2[0] + s2[1] * s2[1] + s2[2] * s2[2] + s2[3] * s2[3];
    block_reduce2(sum2, sq2);
    float mu2 = sum2 * (1.f / 1024.f);
    float rs2 = rsqrtf(sq2 * (1.f / 1024.f) - mu2 * mu2 + 1e-5f);
    float4 o;
    o.x = (s2[0] - mu2) * rs2 * ln2g[tid * 4 + 0] + ln2b[tid * 4 + 0];
    o.y = (s2[1] - mu2) * rs2 * ln2g[tid * 4 + 1] + ln2b[tid * 4 + 1];
    o.z = (s2[2] - mu2) * rs2 * ln2g[tid * 4 + 2] + ln2b[tid * 4 + 2];
    o.w = (s2[3] - mu2) * rs2 * ln2g[tid * 4 + 3] + ln2b[tid * 4 + 3];
    *(float4*)&out2[base] = o;
}

// ---------------- launcher ----------------
extern "C" void kernel_launch(void* const* d_in, const int* in_sizes, int n_in,
                              void* d_out, int out_size, void* d_ws, size_t ws_size,
                              hipStream_t stream) {
    const float* x    = (const float*)d_in[0];
    const float* wq   = (const float*)d_in[1];
    const float* bq   = (const float*)d_in[2];
    const float* wk   = (const float*)d_in[3];
    const float* bk   = (const float*)d_in[4];
    const float* wv   = (const float*)d_in[5];
    const float* bv   = (const float*)d_in[6];
    const float* wp   = (const float*)d_in[7];
    const float* bp   = (const float*)d_in[8];
    const float* w1   = (const float*)d_in[9];
    const float* b1   = (const float*)d_in[10];
    const float* w2   = (const float*)d_in[11];
    const float* b2   = (const float*)d_in[12];
    const float* ln1g = (const float*)d_in[13];
    const float* ln1b = (const float*)d_in[14];
    const float* lnfg = (const float*)d_in[15];
    const float* lnfb = (const float*)d_in[16];
    const float* ln2g = (const float*)d_in[17];
    const float* ln2b = (const float*)d_in[18];

    float* out2 = (float*)d_out;
    float* kv   = (float*)d_out + 4194304;   // Kc then Vc

    // workspace layout (bytes). Liveness:
    char* ws = (char*)d_ws;
    u16*   XB     = (u16*)  (ws + 0);          // 8 MB (dead after G1); WPBT (dead after G3); Q5_0
    u16*   WPBT   = XB;                        // 4 MB: 2 batches x 1024x1024 bf16
    u16*   WQKVT  = (u16*)  (ws + 8388608);    // 6.3 MB (dead after G1)
    float* BQKV   = (float*)(ws + 14680064);   // 12 KB (dead after G1)
    u16*   WPT    = (u16*)  (ws + 14692352);   // 2 MB (dead after wpb)
    u16*   W1T    = (u16*)  (ws + 16789504);   // 8 MB (dead after G4)
    u16*   W2T    = (u16*)  (ws + 25178112);   // 8 MB (live through G5)
    float* KTVF   = (float*)(ws + 33566720);   // 512 KB (dead after wpb)
    u16*   QKVB   = (u16*)  (ws + 34353152);   // 24 MB (dead after G3); OUT1B (live to lnf)
    u16*   OUT1B  = QKVB;
    u16*   Q3_0   = (u16*)  (ws + 59518976);   // 8 MB (dead after ln1)
    u16*   Q3_1   = (u16*)  (ws + 67907584);   // 8 MB (dead after ln1)
    u16*   Q5_1   = (u16*)  (ws + 76296192);   // 8 MB
    u16*   H1     = (u16*)  (ws + 93073408);   // 32 MB (live through G5)
    u16*   Q5_0   = (u16*)  (ws + 0);          // 8 MB (over XB/WPBT, dead after G3)
    (void)ws_size; (void)in_sizes; (void)n_in; (void)out_size;

    hipMemsetAsync(KTVF, 0, 32 * 4096 * 4, stream);
    prep_all<<<16396, 256, 0, stream>>>(x, XB, wq, wk, wv, WQKVT,
                                        wp, w1, w2, WPT, W1T, W2T,
                                        bq, bk, bv, BQKV);

    // G1: QKV = X @ Wqkv + b  (128x384 tile, grid 256 full-fill, col-outer;
    //     f32 KV side-out) — R11-proven config (45.5 us)
    gemmT<1, 2, 4, 4, 6, true><<<256, 512, 0, stream>>>(
        XB, WQKVT, BQKV, QKVB, kv, nullptr, nullptr,
        4096, 3072, 1024, 1024, 1024, 3072, 0);
    ktv_partial<<<dim3(16, 32), 256, 0, stream>>>(QKVB, KTVF);
    // fold (KTV*s) into wp per (b,h): WPBT[b] = block-stacked KTV_h @ wp_h
    wpb_kernel<<<dim3(4, 32), 256, 0, stream>>>(KTVF, WPT, WPBT);

    // G3: out[b] = Q[b] @ WPBT[b]  (A = QKVB Q-cols, lda=3072; batch-B by row half;
    //     128x128 tile, split-K x2, 512 blocks, row-outer)
    gemmT<5, 2, 2, 4, 4, false><<<512, 256, 0, stream>>>(
        QKVB, WPBT, nullptr, (u16*)(WPBT + 1048576), nullptr, Q3_0, Q3_1,
        4096, 1024, 1024, 3072, 1024, 1024, 512);
    ln1_kernel<<<4096, 256, 0, stream>>>(x, Q3_0, Q3_1, bp, ln1g, ln1b, OUT1B);

    // G4: h1 = relu(out1 @ w1 + b1) (256x256 tile, grid 256, 512 thr — R7-proven)
    gemmT<2, 2, 4, 8, 4, false><<<256, 512, 0, stream>>>(
        OUT1B, W1T, b1, H1, nullptr, nullptr, nullptr,
        4096, 4096, 1024, 1024, 1024, 4096, 0);
    // G5: ff = h1 @ w2 (128x128 tile, split-K x2 over K=4096, 512 blocks, row-outer)
    gemmT<4, 2, 2, 4, 4, false><<<512, 256, 0, stream>>>(
        H1, W2T, nullptr, nullptr, nullptr, Q5_0, Q5_1,
        4096, 1024, 4096, 4096, 4096, 1024, 2048);
    lnf_kernel<<<4096, 256, 0, stream>>>(OUT1B, Q5_0, Q5_1, b2,
                                         lnfg, lnfb, ln2g, ln2b, out2);
}

// Round 14
// 187.272 us; speedup vs baseline: 1.1920x; 1.0294x over previous
//
#include <hip/hip_runtime.h>

typedef unsigned short u16;
typedef __attribute__((ext_vector_type(4))) float f32x4;
typedef __attribute__((ext_vector_type(8))) __bf16 bf16x8;
typedef __attribute__((ext_vector_type(8))) unsigned short u16x8;
typedef __attribute__((ext_vector_type(4))) unsigned short u16x4;

// ---------- scalar bf16 helpers ----------
__device__ __forceinline__ u16 f2b(float f) {
    unsigned int u = __builtin_bit_cast(unsigned int, f);
    u = (u + 0x7FFFu + ((u >> 16) & 1u)) >> 16;
    return (u16)u;
}
__device__ __forceinline__ float b2f(u16 h) {
    unsigned int u = ((unsigned int)h) << 16;
    return __builtin_bit_cast(float, u);
}

// async global->LDS, 16B per lane; LDS dest is wave-uniform base (+lane*16 by HW)
__device__ __forceinline__ void gload_lds16(const u16* g, u16* l) {
    __builtin_amdgcn_global_load_lds(
        (const __attribute__((address_space(1))) void*)g,
        (__attribute__((address_space(3))) void*)l,
        16, 0, 0);
}

__device__ __forceinline__ bf16x8 lds_frag(const u16* p) {
    u16x8 t = *(const u16x8*)p;
    return __builtin_bit_cast(bf16x8, t);
}

#define FENCE asm volatile("" ::: "memory")
#define BARRIER do { FENCE; __builtin_amdgcn_s_barrier(); FENCE; \
                     __builtin_amdgcn_sched_barrier(0); } while (0)
#define SCHED0 __builtin_amdgcn_sched_barrier(0)
#define LGKM0 do { asm volatile("s_waitcnt lgkmcnt(0)" ::: "memory"); \
                   __builtin_amdgcn_sched_barrier(0); } while (0)
#define WAIT_VM8 do { asm volatile("s_waitcnt vmcnt(8)" ::: "memory"); \
                      __builtin_amdgcn_sched_barrier(0); } while (0)
#define WAIT_VM0 do { asm volatile("s_waitcnt vmcnt(0)" ::: "memory"); \
                      __builtin_amdgcn_sched_barrier(0); } while (0)

// ---------------- merged prep kernel: one dispatch ----------------
// blocks [0,4096): cast x -> bf16
// [4096,7168): tr_wqkv (48 z x 64 sub)
// [7168,16384): wp/w1/w2 transposes
// [16384,16396): QKV bias pack
// [16396,16428): zero KTVF (512 KB)
__global__ __launch_bounds__(256) void prep_all(
    const float* __restrict__ x, u16* __restrict__ XB,
    const float* __restrict__ wq, const float* __restrict__ wk, const float* __restrict__ wv,
    u16* __restrict__ WQKVT,
    const float* __restrict__ wp, const float* __restrict__ w1, const float* __restrict__ w2,
    u16* __restrict__ WPT, u16* __restrict__ W1T, u16* __restrict__ W2T,
    const float* __restrict__ bq, const float* __restrict__ bk, const float* __restrict__ bv,
    float* __restrict__ BI, float* __restrict__ KTVF) {
    int bid = blockIdx.x;
    if (bid < 4096) {
        int i = (bid * 256 + threadIdx.x) * 4;
        float4 v = *(const float4*)&x[i];
        u16x4 o = { f2b(v.x), f2b(v.y), f2b(v.z), f2b(v.w) };
        *(u16x4*)&XB[i] = o;
        return;
    }
    if (bid >= 16396) {   // zero KTVF: 32 blocks x 256 thr x 16 f32
        int i = ((bid - 16396) * 256 + threadIdx.x) * 16;
        float4 z = { 0.f, 0.f, 0.f, 0.f };
        *(float4*)&KTVF[i] = z;
        *(float4*)&KTVF[i + 4] = z;
        *(float4*)&KTVF[i + 8] = z;
        *(float4*)&KTVF[i + 12] = z;
        return;
    }
    if (bid >= 16384) {
        int i = (bid - 16384) * 256 + threadIdx.x;   // < 3072
        const float* b = (i < 1024) ? bq : (i < 2048) ? bk : bv;
        BI[i] = b[((i & 1023) >> 6) * 64 + (i & 63)];
        return;
    }
    __shared__ float tile[32][33];
    int tx = threadIdx.x & 31, ty = threadIdx.x >> 5;
    if (bid < 7168) {   // tr_wqkv
        int r = bid - 4096;
        int z = r >> 6, sub = r & 63;
        int sel = z >> 4, h = z & 15;
        const float* w = (sel == 0) ? wq : (sel == 1) ? wk : wv;
        w += (long)h * 65536;              // [1024][64]
        int d0 = (sub & 31) * 32, e0 = (sub >> 5) * 32;
#pragma unroll
        for (int i = 0; i < 32; i += 8)
            tile[ty + i][tx] = w[(long)(d0 + ty + i) * 64 + e0 + tx];
        __syncthreads();
#pragma unroll
        for (int i = 0; i < 32; i += 8)
            WQKVT[((long)(sel * 1024 + h * 64 + e0 + ty + i)) * 1024 + d0 + tx] =
                f2b(tile[tx][ty + i]);
        return;
    }
    int b0 = bid - 7168;
    const float* in; u16* out; int C, R, bx, by;
    if (b0 < 1024)      { in = wp; out = WPT; R = 1024; C = 1024; bx = b0 & 31;  by = b0 >> 5; }
    else if (b0 < 5120) { int b = b0 - 1024; in = w1; out = W1T; R = 1024; C = 4096; bx = b & 127; by = b >> 7; }
    else                { int b = b0 - 5120; in = w2; out = W2T; R = 4096; C = 1024; bx = b & 31;  by = b >> 5; }
    int r0 = by * 32, c0 = bx * 32;
#pragma unroll
    for (int i = 0; i < 32; i += 8)
        tile[ty + i][tx] = in[(long)(r0 + ty + i) * C + c0 + tx];
    __syncthreads();
#pragma unroll
    for (int i = 0; i < 32; i += 8)
        out[(long)(c0 + ty + i) * R + r0 + tx] = f2b(tile[tx][ty + i]);
}

// ---------------- templated tiled GEMM, sub-phase pipelined (LDS || MFMA) -----
// C[M,N] = A[M,K] @ BT[N,K]^T. Tile BM=WM*MF*16, BN=WN*NF*16, BK=64, T=WM*WN*64.
// MODE 1: +bias, bf16 out + f32 KV side-write for cols>=1024 (G1).
// MODE 2: +bias, relu (G4). MODE 4: 2-way split-K bf16 partials to Q0/Q1 (G5).
// MODE 5: MODE4 + batch-B: rows >= M/2 use BT2 = (const u16*)Cb (G3 batched wp).
// Pipeline (R7-proven): 4 sub-phases per K-tile; sub-phase s issues ds_reads for
// s+1 into the alternate register frag buffer, then MFMAs current frags; compiler
// emits progressive counted lgkmcnt. 2 barriers/tile; counted vmcnt only.
// LDS byte-swizzle col^=(row&7)<<4 via inverse-swizzled global src (rule #21).
// Epilogue: acc -> swizzled LDS repack -> coalesced u16x8 stores (+f32 KV for MODE 1).
template <int MODE, int WM, int WN, int MF, int NF, bool COLOUT>
__global__ __launch_bounds__(WM * WN * 64, 2) void gemmT(
    const u16* __restrict__ A, const u16* __restrict__ BT, const float* __restrict__ bias,
    u16* __restrict__ Cb, float* __restrict__ KV,
    u16* __restrict__ Q0, u16* __restrict__ Q1,
    int M, int N, int K, int lda, int ldb, int ldc, int kchunk) {
    constexpr int T   = WM * WN * 64;
    constexpr int BM  = WM * MF * 16;
    constexpr int BN  = WN * NF * 16;
    constexpr int RPI = T / 8;            // rows per gload instr
    constexpr int LA  = BM / RPI;         // gload instrs per A K-tile
    constexpr int LB  = BN / RPI;
    constexpr int EPI = T * 8;            // LDS elems per gload instr
    constexpr int MFH = MF / 2;
    constexpr int ASZ = BM * 64, BSZ = BN * 64;
    __shared__ __align__(16) u16 SMEM[2 * ASZ + 2 * BSZ];
    u16* As0 = SMEM;
    u16* As1 = SMEM + ASZ;
    u16* Bs0 = SMEM + 2 * ASZ;
    u16* Bs1 = SMEM + 2 * ASZ + BSZ;
    const int tid = threadIdx.x;
    const int lane = tid & 63;
    const int wid = tid >> 6;
    const int wr = wid / WN, wc = wid % WN;
    const int ntile = N / BN;
    const int mtile = M / BM;
    int bid = blockIdx.x;
    int kb = 0, ksz = K;
    u16* Pout = Q0;
    if (MODE == 4 || MODE == 5) {
        int tiles = mtile * ntile;
        int sk = bid / tiles; bid -= sk * tiles;
        kb = sk * kchunk;
        int rem = K - kb; ksz = rem < kchunk ? rem : kchunk;
        Pout = sk ? Q1 : Q0;
    }
    // XCD-chunked bijective swizzle (tile count multiple of 8)
    {
        int q = (mtile * ntile) >> 3;
        bid = (bid & 7) * q + (bid >> 3);
    }
    int bi, bj;
    if (COLOUT) { bj = bid / mtile; bi = bid % mtile; }   // XCD owns B col-panels (G1)
    else        { bi = bid / ntile; bj = bid % ntile; }   // XCD owns A row-panels
    const int brow = bi * BM, bcol = bj * BN;
    const int nt = ksz >> 6;              // BK=64 tiles
    const u16* BTe = BT;
    if (MODE == 5 && brow >= (M >> 1)) BTe = (const u16*)Cb;   // batch-1 B panel

    // ---- staging addressing (inverse-swizzled global source, linear LDS dest)
    const int srow = tid >> 3;
    const int scol = ((tid & 7) ^ (srow & 7)) << 3;
    const u16* ag = A + (long)(brow + srow) * lda + kb + scol;
    const u16* bg = BTe + (long)(bcol + srow) * ldb + kb + scol;
    const long aI = (long)RPI * lda, bI = (long)RPI * ldb;
    const int sdst = tid << 3;

    auto STAGE = [&](u16* lA, u16* lB, int t) {
#pragma unroll
        for (int j = 0; j < LA; ++j)
            gload_lds16(ag + ((long)t << 6) + j * aI, &lA[j * EPI + sdst]);
#pragma unroll
        for (int j = 0; j < LB; ++j)
            gload_lds16(bg + ((long)t << 6) + j * bI, &lB[j * EPI + sdst]);
    };

    f32x4 acc[MF][NF] = {};
    bf16x8 af0[MFH], af1[MFH], bf0[NF], bf1[NF];

    // ---- fragment read addressing (swizzled)
    const int ln15 = lane & 15;
    const int eoff = (((lane >> 4) << 3) ^ ((lane & 7) << 3));
    const int arow0 = wr * (MF * 16) + ln15;
    const int brow0 = wc * (NF * 16) + ln15;

#define RD_A(dst, S, kh, mh)                                                   \
    _Pragma("unroll") for (int m4 = 0; m4 < MFH; ++m4)                         \
        dst[m4] = lds_frag(&(S)[((arow0 + (((mh) * MFH + m4) << 4)) << 6) +    \
                                (eoff ^ ((kh) << 5))]);
#define RD_B(dst, S, kh)                                                       \
    _Pragma("unroll") for (int n = 0; n < NF; ++n)                             \
        dst[n] = lds_frag(&(S)[((brow0 + (n << 4)) << 6) + (eoff ^ ((kh) << 5))]);
#define MM(a, b, mh) do {                                                      \
    __builtin_amdgcn_s_setprio(1);                                             \
    _Pragma("unroll") for (int m4 = 0; m4 < MFH; ++m4)                         \
        _Pragma("unroll") for (int n = 0; n < NF; ++n)                         \
            acc[(mh) * MFH + m4][n] = __builtin_amdgcn_mfma_f32_16x16x32_bf16( \
                a[m4], b[n], acc[(mh) * MFH + m4][n], 0, 0, 0);                \
    __builtin_amdgcn_s_setprio(0);                                             \
} while (0)

    // ---- prologue: stage t0 + t1; retire t0; initial frags
    STAGE(As0, Bs0, 0);
    if (nt > 1) { STAGE(As1, Bs1, 1); WAIT_VM8; } else { WAIT_VM0; }
    BARRIER;
    RD_B(bf0, Bs0, 0);
    RD_A(af0, As0, 0, 0);

    u16 *Ac = As0, *Bc = Bs0, *Ao = As1, *Bo = Bs1;
    for (int t = 0; t < nt; ++t) {
        const bool hasN = (t + 1 < nt);
        const bool hasNN = (t + 2 < nt);
        // s0: compute (kh0, mh0); prefetch (kh0, mh1)
        RD_A(af1, Ac, 0, 1);
        MM(af0, bf0, 0);
        SCHED0;
        // s1: compute (kh0, mh1); prefetch kh1 B + (kh1, mh0)
        RD_B(bf1, Bc, 1);
        RD_A(af0, Ac, 1, 0);
        MM(af1, bf0, 1);
        SCHED0;
        // s2: compute (kh1, mh0); prefetch (kh1, mh1)
        RD_A(af1, Ac, 1, 1);
        MM(af0, bf1, 0);
        WAIT_VM0;            // stage(t+1 -> other slot) retired
        BARRIER;             // B1: next tile visible
        // s3: compute (kh1, mh1); prefetch next tile (kh0) from other slot
        if (hasN) { RD_B(bf0, Bo, 0); RD_A(af0, Ao, 0, 0); }
        MM(af1, bf1, 1);
        BARRIER;             // B2: all waves done reading current slot
        if (hasNN) STAGE(Ac, Bc, t + 2);
        SCHED0;
        u16* tp;
        tp = Ac; Ac = Ao; Ao = tp;
        tp = Bc; Bc = Bo; Bo = tp;
    }

    // ---- epilogue: swizzled LDS repack -> coalesced stores
    const int crow0 = wr * (MF * 16), ccol0 = wc * (NF * 16);
#pragma unroll
    for (int m = 0; m < MF; ++m) {
        int rbase = crow0 + (m << 4) + ((lane >> 4) << 2);
#pragma unroll
        for (int n = 0; n < NF; ++n) {
            int col = ccol0 + (n << 4) + ln15;
            float bv = (MODE == 4 || MODE == 5) ? 0.f : bias[bcol + col];
#pragma unroll
            for (int r = 0; r < 4; ++r) {
                float v = acc[m][n][r] + bv;
                if (MODE == 2) v = v > 0.f ? v : 0.f;
                int row = rbase + r;
                SMEM[row * BN + (col ^ ((row & 7) << 3))] = f2b(v);
            }
        }
    }
    LGKM0;
    BARRIER;
    u16* outp = (MODE == 4 || MODE == 5) ? Pout : Cb;
    constexpr int CHT = BM * BN / 8 / T;
#pragma unroll
    for (int k = 0; k < CHT; ++k) {
        int c = tid + k * T;
        int row = c / (BN / 8), co = (c % (BN / 8)) * 8;
        u16x8 vv = *(const u16x8*)&SMEM[row * BN + (co ^ ((row & 7) << 3))];
        *(u16x8*)&outp[(long)(brow + row) * ldc + bcol + co] = vv;
        if (MODE == 1) {
            int cg = bcol + co;        // 8-chunks never straddle 1024-boundaries
            if (cg >= 1024) {
                int cc = cg - 1024;
                long kbase = (long)(cc >> 10) * 4194304 + (long)(brow + row) * 1024 + (cc & 1023);
                float4 f0 = { b2f(vv[0]), b2f(vv[1]), b2f(vv[2]), b2f(vv[3]) };
                float4 f1 = { b2f(vv[4]), b2f(vv[5]), b2f(vv[6]), b2f(vv[7]) };
                *(float4*)&KV[kbase] = f0;
                *(float4*)&KV[kbase + 4] = f1;
            }
        }
    }
#undef RD_A
#undef RD_B
#undef MM
}

// ---------------- K^T V partial sums (t-chunked, f32 atomics) ----------------
// grid (16 tchunks of 128, 32 bh)
__global__ __launch_bounds__(256) void ktv_partial(const u16* __restrict__ QKVB,
                                                   float* __restrict__ KTVF) {
    __shared__ __align__(16) u16 Ks[64 * 64];
    __shared__ __align__(16) u16 Vs[64 * 64];
    int tid = threadIdx.x;
    int tc = blockIdx.x, bh = blockIdx.y;
    int b = bh >> 4, h = bh & 15;
    int j = tid & 63, i0 = (tid >> 6) * 16;
    float acc[16] = {};
    for (int st = 0; st < 2; ++st) {
        int t0 = tc * 128 + st * 64;
        __syncthreads();
#pragma unroll
        for (int i = 0; i < 2; ++i) {
            int c = i * 256 + tid;
            long base = (long)(b * 2048 + t0 + (c >> 3)) * 3072 + h * 64 + (c & 7) * 8;
            *(u16x8*)&Ks[c * 8] = *(const u16x8*)&QKVB[base + 1024];
            *(u16x8*)&Vs[c * 8] = *(const u16x8*)&QKVB[base + 2048];
        }
        __syncthreads();
        for (int tt = 0; tt < 64; ++tt) {
            float vj = b2f(Vs[tt * 64 + j]);
            u16x8 k0 = *(const u16x8*)&Ks[tt * 64 + i0];
            u16x8 k1 = *(const u16x8*)&Ks[tt * 64 + i0 + 8];
#pragma unroll
            for (int r = 0; r < 8; ++r) acc[r] += b2f(k0[r]) * vj;
#pragma unroll
            for (int r = 0; r < 8; ++r) acc[r + 8] += b2f(k1[r]) * vj;
        }
    }
#pragma unroll
    for (int r = 0; r < 16; ++r)
        atomicAdd(&KTVF[bh * 4096 + (i0 + r) * 64 + j], acc[r]);
}

// ---------------- fold KTV into wp: WPBT[b][j][h*64+e] = sum_e' KTV[bh][e][e']*0.125
//                  * wp[(h*64+e')][j]   (wp accessed via WPT[j][d])
// grid (4 j-tiles, 32 bh); 256 thr, 4 waves; per wave 64 j rows.
__global__ __launch_bounds__(256) void wpb_kernel(const float* __restrict__ KTVF,
                                                  const u16* __restrict__ WPT,
                                                  u16* __restrict__ WPBT) {
    __shared__ __align__(16) u16 Ks[64 * 72];   // padded rows (72) to break bank conflicts
    int tid = threadIdx.x, lane = tid & 63, w = tid >> 6;
    int jt = blockIdx.x, bh = blockIdx.y;
    int b = bh >> 4, h = bh & 15;
    const float* kt = KTVF + bh * 4096;
    {   // load + scale(0.125) + cast 16 f32/thread into padded LDS
        int idx = tid * 16;
        int e = idx >> 6, ep = idx & 63;
        float4 v0 = *(const float4*)&kt[idx];
        float4 v1 = *(const float4*)&kt[idx + 4];
        float4 v2 = *(const float4*)&kt[idx + 8];
        float4 v3 = *(const float4*)&kt[idx + 12];
        u16x8 o0 = { f2b(v0.x * 0.125f), f2b(v0.y * 0.125f), f2b(v0.z * 0.125f), f2b(v0.w * 0.125f),
                     f2b(v1.x * 0.125f), f2b(v1.y * 0.125f), f2b(v1.z * 0.125f), f2b(v1.w * 0.125f) };
        u16x8 o1 = { f2b(v2.x * 0.125f), f2b(v2.y * 0.125f), f2b(v2.z * 0.125f), f2b(v2.w * 0.125f),
                     f2b(v3.x * 0.125f), f2b(v3.y * 0.125f), f2b(v3.z * 0.125f), f2b(v3.w * 0.125f) };
        *(u16x8*)&Ks[e * 72 + ep] = o0;
        *(u16x8*)&Ks[e * 72 + ep + 8] = o1;
    }
    __syncthreads();
    int ln15 = lane & 15, l4 = lane >> 4;
    bf16x8 bf[4][2];
#pragma unroll
    for (int n = 0; n < 4; ++n)
#pragma unroll
        for (int kh = 0; kh < 2; ++kh)
            bf[n][kh] = lds_frag(&Ks[(n * 16 + ln15) * 72 + kh * 32 + l4 * 8]);
    int j0 = jt * 256 + w * 64;
    f32x4 acc[4][4] = {};
#pragma unroll
    for (int m = 0; m < 4; ++m) {
        const u16* ap = &WPT[(long)(j0 + m * 16 + ln15) * 1024 + h * 64 + l4 * 8];
        bf16x8 a0 = __builtin_bit_cast(bf16x8, *(const u16x8*)ap);
        bf16x8 a1 = __builtin_bit_cast(bf16x8, *(const u16x8*)(ap + 32));
#pragma unroll
        for (int n = 0; n < 4; ++n) {
            acc[m][n] = __builtin_amdgcn_mfma_f32_16x16x32_bf16(a0, bf[n][0], acc[m][n], 0, 0, 0);
            acc[m][n] = __builtin_amdgcn_mfma_f32_16x16x32_bf16(a1, bf[n][1], acc[m][n], 0, 0, 0);
        }
    }
#pragma unroll
    for (int m = 0; m < 4; ++m)
#pragma unroll
        for (int n = 0; n < 4; ++n)
#pragma unroll
            for (int r = 0; r < 4; ++r)
                WPBT[(long)b * 1048576 + (long)(j0 + m * 16 + l4 * 4 + r) * 1024 +
                     h * 64 + n * 16 + ln15] = f2b(acc[m][n][r]);
}

// ---------------- layernorm kernels ----------------
__device__ __forceinline__ void block_reduce2(float& a, float& b) {
    __syncthreads();
#pragma unroll
    for (int off = 32; off; off >>= 1) {
        a += __shfl_down(a, off);
        b += __shfl_down(b, off);
    }
    __shared__ float sa[4], sb[4];
    int wid = threadIdx.x >> 6, lane = threadIdx.x & 63;
    if (lane == 0) { sa[wid] = a; sb[wid] = b; }
    __syncthreads();
    a = sa[0] + sa[1] + sa[2] + sa[3];
    b = sb[0] + sb[1] + sb[2] + sb[3];
}

// out1 = LN(x + (q0+q1 + bp)) ; write bf16 only  (q* = bf16 partials)
__global__ __launch_bounds__(256) void ln1_kernel(
    const float* __restrict__ x,
    const u16* __restrict__ q0, const u16* __restrict__ q1,
    const float* __restrict__ bp,
    const float* __restrict__ g, const float* __restrict__ bt,
    u16* __restrict__ out1b) {
    int row = blockIdx.x, tid = threadIdx.x;
    long base = (long)row * 1024 + tid * 4;
    float4 xv = *(const float4*)&x[base];
    u16x4 a0 = *(const u16x4*)&q0[base];
    u16x4 a1 = *(const u16x4*)&q1[base];
    float4 bb = *(const float4*)&bp[tid * 4];
    float xa[4] = { xv.x, xv.y, xv.z, xv.w };
    float bba[4] = { bb.x, bb.y, bb.z, bb.w };
    float s[4];
#pragma unroll
    for (int r = 0; r < 4; ++r)
        s[r] = xa[r] + b2f(a0[r]) + b2f(a1[r]) + bba[r];
    float sum = s[0] + s[1] + s[2] + s[3];
    float sq = s[0] * s[0] + s[1] * s[1] + s[2] * s[2] + s[3] * s[3];
    block_reduce2(sum, sq);
    float mu = sum * (1.f / 1024.f);
    float var = sq * (1.f / 1024.f) - mu * mu;
    float rs = rsqrtf(var + 1e-5f);
    float o0 = (s[0] - mu) * rs * g[tid * 4 + 0] + bt[tid * 4 + 0];
    float o1 = (s[1] - mu) * rs * g[tid * 4 + 1] + bt[tid * 4 + 1];
    float o2 = (s[2] - mu) * rs * g[tid * 4 + 2] + bt[tid * 4 + 2];
    float o3 = (s[3] - mu) * rs * g[tid * 4 + 3] + bt[tid * 4 + 3];
    u16x4 ob = (u16x4){ f2b(o0), f2b(o1), f2b(o2), f2b(o3) };
    *(u16x4*)&out1b[base] = ob;
}

// ff = (q0+q1)+b2 (bf16 partials); ffo = LN(out1+ff); out2 = LN(out1+ffo)
// out1 read as bf16 (out1b)
__global__ __launch_bounds__(256) void lnf_kernel(
    const u16* __restrict__ out1b,
    const u16* __restrict__ q0, const u16* __restrict__ q1,
    const float* __restrict__ b2,
    const float* __restrict__ lnfg, const float* __restrict__ lnfb,
    const float* __restrict__ ln2g, const float* __restrict__ ln2b,
    float* __restrict__ out2) {
    int row = blockIdx.x, tid = threadIdx.x;
    long base = (long)row * 1024 + tid * 4;
    u16x4 o1v = *(const u16x4*)&out1b[base];
    u16x4 a0 = *(const u16x4*)&q0[base];
    u16x4 a1 = *(const u16x4*)&q1[base];
    float4 bb = *(const float4*)&b2[tid * 4];
    float o1a[4] = { b2f(o1v[0]), b2f(o1v[1]), b2f(o1v[2]), b2f(o1v[3]) };
    float bba[4] = { bb.x, bb.y, bb.z, bb.w };
    float s1[4];
#pragma unroll
    for (int r = 0; r < 4; ++r)
        s1[r] = o1a[r] + b2f(a0[r]) + b2f(a1[r]) + bba[r];
    float sum = s1[0] + s1[1] + s1[2] + s1[3];
    float sq = s1[0] * s1[0] + s1[1] * s1[1] + s1[2] * s1[2] + s1[3] * s1[3];
    block_reduce2(sum, sq);
    float mu = sum * (1.f / 1024.f);
    float rs = rsqrtf(sq * (1.f / 1024.f) - mu * mu + 1e-5f);
    float s2[4];
#pragma unroll
    for (int r = 0; r < 4; ++r) {
        float ffo = (s1[r] - mu) * rs * lnfg[tid * 4 + r] + lnfb[tid * 4 + r];
        s2[r] = o1a[r] + ffo;
    }
    float sum2 = s2[0] + s2[1] + s2[2] + s2[3];
    float sq2 = s2[0] * s2[0] + s2[1] * s2[1] + s2[2] * s2[2] + s2[3] * s2[3];
    block_reduce2(sum2, sq2);
    float mu2 = sum2 * (1.f / 1024.f);
    float rs2 = rsqrtf(sq2 * (1.f / 1024.f) - mu2 * mu2 + 1e-5f);
    float4 o;
    o.x = (s2[0] - mu2) * rs2 * ln2g[tid * 4 + 0] + ln2b[tid * 4 + 0];
    o.y = (s2[1] - mu2) * rs2 * ln2g[tid * 4 + 1] + ln2b[tid * 4 + 1];
    o.z = (s2[2] - mu2) * rs2 * ln2g[tid * 4 + 2] + ln2b[tid * 4 + 2];
    o.w = (s2[3] - mu2) * rs2 * ln2g[tid * 4 + 3] + ln2b[tid * 4 + 3];
    *(float4*)&out2[base] = o;
}

// ---------------- launcher ----------------
extern "C" void kernel_launch(void* const* d_in, const int* in_sizes, int n_in,
                              void* d_out, int out_size, void* d_ws, size_t ws_size,
                              hipStream_t stream) {
    const float* x    = (const float*)d_in[0];
    const float* wq   = (const float*)d_in[1];
    const float* bq   = (const float*)d_in[2];
    const float* wk   = (const float*)d_in[3];
    const float* bk   = (const float*)d_in[4];
    const float* wv   = (const float*)d_in[5];
    const float* bv   = (const float*)d_in[6];
    const float* wp   = (const float*)d_in[7];
    const float* bp   = (const float*)d_in[8];
    const float* w1   = (const float*)d_in[9];
    const float* b1   = (const float*)d_in[10];
    const float* w2   = (const float*)d_in[11];
    const float* b2   = (const float*)d_in[12];
    const float* ln1g = (const float*)d_in[13];
    const float* ln1b = (const float*)d_in[14];
    const float* lnfg = (const float*)d_in[15];
    const float* lnfb = (const float*)d_in[16];
    const float* ln2g = (const float*)d_in[17];
    const float* ln2b = (const float*)d_in[18];

    float* out2 = (float*)d_out;
    float* kv   = (float*)d_out + 4194304;   // Kc then Vc

    // workspace layout (bytes). Liveness:
    char* ws = (char*)d_ws;
    u16*   XB     = (u16*)  (ws + 0);          // 8 MB (dead after G1); WPBT (dead after G3); Q5_0
    u16*   WPBT   = XB;                        // 4 MB: 2 batches x 1024x1024 bf16
    u16*   WQKVT  = (u16*)  (ws + 8388608);    // 6.3 MB (dead after G1)
    float* BQKV   = (float*)(ws + 14680064);   // 12 KB (dead after G1)
    u16*   WPT    = (u16*)  (ws + 14692352);   // 2 MB (dead after wpb)
    u16*   W1T    = (u16*)  (ws + 16789504);   // 8 MB (dead after G4)
    u16*   W2T    = (u16*)  (ws + 25178112);   // 8 MB (live through G5)
    float* KTVF   = (float*)(ws + 33566720);   // 512 KB (dead after wpb)
    u16*   QKVB   = (u16*)  (ws + 34353152);   // 24 MB (dead after G3); OUT1B (live to lnf)
    u16*   OUT1B  = QKVB;
    u16*   Q3_0   = (u16*)  (ws + 59518976);   // 8 MB (dead after ln1)
    u16*   Q3_1   = (u16*)  (ws + 67907584);   // 8 MB (dead after ln1)
    u16*   Q5_1   = (u16*)  (ws + 76296192);   // 8 MB
    u16*   H1     = (u16*)  (ws + 93073408);   // 32 MB (live through G5)
    u16*   Q5_0   = (u16*)  (ws + 0);          // 8 MB (over XB/WPBT, dead after G3)
    (void)ws_size; (void)in_sizes; (void)n_in; (void)out_size;

    prep_all<<<16428, 256, 0, stream>>>(x, XB, wq, wk, wv, WQKVT,
                                        wp, w1, w2, WPT, W1T, W2T,
                                        bq, bk, bv, BQKV, KTVF);

    // G1: QKV = X @ Wqkv + b  (128x384 tile, grid 256 full-fill, col-outer;
    //     f32 KV side-out) — R11-proven config (45.5 us)
    gemmT<1, 2, 4, 4, 6, true><<<256, 512, 0, stream>>>(
        XB, WQKVT, BQKV, QKVB, kv, nullptr, nullptr,
        4096, 3072, 1024, 1024, 1024, 3072, 0);
    ktv_partial<<<dim3(16, 32), 256, 0, stream>>>(QKVB, KTVF);
    // fold (KTV*s) into wp per (b,h): WPBT[b] = block-stacked KTV_h @ wp_h
    wpb_kernel<<<dim3(4, 32), 256, 0, stream>>>(KTVF, WPT, WPBT);

    // G3: out[b] = Q[b] @ WPBT[b]  (A = QKVB Q-cols, lda=3072; batch-B by row half;
    //     128x128 tile, split-K x2, 512 blocks, row-outer)
    gemmT<5, 2, 2, 4, 4, false><<<512, 256, 0, stream>>>(
        QKVB, WPBT, nullptr, (u16*)(WPBT + 1048576), nullptr, Q3_0, Q3_1,
        4096, 1024, 1024, 3072, 1024, 1024, 512);
    ln1_kernel<<<4096, 256, 0, stream>>>(x, Q3_0, Q3_1, bp, ln1g, ln1b, OUT1B);

    // G4: h1 = relu(out1 @ w1 + b1) (256x256 tile, grid 256, 512 thr — R7-proven)
    gemmT<2, 2, 4, 8, 4, false><<<256, 512, 0, stream>>>(
        OUT1B, W1T, b1, H1, nullptr, nullptr, nullptr,
        4096, 4096, 1024, 1024, 1024, 4096, 0);
    // G5: ff = h1 @ w2 (128x128 tile, split-K x2 over K=4096, 512 blocks, row-outer)
    gemmT<4, 2, 2, 4, 4, false><<<512, 256, 0, stream>>>(
        H1, W2T, nullptr, nullptr, nullptr, Q5_0, Q5_1,
        4096, 1024, 4096, 4096, 4096, 1024, 2048);
    lnf_kernel<<<4096, 256, 0, stream>>>(OUT1B, Q5_0, Q5_1, b2,
                                         lnfg, lnfb, ln2g, ln2b, out2);
}